// Round 1
// baseline (1002.565 us; speedup 1.0000x reference)
//
#include <hip/hip_runtime.h>
#include <math.h>

__device__ __forceinline__ float lrelu(float x){ return x > 0.f ? x : 0.2f*x; }

// ---------------- CSR build ----------------
__global__ void k_deg(const int* __restrict__ dst, int* __restrict__ deg, int E){
  int e = blockIdx.x*blockDim.x + threadIdx.x;
  if(e < E) atomicAdd(&deg[dst[e]], 1);
}

__global__ __launch_bounds__(1024) void k_scan(const int* __restrict__ deg, int* __restrict__ offs, int n){
  __shared__ int sm[1024];
  __shared__ int carry;
  if(threadIdx.x==0) carry = 0;
  __syncthreads();
  for(int base=0; base<n; base+=1024){
    int i = base + (int)threadIdx.x;
    int v = (i<n) ? deg[i] : 0;
    sm[threadIdx.x] = v;
    __syncthreads();
    for(int off=1; off<1024; off<<=1){
      int t = (threadIdx.x >= off) ? sm[threadIdx.x-off] : 0;
      __syncthreads();
      sm[threadIdx.x] += t;
      __syncthreads();
    }
    if(i<n) offs[i] = carry + sm[threadIdx.x] - v;   // exclusive
    __syncthreads();
    if(threadIdx.x==1023) carry += sm[1023];
    __syncthreads();
  }
  if(threadIdx.x==0) offs[n] = carry;
}

__global__ void k_fill(const int* __restrict__ src, const int* __restrict__ dst,
                       const int* __restrict__ offs, int* __restrict__ cur,
                       int* __restrict__ esrc, int E){
  int e = blockIdx.x*blockDim.x + threadIdx.x;
  if(e < E){
    int d = dst[e];
    int pos = offs[d] + atomicAdd(&cur[d], 1);
    esrc[pos] = src[e];
  }
}

// ---------------- GIN aggregation: out[i] = x[i] + sum_{j in in(i)} x[j] ----------------
template<int D>
__global__ __launch_bounds__(256) void k_agg(const float* __restrict__ xin,
                                             const int* __restrict__ offs,
                                             const int* __restrict__ esrc,
                                             float* __restrict__ out, int n){
  int wid  = (int)((blockIdx.x*256u + threadIdx.x) >> 6);
  int lane = threadIdx.x & 63;
  if(wid >= n) return;
  constexpr int NC = (D + 63) / 64;
  float acc[NC];
  #pragma unroll
  for(int j=0;j<NC;j++){ int c = lane + j*64; acc[j] = (c<D) ? xin[(size_t)wid*D + c] : 0.f; }
  int e0 = offs[wid], e1 = offs[wid+1];
  for(int t=e0; t<e1; t++){
    int s = esrc[t];
    const float* row = xin + (size_t)s*D;
    #pragma unroll
    for(int j=0;j<NC;j++){ int c = lane + j*64; if(c<D) acc[j] += row[c]; }
  }
  #pragma unroll
  for(int j=0;j<NC;j++){ int c = lane + j*64; if(c<D) out[(size_t)wid*D + c] = acc[j]; }
}

// ---------------- tiled fp32 GEMM: C[M,Nd] = A[M,K] @ B[K,Nd] (+bias)(+relu) ----------------
#define BM 64
#define BN 64
#define BKK 32

template<int ACT, bool HASBIAS>
__global__ __launch_bounds__(256) void k_gemm(const float* __restrict__ A, const float* __restrict__ B,
                                              const float* __restrict__ bias, float* __restrict__ C,
                                              int M, int K, int Nd){
  __shared__ float As[BM][BKK];
  __shared__ float Bs[BKK][BN];
  int row0 = blockIdx.x * BM;
  int col0 = blockIdx.y * BN;
  int tid = threadIdx.x;
  int tr = tid >> 4, tc = tid & 15;
  float acc[4][4] = {};
  for(int k0=0; k0<K; k0+=BKK){
    #pragma unroll
    for(int l=0;l<8;l++){                 // 64*32 = 2048 elems / 256 thr
      int idx = tid + l*256;
      int r = idx >> 5, c = idx & 31;
      int gr = row0 + r, gk = k0 + c;
      As[r][c] = (gr < M && gk < K) ? A[(size_t)gr*K + gk] : 0.f;
    }
    #pragma unroll
    for(int l=0;l<8;l++){                 // 32*64 = 2048
      int idx = tid + l*256;
      int r = idx >> 6, c = idx & 63;
      int gk = k0 + r, gc = col0 + c;
      Bs[r][c] = (gk < K && gc < Nd) ? B[(size_t)gk*Nd + gc] : 0.f;
    }
    __syncthreads();
    #pragma unroll
    for(int kk=0; kk<BKK; kk++){
      float a[4], b[4];
      #pragma unroll
      for(int i=0;i<4;i++) a[i] = As[tr*4+i][kk];
      #pragma unroll
      for(int j=0;j<4;j++) b[j] = Bs[kk][tc*4+j];
      #pragma unroll
      for(int i=0;i<4;i++)
        #pragma unroll
        for(int j=0;j<4;j++) acc[i][j] += a[i]*b[j];
    }
    __syncthreads();
  }
  #pragma unroll
  for(int i=0;i<4;i++){
    int gr = row0 + tr*4 + i;
    if(gr >= M) continue;
    #pragma unroll
    for(int j=0;j<4;j++){
      int gc = col0 + tc*4 + j;
      if(gc < Nd){
        float v = acc[i][j];
        if(HASBIAS) v += bias[gc];
        if(ACT) v = fmaxf(v, 0.f);
        C[(size_t)gr*Nd + gc] = v;
      }
    }
  }
}

// ---------------- GAT: per-node attention dots ----------------
template<int D>
__global__ __launch_bounds__(256) void k_dots(const float* __restrict__ hP,
                                              const float* __restrict__ a_s, const float* __restrict__ a_d,
                                              float* __restrict__ as_, float* __restrict__ ad_, int n){
  int wid  = (int)((blockIdx.x*256u + threadIdx.x) >> 6);
  int lane = threadIdx.x & 63;
  if(wid >= n) return;
  float s = 0.f, d = 0.f;
  #pragma unroll
  for(int j=0;j<D/64;j++){
    int c = lane + j*64;
    float v = hP[(size_t)wid*D + c];
    s += v * a_s[c];
    d += v * a_d[c];
  }
  #pragma unroll
  for(int off=32; off; off>>=1){ s += __shfl_down(s, off); d += __shfl_down(d, off); }
  if(lane==0){ as_[wid] = s; ad_[wid] = d; }
}

// ---------------- GAT: per-node softmax max & sum (self-loop included) ----------------
__global__ __launch_bounds__(256) void k_ms(const float* __restrict__ as_, const float* __restrict__ ad_,
                                            const int* __restrict__ offs, const int* __restrict__ esrc,
                                            float* __restrict__ m_, float* __restrict__ S_, int n){
  int i = blockIdx.x*blockDim.x + threadIdx.x;
  if(i >= n) return;
  float adi = ad_[i];
  float lself = lrelu(as_[i] + adi);
  float m = lself;
  int b = offs[i], e = offs[i+1];
  for(int t=b; t<e; t++){
    float l = lrelu(as_[esrc[t]] + adi);
    m = fmaxf(m, l);
  }
  float S = __expf(lself - m);
  for(int t=b; t<e; t++){
    float l = lrelu(as_[esrc[t]] + adi);
    S += __expf(l - m);
  }
  m_[i] = m; S_[i] = S;
}

// ---------------- GAT: weighted aggregation (self-loop included) ----------------
template<int D, int ACT>
__global__ __launch_bounds__(256) void k_gat_agg(const float* __restrict__ hP,
                                                 const float* __restrict__ as_, const float* __restrict__ ad_,
                                                 const float* __restrict__ m_, const float* __restrict__ S_,
                                                 const int* __restrict__ offs, const int* __restrict__ esrc,
                                                 const float* __restrict__ bias, float* __restrict__ out, int n){
  int wid  = (int)((blockIdx.x*256u + threadIdx.x) >> 6);
  int lane = threadIdx.x & 63;
  if(wid >= n) return;
  constexpr int NC = D/64;
  float adi = ad_[wid], mi = m_[wid];
  float inv = 1.f / (S_[wid] + 1e-16f);
  float acc[NC];
  float wgt = __expf(lrelu(as_[wid] + adi) - mi) * inv;   // self loop
  #pragma unroll
  for(int j=0;j<NC;j++) acc[j] = wgt * hP[(size_t)wid*D + lane + j*64];
  int e0 = offs[wid], e1 = offs[wid+1];
  for(int t=e0; t<e1; t++){
    int s = esrc[t];
    float w2 = __expf(lrelu(as_[s] + adi) - mi) * inv;
    const float* row = hP + (size_t)s*D;
    #pragma unroll
    for(int j=0;j<NC;j++) acc[j] += w2 * row[lane + j*64];
  }
  #pragma unroll
  for(int j=0;j<NC;j++){
    float v = acc[j] + bias[lane + j*64];
    if(ACT) v = fmaxf(v, 0.f);
    out[(size_t)wid*D + lane + j*64] = v;
  }
}

extern "C" void kernel_launch(void* const* d_in, const int* in_sizes, int n_in,
                              void* d_out, int out_size, void* d_ws, size_t ws_size,
                              hipStream_t stream){
  const float* x        = (const float*)d_in[0];
  const int*   ei       = (const int*)  d_in[1];
  const float* gin1_w1  = (const float*)d_in[3];
  const float* gin1_b1  = (const float*)d_in[4];
  const float* gin1_w2  = (const float*)d_in[5];
  const float* gin1_b2  = (const float*)d_in[6];
  const float* gin2_w1  = (const float*)d_in[7];
  const float* gin2_b1  = (const float*)d_in[8];
  const float* gin2_w2  = (const float*)d_in[9];
  const float* gin2_b2  = (const float*)d_in[10];
  const float* gat1_w   = (const float*)d_in[11];
  const float* gat1_as  = (const float*)d_in[12];
  const float* gat1_ad  = (const float*)d_in[13];
  const float* gat1_b   = (const float*)d_in[14];
  const float* gat2_w   = (const float*)d_in[15];
  const float* gat2_as  = (const float*)d_in[16];
  const float* gat2_ad  = (const float*)d_in[17];
  const float* gat2_b   = (const float*)d_in[18];

  const int n = in_sizes[0] / 10;
  const int E = in_sizes[1] / 2;
  const int* src = ei;
  const int* dst = ei + E;

  // workspace carve (256B aligned)
  char* w = (char*)d_ws;
  auto carve = [&](size_t bytes)->char*{ char* p = w; w += (bytes + 255) & ~(size_t)255; return p; };
  int*   esrc = (int*)  carve((size_t)E*4);
  int*   offs = (int*)  carve((size_t)(n+1)*4);
  int*   deg  = (int*)  carve((size_t)n*4);
  int*   cur  = (int*)  carve((size_t)n*4);
  float* buf1 = (float*)carve((size_t)n*256*4);   // N x 256
  float* buf2 = (float*)carve((size_t)n*128*4);   // N x 128
  float* buf3 = (float*)carve((size_t)n*256*4);   // N x 256
  float* as_  = (float*)carve((size_t)n*4);
  float* ad_  = (float*)carve((size_t)n*4);
  float* m_   = (float*)carve((size_t)n*4);
  float* S_   = (float*)carve((size_t)n*4);

  const int TPB = 256;
  int ebk = (E + TPB - 1) / TPB;
  int nbk = (n + TPB - 1) / TPB;
  int wbk = (n + 3) / 4;               // 4 waves per 256-thread block
  int mt  = (n + BM - 1) / BM;

  // CSR build
  hipMemsetAsync(deg, 0, (size_t)n*4, stream);
  hipMemsetAsync(cur, 0, (size_t)n*4, stream);
  k_deg<<<ebk, TPB, 0, stream>>>(dst, deg, E);
  k_scan<<<1, 1024, 0, stream>>>(deg, offs, n);
  k_fill<<<ebk, TPB, 0, stream>>>(src, dst, offs, cur, esrc, E);

  // GIN1: agg(x) -> buf1[N,10]; MLP 10->64 relu -> buf2; 64->64 +relu(outer) -> buf1 (hA)
  k_agg<10><<<wbk, TPB, 0, stream>>>(x, offs, esrc, buf1, n);
  k_gemm<1,true><<<dim3(mt,1), TPB, 0, stream>>>(buf1, gin1_w1, gin1_b1, buf2, n, 10, 64);
  k_gemm<1,true><<<dim3(mt,1), TPB, 0, stream>>>(buf2, gin1_w2, gin1_b2, buf1, n, 64, 64);

  // GIN2: agg(hA) -> buf2[N,64]; 64->128 relu -> buf3; 128->128 -> buf2 (hB)
  k_agg<64><<<wbk, TPB, 0, stream>>>(buf1, offs, esrc, buf2, n);
  k_gemm<1,true><<<dim3(mt,2), TPB, 0, stream>>>(buf2, gin2_w1, gin2_b1, buf3, n, 64, 128);
  k_gemm<0,true><<<dim3(mt,2), TPB, 0, stream>>>(buf3, gin2_w2, gin2_b2, buf2, n, 128, 128);

  // GAT1: proj 128->256 -> buf1 (hP); dots; ms; agg +bias +relu -> buf3
  k_gemm<0,false><<<dim3(mt,4), TPB, 0, stream>>>(buf2, gat1_w, nullptr, buf1, n, 128, 256);
  k_dots<256><<<wbk, TPB, 0, stream>>>(buf1, gat1_as, gat1_ad, as_, ad_, n);
  k_ms<<<nbk, TPB, 0, stream>>>(as_, ad_, offs, esrc, m_, S_, n);
  k_gat_agg<256,1><<<wbk, TPB, 0, stream>>>(buf1, as_, ad_, m_, S_, offs, esrc, gat1_b, buf3, n);

  // GAT2: proj 256->128 -> buf2 (hP2); dots; ms; agg +bias -> d_out
  k_gemm<0,false><<<dim3(mt,2), TPB, 0, stream>>>(buf3, gat2_w, nullptr, buf2, n, 256, 128);
  k_dots<128><<<wbk, TPB, 0, stream>>>(buf2, gat2_as, gat2_ad, as_, ad_, n);
  k_ms<<<nbk, TPB, 0, stream>>>(as_, ad_, offs, esrc, m_, S_, n);
  k_gat_agg<128,0><<<wbk, TPB, 0, stream>>>(buf2, as_, ad_, m_, S_, offs, esrc, gat2_b, (float*)d_out, n);
}

// Round 2
// 755.715 us; speedup vs baseline: 1.3266x; 1.3266x over previous
//
#include <hip/hip_runtime.h>
#include <math.h>

__device__ __forceinline__ float lrelu(float x){ return x > 0.f ? x : 0.2f*x; }

typedef short s16x8 __attribute__((ext_vector_type(8)));
typedef float f32x4 __attribute__((ext_vector_type(4)));

__device__ __forceinline__ f32x4 bmma(s16x8 a, s16x8 b, f32x4 c){
  return __builtin_amdgcn_mfma_f32_16x16x32_bf16(a, b, c, 0, 0, 0);
}

__device__ __forceinline__ unsigned short f2bf(float f){
  unsigned u = __float_as_uint(f);
  unsigned r = (u + 0x7fffu + ((u >> 16) & 1u)) >> 16;
  return (unsigned short)r;
}
__device__ __forceinline__ float bf2f(unsigned short h){
  return __uint_as_float(((unsigned)h) << 16);
}

// ---------------- CSR build ----------------
__global__ void k_deg(const int* __restrict__ dst, int* __restrict__ deg, int E){
  int e = blockIdx.x*blockDim.x + threadIdx.x;
  if(e < E) atomicAdd(&deg[dst[e]], 1);
}

__global__ __launch_bounds__(1024) void k_scan(const int* __restrict__ deg, int* __restrict__ offs, int n){
  __shared__ int sm[1024];
  __shared__ int carry;
  if(threadIdx.x==0) carry = 0;
  __syncthreads();
  for(int base=0; base<n; base+=1024){
    int i = base + (int)threadIdx.x;
    int v = (i<n) ? deg[i] : 0;
    sm[threadIdx.x] = v;
    __syncthreads();
    for(int off=1; off<1024; off<<=1){
      int t = (threadIdx.x >= off) ? sm[threadIdx.x-off] : 0;
      __syncthreads();
      sm[threadIdx.x] += t;
      __syncthreads();
    }
    if(i<n) offs[i] = carry + sm[threadIdx.x] - v;   // exclusive
    __syncthreads();
    if(threadIdx.x==1023) carry += sm[1023];
    __syncthreads();
  }
  if(threadIdx.x==0) offs[n] = carry;
}

__global__ void k_fill(const int* __restrict__ src, const int* __restrict__ dst,
                       const int* __restrict__ offs, int* __restrict__ cur,
                       int* __restrict__ esrc, int E){
  int e = blockIdx.x*blockDim.x + threadIdx.x;
  if(e < E){
    int d = dst[e];
    int pos = offs[d] + atomicAdd(&cur[d], 1);
    esrc[pos] = src[e];
  }
}

// ---------------- GIN aggregation: out[i] = x[i] + sum_{j in in(i)} x[j] ----------------
template<int D>
__global__ __launch_bounds__(256) void k_agg(const float* __restrict__ xin,
                                             const int* __restrict__ offs,
                                             const int* __restrict__ esrc,
                                             float* __restrict__ out, int n){
  int wid  = (int)((blockIdx.x*256u + threadIdx.x) >> 6);
  int lane = threadIdx.x & 63;
  if(wid >= n) return;
  constexpr int NC = (D + 63) / 64;
  float acc[NC];
  #pragma unroll
  for(int j=0;j<NC;j++){ int c = lane + j*64; acc[j] = (c<D) ? xin[(size_t)wid*D + c] : 0.f; }
  int e0 = offs[wid], e1 = offs[wid+1];
  for(int t=e0; t<e1; t++){
    int s = esrc[t];
    const float* row = xin + (size_t)s*D;
    #pragma unroll
    for(int j=0;j<NC;j++){ int c = lane + j*64; if(c<D) acc[j] += row[c]; }
  }
  #pragma unroll
  for(int j=0;j<NC;j++){ int c = lane + j*64; if(c<D) out[(size_t)wid*D + c] = acc[j]; }
}

// ---------------- split-bf16 fragment prep ----------------
// A [M x K] fp32 -> frag layout [Mc][Kc][64 lanes][8], hi/lo bf16.
// frag lane mapping (mfma_f32_16x16x32_bf16 A-operand):
//   row = mc*16 + (lane&15), k = kc*32 + (lane>>4)*8 + j
__global__ __launch_bounds__(256) void k_prepA(const float* __restrict__ A,
                                               unsigned short* __restrict__ hi,
                                               unsigned short* __restrict__ lo,
                                               int M, int K, int Mc, int Kc){
  int gid = blockIdx.x*256 + threadIdx.x;
  int lane = gid & 63;
  int fid  = gid >> 6;                 // fid = mc*Kc + kc
  if(fid >= Mc*Kc) return;
  int mc = fid / Kc, kc = fid - mc*Kc;
  int row = mc*16 + (lane & 15);
  int k0  = kc*32 + (lane >> 4)*8;
  s16x8 h, l;
  if(row < M){
    const float* ap = A + (size_t)row*K + k0;
    #pragma unroll
    for(int j=0;j<8;j++){
      float v = (k0 + j < K) ? ap[j] : 0.f;
      unsigned short hb = f2bf(v);
      float r = v - bf2f(hb);
      h[j] = (short)hb; l[j] = (short)f2bf(r);
    }
  } else {
    #pragma unroll
    for(int j=0;j<8;j++){ h[j]=0; l[j]=0; }
  }
  size_t off = (size_t)fid*512 + (size_t)lane*8;
  *(s16x8*)(hi + off) = h;
  *(s16x8*)(lo + off) = l;
}

// B [K x Nd] fp32 -> frag layout [Nc][Kc][64][8]:
//   col = nc*16 + (lane&15), k = kc*32 + (lane>>4)*8 + j
__global__ __launch_bounds__(256) void k_prepB(const float* __restrict__ B,
                                               unsigned short* __restrict__ hi,
                                               unsigned short* __restrict__ lo,
                                               int K, int Nd, int Kc, int Nc){
  int gid = blockIdx.x*256 + threadIdx.x;
  int lane = gid & 63;
  int fid  = gid >> 6;                 // fid = nc*Kc + kc
  if(fid >= Nc*Kc) return;
  int nc = fid / Kc, kc = fid - nc*Kc;
  int col = nc*16 + (lane & 15);
  int k0  = kc*32 + (lane >> 4)*8;
  s16x8 h, l;
  #pragma unroll
  for(int j=0;j<8;j++){
    int k = k0 + j;
    float v = (k < K) ? B[(size_t)k*Nd + col] : 0.f;
    unsigned short hb = f2bf(v);
    float r = v - bf2f(hb);
    h[j] = (short)hb; l[j] = (short)f2bf(r);
  }
  size_t off = (size_t)fid*512 + (size_t)lane*8;
  *(s16x8*)(hi + off) = h;
  *(s16x8*)(lo + off) = l;
}

// ---------------- split-bf16 MFMA GEMM ----------------
// C[M,Nd] = A*B (+bias)(+relu); A,B prepped in fragment order.
// block: 256 thr = 4 waves (2Mx2N); wave: 64 rows x 32 cols; mfma 16x16x32.
template<int ACT, bool HASBIAS>
__global__ __launch_bounds__(256) void k_mgemm(const unsigned short* __restrict__ Ahi,
                                               const unsigned short* __restrict__ Alo,
                                               const unsigned short* __restrict__ Bhi,
                                               const unsigned short* __restrict__ Blo,
                                               const float* __restrict__ bias,
                                               float* __restrict__ C,
                                               int M, int Nd, int Kc, int Mc){
  int tid = threadIdx.x;
  int wid = tid >> 6, lane = tid & 63;
  int wm = wid >> 1, wn = wid & 1;
  int mcb = blockIdx.x*8 + wm*4;
  int ncb = blockIdx.y*4 + wn*2;

  f32x4 acc[4][2];
  #pragma unroll
  for(int f=0;f<4;f++)
    #pragma unroll
    for(int g=0;g<2;g++) acc[f][g] = (f32x4){0.f,0.f,0.f,0.f};

  for(int kc=0; kc<Kc; kc++){
    s16x8 ah[4], al[4], bh[2], bl[2];
    #pragma unroll
    for(int f=0;f<4;f++){
      int mcf = mcb + f; if(mcf > Mc-1) mcf = Mc-1;     // clamp (stores guarded by row<M)
      size_t off = ((size_t)mcf*Kc + kc)*512 + (size_t)lane*8;
      ah[f] = *(const s16x8*)(Ahi + off);
      al[f] = *(const s16x8*)(Alo + off);
    }
    #pragma unroll
    for(int g=0;g<2;g++){
      size_t off = ((size_t)(ncb+g)*Kc + kc)*512 + (size_t)lane*8;
      bh[g] = *(const s16x8*)(Bhi + off);
      bl[g] = *(const s16x8*)(Blo + off);
    }
    #pragma unroll
    for(int f=0;f<4;f++)
      #pragma unroll
      for(int g=0;g<2;g++){
        acc[f][g] = bmma(ah[f], bh[g], acc[f][g]);
        acc[f][g] = bmma(ah[f], bl[g], acc[f][g]);
        acc[f][g] = bmma(al[f], bh[g], acc[f][g]);
      }
  }

  // epilogue: C/D layout col=lane&15, row=(lane>>4)*4+reg
  #pragma unroll
  for(int g=0;g<2;g++){
    int col = (ncb+g)*16 + (lane & 15);
    float bv = HASBIAS ? bias[col] : 0.f;
    #pragma unroll
    for(int f=0;f<4;f++){
      int row0 = (mcb+f)*16 + (lane>>4)*4;
      #pragma unroll
      for(int r=0;r<4;r++){
        int row = row0 + r;
        if(row < M){
          float v = acc[f][g][r] + bv;
          if(ACT) v = fmaxf(v, 0.f);
          C[(size_t)row*Nd + col] = v;
        }
      }
    }
  }
}

// ---------------- GAT: per-node attention dots ----------------
template<int D>
__global__ __launch_bounds__(256) void k_dots(const float* __restrict__ hP,
                                              const float* __restrict__ a_s, const float* __restrict__ a_d,
                                              float* __restrict__ as_, float* __restrict__ ad_, int n){
  int wid  = (int)((blockIdx.x*256u + threadIdx.x) >> 6);
  int lane = threadIdx.x & 63;
  if(wid >= n) return;
  float s = 0.f, d = 0.f;
  #pragma unroll
  for(int j=0;j<D/64;j++){
    int c = lane + j*64;
    float v = hP[(size_t)wid*D + c];
    s += v * a_s[c];
    d += v * a_d[c];
  }
  #pragma unroll
  for(int off=32; off; off>>=1){ s += __shfl_down(s, off); d += __shfl_down(d, off); }
  if(lane==0){ as_[wid] = s; ad_[wid] = d; }
}

// ---------------- GAT: per-node softmax max & sum (self-loop included) ----------------
__global__ __launch_bounds__(256) void k_ms(const float* __restrict__ as_, const float* __restrict__ ad_,
                                            const int* __restrict__ offs, const int* __restrict__ esrc,
                                            float* __restrict__ m_, float* __restrict__ S_, int n){
  int i = blockIdx.x*blockDim.x + threadIdx.x;
  if(i >= n) return;
  float adi = ad_[i];
  float lself = lrelu(as_[i] + adi);
  float m = lself;
  int b = offs[i], e = offs[i+1];
  for(int t=b; t<e; t++){
    float l = lrelu(as_[esrc[t]] + adi);
    m = fmaxf(m, l);
  }
  float S = __expf(lself - m);
  for(int t=b; t<e; t++){
    float l = lrelu(as_[esrc[t]] + adi);
    S += __expf(l - m);
  }
  m_[i] = m; S_[i] = S;
}

// ---------------- GAT: weighted aggregation (self-loop included) ----------------
template<int D, int ACT>
__global__ __launch_bounds__(256) void k_gat_agg(const float* __restrict__ hP,
                                                 const float* __restrict__ as_, const float* __restrict__ ad_,
                                                 const float* __restrict__ m_, const float* __restrict__ S_,
                                                 const int* __restrict__ offs, const int* __restrict__ esrc,
                                                 const float* __restrict__ bias, float* __restrict__ out, int n){
  int wid  = (int)((blockIdx.x*256u + threadIdx.x) >> 6);
  int lane = threadIdx.x & 63;
  if(wid >= n) return;
  constexpr int NC = D/64;
  float adi = ad_[wid], mi = m_[wid];
  float inv = 1.f / (S_[wid] + 1e-16f);
  float acc[NC];
  float wgt = __expf(lrelu(as_[wid] + adi) - mi) * inv;   // self loop
  #pragma unroll
  for(int j=0;j<NC;j++) acc[j] = wgt * hP[(size_t)wid*D + lane + j*64];
  int e0 = offs[wid], e1 = offs[wid+1];
  for(int t=e0; t<e1; t++){
    int s = esrc[t];
    float w2 = __expf(lrelu(as_[s] + adi) - mi) * inv;
    const float* row = hP + (size_t)s*D;
    #pragma unroll
    for(int j=0;j<NC;j++) acc[j] += w2 * row[lane + j*64];
  }
  #pragma unroll
  for(int j=0;j<NC;j++){
    float v = acc[j] + bias[lane + j*64];
    if(ACT) v = fmaxf(v, 0.f);
    out[(size_t)wid*D + lane + j*64] = v;
  }
}

extern "C" void kernel_launch(void* const* d_in, const int* in_sizes, int n_in,
                              void* d_out, int out_size, void* d_ws, size_t ws_size,
                              hipStream_t stream){
  const float* x        = (const float*)d_in[0];
  const int*   ei       = (const int*)  d_in[1];
  const float* gin1_w1  = (const float*)d_in[3];
  const float* gin1_b1  = (const float*)d_in[4];
  const float* gin1_w2  = (const float*)d_in[5];
  const float* gin1_b2  = (const float*)d_in[6];
  const float* gin2_w1  = (const float*)d_in[7];
  const float* gin2_b1  = (const float*)d_in[8];
  const float* gin2_w2  = (const float*)d_in[9];
  const float* gin2_b2  = (const float*)d_in[10];
  const float* gat1_w   = (const float*)d_in[11];
  const float* gat1_as  = (const float*)d_in[12];
  const float* gat1_ad  = (const float*)d_in[13];
  const float* gat1_b   = (const float*)d_in[14];
  const float* gat2_w   = (const float*)d_in[15];
  const float* gat2_as  = (const float*)d_in[16];
  const float* gat2_ad  = (const float*)d_in[17];
  const float* gat2_b   = (const float*)d_in[18];

  const int n = in_sizes[0] / 10;
  const int E = in_sizes[1] / 2;
  const int* src = ei;
  const int* dst = ei + E;
  const int Mc = (n + 15) / 16;

  // workspace carve (256B aligned)
  char* w = (char*)d_ws;
  auto carve = [&](size_t bytes)->char*{ char* p = w; w += (bytes + 255) & ~(size_t)255; return p; };
  int*   esrc = (int*)  carve((size_t)E*4);
  int*   offs = (int*)  carve((size_t)(n+1)*4);
  int*   deg  = (int*)  carve((size_t)n*4);
  int*   cur  = (int*)  carve((size_t)n*4);
  float* bufA = (float*)carve((size_t)n*256*4);
  float* bufB = (float*)carve((size_t)n*256*4);
  float* as_  = (float*)carve((size_t)n*4);
  float* ad_  = (float*)carve((size_t)n*4);
  float* m_   = (float*)carve((size_t)n*4);
  float* S_   = (float*)carve((size_t)n*4);
  unsigned short* AfH = (unsigned short*)carve((size_t)Mc*8*512*2);  // Kc<=8
  unsigned short* AfL = (unsigned short*)carve((size_t)Mc*8*512*2);
  unsigned short* BfH = (unsigned short*)carve((size_t)64*512*2);    // Nc*Kc<=64 frags
  unsigned short* BfL = (unsigned short*)carve((size_t)64*512*2);

  const int TPB = 256;
  int ebk = (E + TPB - 1) / TPB;
  int nbk = (n + TPB - 1) / TPB;
  int wbk = (n + 3) / 4;               // 4 waves per 256-thread block

  auto run_gemm = [&](const float* Afp, const float* Bfp, const float* bias, float* Cout,
                      int K, int Nd, int act, bool hasb){
    int Kc = (K + 31) / 32, Nc = Nd / 16;
    int afr = Mc * Kc, bfr = Nc * Kc;
    k_prepA<<<(afr*64 + 255)/256, 256, 0, stream>>>(Afp, AfH, AfL, n, K, Mc, Kc);
    k_prepB<<<(bfr*64 + 255)/256, 256, 0, stream>>>(Bfp, BfH, BfL, K, Nd, Kc, Nc);
    dim3 g((Mc + 7)/8, Nd/64);
    if(act && hasb)       k_mgemm<1,true ><<<g, TPB, 0, stream>>>(AfH, AfL, BfH, BfL, bias, Cout, n, Nd, Kc, Mc);
    else if(!act && hasb) k_mgemm<0,true ><<<g, TPB, 0, stream>>>(AfH, AfL, BfH, BfL, bias, Cout, n, Nd, Kc, Mc);
    else                  k_mgemm<0,false><<<g, TPB, 0, stream>>>(AfH, AfL, BfH, BfL, nullptr, Cout, n, Nd, Kc, Mc);
  };

  // CSR build
  hipMemsetAsync(deg, 0, (size_t)n*4, stream);
  hipMemsetAsync(cur, 0, (size_t)n*4, stream);
  k_deg<<<ebk, TPB, 0, stream>>>(dst, deg, E);
  k_scan<<<1, 1024, 0, stream>>>(deg, offs, n);
  k_fill<<<ebk, TPB, 0, stream>>>(src, dst, offs, cur, esrc, E);

  // GIN1: agg(x) -> bufA[N,10]; 10->64 relu -> bufB; 64->64 relu(outer fused) -> bufA (hA)
  k_agg<10><<<wbk, TPB, 0, stream>>>(x, offs, esrc, bufA, n);
  run_gemm(bufA, gin1_w1, gin1_b1, bufB, 10, 64, 1, true);
  run_gemm(bufB, gin1_w2, gin1_b2, bufA, 64, 64, 1, true);

  // GIN2: agg(hA) -> bufB[N,64]; 64->128 relu -> bufA; 128->128 -> bufB (hB)
  k_agg<64><<<wbk, TPB, 0, stream>>>(bufA, offs, esrc, bufB, n);
  run_gemm(bufB, gin2_w1, gin2_b1, bufA, 64, 128, 1, true);
  run_gemm(bufA, gin2_w2, gin2_b2, bufB, 128, 128, 0, true);

  // GAT1: proj 128->256 -> bufA (hP1); dots; ms; agg +bias +relu -> bufB
  run_gemm(bufB, gat1_w, nullptr, bufA, 128, 256, 0, false);
  k_dots<256><<<wbk, TPB, 0, stream>>>(bufA, gat1_as, gat1_ad, as_, ad_, n);
  k_ms<<<nbk, TPB, 0, stream>>>(as_, ad_, offs, esrc, m_, S_, n);
  k_gat_agg<256,1><<<wbk, TPB, 0, stream>>>(bufA, as_, ad_, m_, S_, offs, esrc, gat1_b, bufB, n);

  // GAT2: proj 256->128 -> bufA (hP2); dots; ms; agg +bias -> d_out
  run_gemm(bufB, gat2_w, nullptr, bufA, 256, 128, 0, false);
  k_dots<128><<<wbk, TPB, 0, stream>>>(bufA, gat2_as, gat2_ad, as_, ad_, n);
  k_ms<<<nbk, TPB, 0, stream>>>(as_, ad_, offs, esrc, m_, S_, n);
  k_gat_agg<128,0><<<wbk, TPB, 0, stream>>>(bufA, as_, ad_, m_, S_, offs, esrc, gat2_b, (float*)d_out, n);
}

// Round 4
// 607.786 us; speedup vs baseline: 1.6495x; 1.2434x over previous
//
#include <hip/hip_runtime.h>
#include <math.h>

__device__ __forceinline__ float lrelu(float x){ return x > 0.f ? x : 0.2f*x; }

typedef short s16x8 __attribute__((ext_vector_type(8)));
typedef float f32x4 __attribute__((ext_vector_type(4)));
typedef unsigned short u16x4 __attribute__((ext_vector_type(4)));
typedef unsigned short u16x2 __attribute__((ext_vector_type(2)));

__device__ __forceinline__ f32x4 bmma(s16x8 a, s16x8 b, f32x4 c){
  return __builtin_amdgcn_mfma_f32_16x16x32_bf16(a, b, c, 0, 0, 0);
}

__device__ __forceinline__ unsigned short f2bf(float f){
  unsigned u = __float_as_uint(f);
  unsigned r = (u + 0x7fffu + ((u >> 16) & 1u)) >> 16;
  return (unsigned short)r;
}
__device__ __forceinline__ float bf2f(unsigned short h){
  return __uint_as_float(((unsigned)h) << 16);
}

// ---------------- CSR build ----------------
__global__ void k_deg(const int* __restrict__ dst, int* __restrict__ deg, int E){
  int e = blockIdx.x*blockDim.x + threadIdx.x;
  if(e < E) atomicAdd(&deg[dst[e]], 1);
}

__global__ __launch_bounds__(1024) void k_scan(const int* __restrict__ deg, int* __restrict__ offs, int n){
  __shared__ int sm[1024];
  __shared__ int carry;
  if(threadIdx.x==0) carry = 0;
  __syncthreads();
  for(int base=0; base<n; base+=1024){
    int i = base + (int)threadIdx.x;
    int v = (i<n) ? deg[i] : 0;
    sm[threadIdx.x] = v;
    __syncthreads();
    for(int off=1; off<1024; off<<=1){
      int t = (threadIdx.x >= off) ? sm[threadIdx.x-off] : 0;
      __syncthreads();
      sm[threadIdx.x] += t;
      __syncthreads();
    }
    if(i<n) offs[i] = carry + sm[threadIdx.x] - v;   // exclusive
    __syncthreads();
    if(threadIdx.x==1023) carry += sm[1023];
    __syncthreads();
  }
  if(threadIdx.x==0) offs[n] = carry;
}

__global__ void k_fill(const int* __restrict__ src, const int* __restrict__ dst,
                       const int* __restrict__ offs, int* __restrict__ cur,
                       int* __restrict__ esrc, int E){
  int e = blockIdx.x*blockDim.x + threadIdx.x;
  if(e < E){
    int d = dst[e];
    int pos = offs[d] + atomicAdd(&cur[d], 1);
    esrc[pos] = src[e];
  }
}

// ---------------- GIN aggregation (fp32 input, layer 1 only, D=10) ----------------
template<int D>
__global__ __launch_bounds__(256) void k_agg(const float* __restrict__ xin,
                                             const int* __restrict__ offs,
                                             const int* __restrict__ esrc,
                                             float* __restrict__ out, int n){
  int wid  = (int)((blockIdx.x*256u + threadIdx.x) >> 6);
  int lane = threadIdx.x & 63;
  if(wid >= n) return;
  constexpr int NC = (D + 63) / 64;
  float acc[NC];
  #pragma unroll
  for(int j=0;j<NC;j++){ int c = lane + j*64; acc[j] = (c<D) ? xin[(size_t)wid*D + c] : 0.f; }
  int e0 = offs[wid], e1 = offs[wid+1];
  for(int t=e0; t<e1; t++){
    int s = esrc[t];
    const float* row = xin + (size_t)s*D;
    #pragma unroll
    for(int j=0;j<NC;j++){ int c = lane + j*64; if(c<D) acc[j] += row[c]; }
  }
  #pragma unroll
  for(int j=0;j<NC;j++){ int c = lane + j*64; if(c<D) out[(size_t)wid*D + c] = acc[j]; }
}

// ---------------- GIN aggregation, bf16 rows: out[i] = x[i] + sum x[j] (fp32 out) ----------------
template<int D>
__global__ __launch_bounds__(256) void k_agg_bf(const unsigned short* __restrict__ xin,
                                                const int* __restrict__ offs,
                                                const int* __restrict__ esrc,
                                                float* __restrict__ out, int n){
  int wid  = (int)((blockIdx.x*256u + threadIdx.x) >> 6);
  int lane = threadIdx.x & 63;
  if(wid >= n) return;
  static_assert(D == 64, "D=64 only");
  float acc = bf2f(xin[(size_t)wid*D + lane]);
  int e0 = offs[wid], e1 = offs[wid+1];
  int t = e0;
  for(; t+3 < e1; t += 4){
    int s0 = esrc[t], s1 = esrc[t+1], s2 = esrc[t+2], s3 = esrc[t+3];
    unsigned short v0 = xin[(size_t)s0*D + lane];
    unsigned short v1 = xin[(size_t)s1*D + lane];
    unsigned short v2 = xin[(size_t)s2*D + lane];
    unsigned short v3 = xin[(size_t)s3*D + lane];
    acc += bf2f(v0) + bf2f(v1) + bf2f(v2) + bf2f(v3);
  }
  for(; t < e1; t++) acc += bf2f(xin[(size_t)esrc[t]*D + lane]);
  out[(size_t)wid*D + lane] = acc;
}

// ---------------- split-bf16 fragment prep ----------------
__global__ __launch_bounds__(256) void k_prepA(const float* __restrict__ A,
                                               unsigned short* __restrict__ hi,
                                               unsigned short* __restrict__ lo,
                                               int M, int K, int Mc, int Kc){
  int gid = blockIdx.x*256 + threadIdx.x;
  int lane = gid & 63;
  int fid  = gid >> 6;                 // fid = mc*Kc + kc
  if(fid >= Mc*Kc) return;
  int mc = fid / Kc, kc = fid - mc*Kc;
  int row = mc*16 + (lane & 15);
  int k0  = kc*32 + (lane >> 4)*8;
  s16x8 h, l;
  if(row < M){
    const float* ap = A + (size_t)row*K + k0;
    #pragma unroll
    for(int j=0;j<8;j++){
      float v = (k0 + j < K) ? ap[j] : 0.f;
      unsigned short hb = f2bf(v);
      float r = v - bf2f(hb);
      h[j] = (short)hb; l[j] = (short)f2bf(r);
    }
  } else {
    #pragma unroll
    for(int j=0;j<8;j++){ h[j]=0; l[j]=0; }
  }
  size_t off = (size_t)fid*512 + (size_t)lane*8;
  *(s16x8*)(hi + off) = h;
  *(s16x8*)(lo + off) = l;
}

__global__ __launch_bounds__(256) void k_prepB(const float* __restrict__ B,
                                               unsigned short* __restrict__ hi,
                                               unsigned short* __restrict__ lo,
                                               int K, int Nd, int Kc, int Nc){
  int gid = blockIdx.x*256 + threadIdx.x;
  int lane = gid & 63;
  int fid  = gid >> 6;                 // fid = nc*Kc + kc
  if(fid >= Nc*Kc) return;
  int nc = fid / Kc, kc = fid - nc*Kc;
  int col = nc*16 + (lane & 15);
  int k0  = kc*32 + (lane >> 4)*8;
  s16x8 h, l;
  #pragma unroll
  for(int j=0;j<8;j++){
    int k = k0 + j;
    float v = (k < K) ? B[(size_t)k*Nd + col] : 0.f;
    unsigned short hb = f2bf(v);
    float r = v - bf2f(hb);
    h[j] = (short)hb; l[j] = (short)f2bf(r);
  }
  size_t off = (size_t)fid*512 + (size_t)lane*8;
  *(s16x8*)(hi + off) = h;
  *(s16x8*)(lo + off) = l;
}

// ---------------- split-bf16 MFMA GEMM ----------------
template<int ACT, bool HASBIAS, bool OBF>
__global__ __launch_bounds__(256) void k_mgemm(const unsigned short* __restrict__ Ahi,
                                               const unsigned short* __restrict__ Alo,
                                               const unsigned short* __restrict__ Bhi,
                                               const unsigned short* __restrict__ Blo,
                                               const float* __restrict__ bias,
                                               float* __restrict__ C,
                                               unsigned short* __restrict__ Cbf,
                                               int M, int Nd, int Kc, int Mc){
  int tid = threadIdx.x;
  int wid = tid >> 6, lane = tid & 63;
  int wm = wid >> 1, wn = wid & 1;
  int mcb = blockIdx.x*8 + wm*4;
  int ncb = blockIdx.y*4 + wn*2;

  f32x4 acc[4][2];
  #pragma unroll
  for(int f=0;f<4;f++)
    #pragma unroll
    for(int g=0;g<2;g++) acc[f][g] = (f32x4){0.f,0.f,0.f,0.f};

  for(int kc=0; kc<Kc; kc++){
    s16x8 ah[4], al[4], bh[2], bl[2];
    #pragma unroll
    for(int f=0;f<4;f++){
      int mcf = mcb + f; if(mcf > Mc-1) mcf = Mc-1;     // clamp (stores guarded by row<M)
      size_t off = ((size_t)mcf*Kc + kc)*512 + (size_t)lane*8;
      ah[f] = *(const s16x8*)(Ahi + off);
      al[f] = *(const s16x8*)(Alo + off);
    }
    #pragma unroll
    for(int g=0;g<2;g++){
      size_t off = ((size_t)(ncb+g)*Kc + kc)*512 + (size_t)lane*8;
      bh[g] = *(const s16x8*)(Bhi + off);
      bl[g] = *(const s16x8*)(Blo + off);
    }
    #pragma unroll
    for(int f=0;f<4;f++)
      #pragma unroll
      for(int g=0;g<2;g++){
        acc[f][g] = bmma(ah[f], bh[g], acc[f][g]);
        acc[f][g] = bmma(ah[f], bl[g], acc[f][g]);
        acc[f][g] = bmma(al[f], bh[g], acc[f][g]);
      }
  }

  // epilogue: C/D layout col=lane&15, row=(lane>>4)*4+reg
  #pragma unroll
  for(int g=0;g<2;g++){
    int col = (ncb+g)*16 + (lane & 15);
    float bv = HASBIAS ? bias[col] : 0.f;
    #pragma unroll
    for(int f=0;f<4;f++){
      int row0 = (mcb+f)*16 + (lane>>4)*4;
      #pragma unroll
      for(int r=0;r<4;r++){
        int row = row0 + r;
        if(row < M){
          float v = acc[f][g][r] + bv;
          if(ACT) v = fmaxf(v, 0.f);
          if(OBF) Cbf[(size_t)row*Nd + col] = f2bf(v);
          else    C  [(size_t)row*Nd + col] = v;
        }
      }
    }
  }
}

// ---------------- GAT: wa = W @ a (folded attention vectors) ----------------
// W [rows x L] row-major, a_s/a_d [L] -> wa_s/wa_d [rows]
template<int L>
__global__ __launch_bounds__(256) void k_wa(const float* __restrict__ W,
                                            const float* __restrict__ a_s, const float* __restrict__ a_d,
                                            float* __restrict__ wa_s, float* __restrict__ wa_d, int rows){
  int wid  = (int)((blockIdx.x*256u + threadIdx.x) >> 6);
  int lane = threadIdx.x & 63;
  if(wid >= rows) return;
  float s = 0.f, d = 0.f;
  #pragma unroll
  for(int j=0;j<L/64;j++){
    int c = lane + j*64;
    float v = W[(size_t)wid*L + c];
    s += v * a_s[c];
    d += v * a_d[c];
  }
  #pragma unroll
  for(int off=32; off; off>>=1){ s += __shfl_down(s, off); d += __shfl_down(d, off); }
  if(lane==0){ wa_s[wid] = s; wa_d[wid] = d; }
}

// ---------------- GAT: logits from fp32 GEMM input: as_[i] = F[i,:]·wa_s ----------------
template<int K>
__global__ __launch_bounds__(256) void k_dotsF(const float* __restrict__ F,
                                               const float* __restrict__ wa_s, const float* __restrict__ wa_d,
                                               float* __restrict__ as_, float* __restrict__ ad_, int n){
  int wid  = (int)((blockIdx.x*256u + threadIdx.x) >> 6);
  int lane = threadIdx.x & 63;
  if(wid >= n) return;
  float s = 0.f, d = 0.f;
  #pragma unroll
  for(int j=0;j<K/64;j++){
    int c = lane + j*64;
    float v = F[(size_t)wid*K + c];
    s += v * wa_s[c];
    d += v * wa_d[c];
  }
  #pragma unroll
  for(int off=32; off; off>>=1){ s += __shfl_down(s, off); d += __shfl_down(d, off); }
  if(lane==0){ as_[wid] = s; ad_[wid] = d; }
}

// ---------------- GAT: per-node softmax max & sum, single pass (self-loop included) ----------------
__global__ __launch_bounds__(256) void k_ms(const float* __restrict__ as_, const float* __restrict__ ad_,
                                            const int* __restrict__ offs, const int* __restrict__ esrc,
                                            float* __restrict__ m_, float* __restrict__ S_, int n){
  int i = blockIdx.x*blockDim.x + threadIdx.x;
  if(i >= n) return;
  float adi = ad_[i];
  float m = lrelu(as_[i] + adi);    // self
  float S = 1.f;
  int b = offs[i], e = offs[i+1];
  for(int t=b; t<e; t++){
    float l = lrelu(as_[esrc[t]] + adi);
    if(l > m){ S = S*__expf(m - l) + 1.f; m = l; }
    else      S += __expf(l - m);
  }
  m_[i] = m; S_[i] = S;
}

// ---------------- GAT: weighted aggregation, bf16 rows (self-loop included) ----------------
template<int ACT>
__global__ __launch_bounds__(256) void k_gat_agg_bf256(const unsigned short* __restrict__ hP,
                                                       const float* __restrict__ as_, const float* __restrict__ ad_,
                                                       const float* __restrict__ m_, const float* __restrict__ S_,
                                                       const int* __restrict__ offs, const int* __restrict__ esrc,
                                                       const float* __restrict__ bias, float* __restrict__ out, int n){
  int wid  = (int)((blockIdx.x*256u + threadIdx.x) >> 6);
  int lane = threadIdx.x & 63;
  if(wid >= n) return;
  float adi = ad_[wid], mi = m_[wid];
  float inv = 1.f / (S_[wid] + 1e-16f);
  float w0 = __expf(lrelu(as_[wid] + adi) - mi);   // self
  u16x4 rs = *(const u16x4*)(hP + (size_t)wid*256 + 4*lane);
  float a0 = w0*bf2f(rs[0]), a1 = w0*bf2f(rs[1]), a2 = w0*bf2f(rs[2]), a3 = w0*bf2f(rs[3]);
  int e0 = offs[wid], e1 = offs[wid+1];
  int t = e0;
  for(; t+1 < e1; t += 2){
    int s0 = esrc[t], s1 = esrc[t+1];
    u16x4 r0 = *(const u16x4*)(hP + (size_t)s0*256 + 4*lane);
    u16x4 r1 = *(const u16x4*)(hP + (size_t)s1*256 + 4*lane);
    float wa = __expf(lrelu(as_[s0] + adi) - mi);
    float wb = __expf(lrelu(as_[s1] + adi) - mi);
    a0 += wa*bf2f(r0[0]) + wb*bf2f(r1[0]);
    a1 += wa*bf2f(r0[1]) + wb*bf2f(r1[1]);
    a2 += wa*bf2f(r0[2]) + wb*bf2f(r1[2]);
    a3 += wa*bf2f(r0[3]) + wb*bf2f(r1[3]);
  }
  for(; t < e1; t++){
    int s = esrc[t];
    u16x4 r = *(const u16x4*)(hP + (size_t)s*256 + 4*lane);
    float wa = __expf(lrelu(as_[s] + adi) - mi);
    a0 += wa*bf2f(r[0]); a1 += wa*bf2f(r[1]); a2 += wa*bf2f(r[2]); a3 += wa*bf2f(r[3]);
  }
  float4 b4 = *(const float4*)(bias + 4*lane);
  float4 o;
  o.x = a0*inv + b4.x; o.y = a1*inv + b4.y; o.z = a2*inv + b4.z; o.w = a3*inv + b4.w;
  if(ACT){ o.x=fmaxf(o.x,0.f); o.y=fmaxf(o.y,0.f); o.z=fmaxf(o.z,0.f); o.w=fmaxf(o.w,0.f); }
  *(float4*)(out + (size_t)wid*256 + 4*lane) = o;
}

template<int ACT>
__global__ __launch_bounds__(256) void k_gat_agg_bf128(const unsigned short* __restrict__ hP,
                                                       const float* __restrict__ as_, const float* __restrict__ ad_,
                                                       const float* __restrict__ m_, const float* __restrict__ S_,
                                                       const int* __restrict__ offs, const int* __restrict__ esrc,
                                                       const float* __restrict__ bias, float* __restrict__ out, int n){
  int wid  = (int)((blockIdx.x*256u + threadIdx.x) >> 6);
  int lane = threadIdx.x & 63;
  if(wid >= n) return;
  float adi = ad_[wid], mi = m_[wid];
  float inv = 1.f / (S_[wid] + 1e-16f);
  float w0 = __expf(lrelu(as_[wid] + adi) - mi);   // self
  u16x2 rs = *(const u16x2*)(hP + (size_t)wid*128 + 2*lane);
  float a0 = w0*bf2f(rs[0]), a1 = w0*bf2f(rs[1]);
  int e0 = offs[wid], e1 = offs[wid+1];
  int t = e0;
  for(; t+3 < e1; t += 4){
    int s0 = esrc[t], s1 = esrc[t+1], s2 = esrc[t+2], s3 = esrc[t+3];
    u16x2 r0 = *(const u16x2*)(hP + (size_t)s0*128 + 2*lane);
    u16x2 r1 = *(const u16x2*)(hP + (size_t)s1*128 + 2*lane);
    u16x2 r2 = *(const u16x2*)(hP + (size_t)s2*128 + 2*lane);
    u16x2 r3 = *(const u16x2*)(hP + (size_t)s3*128 + 2*lane);
    float wa = __expf(lrelu(as_[s0] + adi) - mi);
    float wb = __expf(lrelu(as_[s1] + adi) - mi);
    float wc = __expf(lrelu(as_[s2] + adi) - mi);
    float wd = __expf(lrelu(as_[s3] + adi) - mi);
    a0 += wa*bf2f(r0[0]) + wb*bf2f(r1[0]) + wc*bf2f(r2[0]) + wd*bf2f(r3[0]);
    a1 += wa*bf2f(r0[1]) + wb*bf2f(r1[1]) + wc*bf2f(r2[1]) + wd*bf2f(r3[1]);
  }
  for(; t < e1; t++){
    int s = esrc[t];
    u16x2 r = *(const u16x2*)(hP + (size_t)s*128 + 2*lane);
    float wa = __expf(lrelu(as_[s] + adi) - mi);
    a0 += wa*bf2f(r[0]); a1 += wa*bf2f(r[1]);
  }
  float2 b2 = *(const float2*)(bias + 2*lane);
  float2 o;
  o.x = a0*inv + b2.x; o.y = a1*inv + b2.y;
  if(ACT){ o.x=fmaxf(o.x,0.f); o.y=fmaxf(o.y,0.f); }
  *(float2*)(out + (size_t)wid*128 + 2*lane) = o;
}

extern "C" void kernel_launch(void* const* d_in, const int* in_sizes, int n_in,
                              void* d_out, int out_size, void* d_ws, size_t ws_size,
                              hipStream_t stream){
  const float* x        = (const float*)d_in[0];
  const int*   ei       = (const int*)  d_in[1];
  const float* gin1_w1  = (const float*)d_in[3];
  const float* gin1_b1  = (const float*)d_in[4];
  const float* gin1_w2  = (const float*)d_in[5];
  const float* gin1_b2  = (const float*)d_in[6];
  const float* gin2_w1  = (const float*)d_in[7];
  const float* gin2_b1  = (const float*)d_in[8];
  const float* gin2_w2  = (const float*)d_in[9];
  const float* gin2_b2  = (const float*)d_in[10];
  const float* gat1_w   = (const float*)d_in[11];
  const float* gat1_as  = (const float*)d_in[12];
  const float* gat1_ad  = (const float*)d_in[13];
  const float* gat1_b   = (const float*)d_in[14];
  const float* gat2_w   = (const float*)d_in[15];
  const float* gat2_as  = (const float*)d_in[16];
  const float* gat2_ad  = (const float*)d_in[17];
  const float* gat2_b   = (const float*)d_in[18];

  const int n = in_sizes[0] / 10;
  const int E = in_sizes[1] / 2;
  const int* src = ei;
  const int* dst = ei + E;
  const int Mc = (n + 15) / 16;

  // workspace carve (256B aligned)
  char* w = (char*)d_ws;
  auto carve = [&](size_t bytes)->char*{ char* p = w; w += (bytes + 255) & ~(size_t)255; return p; };
  int*   esrc = (int*)  carve((size_t)E*4);
  int*   offs = (int*)  carve((size_t)(n+1)*4);
  int*   deg  = (int*)  carve((size_t)n*4);
  int*   cur  = (int*)  carve((size_t)n*4);
  float* F1   = (float*)carve((size_t)n*128*4);
  float* F2   = (float*)carve((size_t)n*256*4);
  unsigned short* Hbf = (unsigned short*)carve((size_t)n*64*2);
  unsigned short* Pbf = (unsigned short*)carve((size_t)n*256*2);
  float* as_  = (float*)carve((size_t)n*4);
  float* ad_  = (float*)carve((size_t)n*4);
  float* m_   = (float*)carve((size_t)n*4);
  float* S_   = (float*)carve((size_t)n*4);
  float* waS  = (float*)carve(256*4);
  float* waD  = (float*)carve(256*4);
  unsigned short* AfH = (unsigned short*)carve((size_t)Mc*8*512*2);  // Kc<=8
  unsigned short* AfL = (unsigned short*)carve((size_t)Mc*8*512*2);
  unsigned short* BfH = (unsigned short*)carve((size_t)64*512*2);    // Nc*Kc<=64 frags
  unsigned short* BfL = (unsigned short*)carve((size_t)64*512*2);

  const int TPB = 256;
  int ebk = (E + TPB - 1) / TPB;
  int nbk = (n + TPB - 1) / TPB;
  int wbk = (n + 3) / 4;               // 4 waves per 256-thread block

  auto run_gemm = [&](const float* Afp, const float* Bfp, const float* bias,
                      float* Cf, unsigned short* Cb,
                      int K, int Nd, int act){
    int Kc = (K + 31) / 32, Nc = Nd / 16;
    int afr = Mc * Kc, bfr = Nc * Kc;
    k_prepA<<<(afr*64 + 255)/256, 256, 0, stream>>>(Afp, AfH, AfL, n, K, Mc, Kc);
    k_prepB<<<(bfr*64 + 255)/256, 256, 0, stream>>>(Bfp, BfH, BfL, K, Nd, Kc, Nc);
    dim3 g((Mc + 7)/8, Nd/64);
    if(Cb){
      if(act) k_mgemm<1,true ,true ><<<g, TPB, 0, stream>>>(AfH, AfL, BfH, BfL, bias, nullptr, Cb, n, Nd, Kc, Mc);
      else    k_mgemm<0,false,true ><<<g, TPB, 0, stream>>>(AfH, AfL, BfH, BfL, nullptr, nullptr, Cb, n, Nd, Kc, Mc);
    } else {
      if(act) k_mgemm<1,true ,false><<<g, TPB, 0, stream>>>(AfH, AfL, BfH, BfL, bias, Cf, nullptr, n, Nd, Kc, Mc);
      else    k_mgemm<0,true ,false><<<g, TPB, 0, stream>>>(AfH, AfL, BfH, BfL, bias, Cf, nullptr, n, Nd, Kc, Mc);
    }
  };

  // CSR build
  hipMemsetAsync(deg, 0, (size_t)n*4, stream);
  hipMemsetAsync(cur, 0, (size_t)n*4, stream);
  k_deg<<<ebk, TPB, 0, stream>>>(dst, deg, E);
  k_scan<<<1, 1024, 0, stream>>>(deg, offs, n);
  k_fill<<<ebk, TPB, 0, stream>>>(src, dst, offs, cur, esrc, E);

  // GIN1: agg(x) -> F1[N,10]; 10->64 relu -> F2; 64->64 +bias +relu(outer) -> Hbf (bf16 hA)
  k_agg<10><<<wbk, TPB, 0, stream>>>(x, offs, esrc, F1, n);
  run_gemm(F1, gin1_w1, gin1_b1, F2, nullptr, 10, 64, 1);
  run_gemm(F2, gin1_w2, gin1_b2, nullptr, Hbf, 64, 64, 1);

  // GIN2: agg(hA) -> F1[N,64]; 64->128 relu -> F2; 128->128 -> F1 (hB, fp32)
  k_agg_bf<64><<<wbk, TPB, 0, stream>>>(Hbf, offs, esrc, F1, n);
  run_gemm(F1, gin2_w1, gin2_b1, F2, nullptr, 64, 128, 1);
  run_gemm(F2, gin2_w2, gin2_b2, F1, nullptr, 128, 128, 0);

  // GAT1: logits via hB @ (W @ a) in fp32; proj 128->256 -> Pbf (bf16); ms; agg -> F2
  k_wa<256><<<(128+3)/4, TPB, 0, stream>>>(gat1_w, gat1_as, gat1_ad, waS, waD, 128);
  k_dotsF<128><<<wbk, TPB, 0, stream>>>(F1, waS, waD, as_, ad_, n);
  run_gemm(F1, gat1_w, nullptr, nullptr, Pbf, 128, 256, 0);
  k_ms<<<nbk, TPB, 0, stream>>>(as_, ad_, offs, esrc, m_, S_, n);
  k_gat_agg_bf256<1><<<wbk, TPB, 0, stream>>>(Pbf, as_, ad_, m_, S_, offs, esrc, gat1_b, F2, n);

  // GAT2: logits via out1 @ (W @ a) in fp32; proj 256->128 -> Pbf; ms; agg -> d_out
  k_wa<128><<<(256+3)/4, TPB, 0, stream>>>(gat2_w, gat2_as, gat2_ad, waS, waD, 256);
  k_dotsF<256><<<wbk, TPB, 0, stream>>>(F2, waS, waD, as_, ad_, n);
  run_gemm(F2, gat2_w, nullptr, nullptr, Pbf, 256, 128, 0);
  k_ms<<<nbk, TPB, 0, stream>>>(as_, ad_, offs, esrc, m_, S_, n);
  k_gat_agg_bf128<0><<<wbk, TPB, 0, stream>>>(Pbf, as_, ad_, m_, S_, offs, esrc, gat2_b, (float*)d_out, n);
}

// Round 5
// 527.338 us; speedup vs baseline: 1.9012x; 1.1526x over previous
//
#include <hip/hip_runtime.h>
#include <math.h>

__device__ __forceinline__ float lrelu(float x){ return x > 0.f ? x : 0.2f*x; }

typedef short s16x8 __attribute__((ext_vector_type(8)));
typedef float f32x4 __attribute__((ext_vector_type(4)));
typedef unsigned short u16x4 __attribute__((ext_vector_type(4)));
typedef unsigned short u16x2 __attribute__((ext_vector_type(2)));

__device__ __forceinline__ f32x4 bmma(s16x8 a, s16x8 b, f32x4 c){
  return __builtin_amdgcn_mfma_f32_16x16x32_bf16(a, b, c, 0, 0, 0);
}

__device__ __forceinline__ unsigned short f2bf(float f){
  unsigned u = __float_as_uint(f);
  unsigned r = (u + 0x7fffu + ((u >> 16) & 1u)) >> 16;
  return (unsigned short)r;
}
__device__ __forceinline__ float bf2f(unsigned short h){
  return __uint_as_float(((unsigned)h) << 16);
}

// ---------------- CSR build ----------------
__global__ void k_deg(const int* __restrict__ dst, int* __restrict__ deg, int E){
  int e = blockIdx.x*blockDim.x + threadIdx.x;
  if(e < E) atomicAdd(&deg[dst[e]], 1);
}

// 3-phase parallel exclusive scan (replaces 92us single-block k_scan)
__global__ __launch_bounds__(1024) void k_scan1(const int* __restrict__ deg,
                                                int* __restrict__ part,
                                                int* __restrict__ bsum, int n){
  int i = blockIdx.x*1024 + threadIdx.x;
  int lane = threadIdx.x & 63, wv = threadIdx.x >> 6;
  int v = (i < n) ? deg[i] : 0;
  int s = v;
  #pragma unroll
  for(int off=1; off<64; off<<=1){
    int t = __shfl_up(s, off);
    if(lane >= off) s += t;
  }
  __shared__ int wsum[16];
  if(lane==63) wsum[wv] = s;
  __syncthreads();
  if(wv==0 && lane<16){
    int t = wsum[lane], ss = t;
    #pragma unroll
    for(int off=1; off<16; off<<=1){
      int u = __shfl_up(ss, off);
      if(lane >= off) ss += u;
    }
    wsum[lane] = ss - t;                 // exclusive wave offsets
    if(lane==15) bsum[blockIdx.x] = ss;  // block total
  }
  __syncthreads();
  if(i < n) part[i] = s - v + wsum[wv];  // exclusive within block
}

__global__ __launch_bounds__(1024) void k_scan2(int* __restrict__ bsum, int nb){
  int i = threadIdx.x;
  int lane = i & 63, wv = i >> 6;
  int v = (i < nb) ? bsum[i] : 0;
  int s = v;
  #pragma unroll
  for(int off=1; off<64; off<<=1){
    int t = __shfl_up(s, off);
    if(lane >= off) s += t;
  }
  __shared__ int wsum[16];
  if(lane==63) wsum[wv] = s;
  __syncthreads();
  if(wv==0 && lane<16){
    int t = wsum[lane], ss = t;
    #pragma unroll
    for(int off=1; off<16; off<<=1){
      int u = __shfl_up(ss, off);
      if(lane >= off) ss += u;
    }
    wsum[lane] = ss - t;
  }
  __syncthreads();
  if(i < nb) bsum[i] = s - v + wsum[wv];
}

__global__ void k_scan3(const int* __restrict__ part, const int* __restrict__ bsum,
                        int* __restrict__ offs, int n, int E){
  int i = blockIdx.x*blockDim.x + threadIdx.x;
  if(i < n) offs[i] = part[i] + bsum[i >> 10];
  if(i == 0) offs[n] = E;
}

__global__ void k_fill(const int* __restrict__ src, const int* __restrict__ dst,
                       const int* __restrict__ offs, int* __restrict__ cur,
                       int* __restrict__ esrc, int E){
  int e = blockIdx.x*blockDim.x + threadIdx.x;
  if(e < E){
    int d = dst[e];
    int pos = offs[d] + atomicAdd(&cur[d], 1);
    esrc[pos] = src[e];
  }
}

// ---------------- GIN aggregation (fp32 input, layer 1 only, D=10) ----------------
template<int D>
__global__ __launch_bounds__(256) void k_agg(const float* __restrict__ xin,
                                             const int* __restrict__ offs,
                                             const int* __restrict__ esrc,
                                             float* __restrict__ out, int n){
  int wid  = (int)((blockIdx.x*256u + threadIdx.x) >> 6);
  int lane = threadIdx.x & 63;
  if(wid >= n) return;
  constexpr int NC = (D + 63) / 64;
  float acc[NC];
  #pragma unroll
  for(int j=0;j<NC;j++){ int c = lane + j*64; acc[j] = (c<D) ? xin[(size_t)wid*D + c] : 0.f; }
  int e0 = offs[wid], e1 = offs[wid+1];
  for(int t=e0; t<e1; t++){
    int s = esrc[t];
    const float* row = xin + (size_t)s*D;
    #pragma unroll
    for(int j=0;j<NC;j++){ int c = lane + j*64; if(c<D) acc[j] += row[c]; }
  }
  #pragma unroll
  for(int j=0;j<NC;j++){ int c = lane + j*64; if(c<D) out[(size_t)wid*D + c] = acc[j]; }
}

// ---------------- GIN aggregation, bf16 rows: out[i] = x[i] + sum x[j] (fp32 out) ----------------
template<int D>
__global__ __launch_bounds__(256) void k_agg_bf(const unsigned short* __restrict__ xin,
                                                const int* __restrict__ offs,
                                                const int* __restrict__ esrc,
                                                float* __restrict__ out, int n){
  int wid  = (int)((blockIdx.x*256u + threadIdx.x) >> 6);
  int lane = threadIdx.x & 63;
  if(wid >= n) return;
  static_assert(D == 64, "D=64 only");
  float acc = bf2f(xin[(size_t)wid*D + lane]);
  int e0 = offs[wid], e1 = offs[wid+1];
  int t = e0;
  for(; t+3 < e1; t += 4){
    int s0 = esrc[t], s1 = esrc[t+1], s2 = esrc[t+2], s3 = esrc[t+3];
    unsigned short v0 = xin[(size_t)s0*D + lane];
    unsigned short v1 = xin[(size_t)s1*D + lane];
    unsigned short v2 = xin[(size_t)s2*D + lane];
    unsigned short v3 = xin[(size_t)s3*D + lane];
    acc += bf2f(v0) + bf2f(v1) + bf2f(v2) + bf2f(v3);
  }
  for(; t < e1; t++) acc += bf2f(xin[(size_t)esrc[t]*D + lane]);
  out[(size_t)wid*D + lane] = acc;
}

// ---------------- split-bf16 fragment prep ----------------
__global__ __launch_bounds__(256) void k_prepA(const float* __restrict__ A,
                                               unsigned short* __restrict__ hi,
                                               unsigned short* __restrict__ lo,
                                               int M, int K, int Mc, int Kc){
  int gid = blockIdx.x*256 + threadIdx.x;
  int lane = gid & 63;
  int fid  = gid >> 6;                 // fid = mc*Kc + kc
  if(fid >= Mc*Kc) return;
  int mc = fid / Kc, kc = fid - mc*Kc;
  int row = mc*16 + (lane & 15);
  int k0  = kc*32 + (lane >> 4)*8;
  s16x8 h, l;
  if(row < M){
    const float* ap = A + (size_t)row*K + k0;
    #pragma unroll
    for(int j=0;j<8;j++){
      float v = (k0 + j < K) ? ap[j] : 0.f;
      unsigned short hb = f2bf(v);
      float r = v - bf2f(hb);
      h[j] = (short)hb; l[j] = (short)f2bf(r);
    }
  } else {
    #pragma unroll
    for(int j=0;j<8;j++){ h[j]=0; l[j]=0; }
  }
  size_t off = (size_t)fid*512 + (size_t)lane*8;
  *(s16x8*)(hi + off) = h;
  *(s16x8*)(lo + off) = l;
}

__global__ __launch_bounds__(256) void k_prepB(const float* __restrict__ B,
                                               unsigned short* __restrict__ hi,
                                               unsigned short* __restrict__ lo,
                                               int K, int Nd, int Kc, int Nc){
  int gid = blockIdx.x*256 + threadIdx.x;
  int lane = gid & 63;
  int fid  = gid >> 6;                 // fid = nc*Kc + kc
  if(fid >= Nc*Kc) return;
  int nc = fid / Kc, kc = fid - nc*Kc;
  int col = nc*16 + (lane & 15);
  int k0  = kc*32 + (lane >> 4)*8;
  s16x8 h, l;
  #pragma unroll
  for(int j=0;j<8;j++){
    int k = k0 + j;
    float v = (k < K) ? B[(size_t)k*Nd + col] : 0.f;
    unsigned short hb = f2bf(v);
    float r = v - bf2f(hb);
    h[j] = (short)hb; l[j] = (short)f2bf(r);
  }
  size_t off = (size_t)fid*512 + (size_t)lane*8;
  *(s16x8*)(hi + off) = h;
  *(s16x8*)(lo + off) = l;
}

// ---------------- split-bf16 MFMA GEMM ----------------
template<int ACT, bool HASBIAS, bool OBF>
__global__ __launch_bounds__(256) void k_mgemm(const unsigned short* __restrict__ Ahi,
                                               const unsigned short* __restrict__ Alo,
                                               const unsigned short* __restrict__ Bhi,
                                               const unsigned short* __restrict__ Blo,
                                               const float* __restrict__ bias,
                                               float* __restrict__ C,
                                               unsigned short* __restrict__ Cbf,
                                               int M, int Nd, int Kc, int Mc){
  int tid = threadIdx.x;
  int wid = tid >> 6, lane = tid & 63;
  int wm = wid >> 1, wn = wid & 1;
  int mcb = blockIdx.x*8 + wm*4;
  int ncb = blockIdx.y*4 + wn*2;

  f32x4 acc[4][2];
  #pragma unroll
  for(int f=0;f<4;f++)
    #pragma unroll
    for(int g=0;g<2;g++) acc[f][g] = (f32x4){0.f,0.f,0.f,0.f};

  for(int kc=0; kc<Kc; kc++){
    s16x8 ah[4], al[4], bh[2], bl[2];
    #pragma unroll
    for(int f=0;f<4;f++){
      int mcf = mcb + f; if(mcf > Mc-1) mcf = Mc-1;     // clamp (stores guarded by row<M)
      size_t off = ((size_t)mcf*Kc + kc)*512 + (size_t)lane*8;
      ah[f] = *(const s16x8*)(Ahi + off);
      al[f] = *(const s16x8*)(Alo + off);
    }
    #pragma unroll
    for(int g=0;g<2;g++){
      size_t off = ((size_t)(ncb+g)*Kc + kc)*512 + (size_t)lane*8;
      bh[g] = *(const s16x8*)(Bhi + off);
      bl[g] = *(const s16x8*)(Blo + off);
    }
    #pragma unroll
    for(int f=0;f<4;f++)
      #pragma unroll
      for(int g=0;g<2;g++){
        acc[f][g] = bmma(ah[f], bh[g], acc[f][g]);
        acc[f][g] = bmma(ah[f], bl[g], acc[f][g]);
        acc[f][g] = bmma(al[f], bh[g], acc[f][g]);
      }
  }

  // epilogue: C/D layout col=lane&15, row=(lane>>4)*4+reg
  #pragma unroll
  for(int g=0;g<2;g++){
    int col = (ncb+g)*16 + (lane & 15);
    float bv = HASBIAS ? bias[col] : 0.f;
    #pragma unroll
    for(int f=0;f<4;f++){
      int row0 = (mcb+f)*16 + (lane>>4)*4;
      #pragma unroll
      for(int r=0;r<4;r++){
        int row = row0 + r;
        if(row < M){
          float v = acc[f][g][r] + bv;
          if(ACT) v = fmaxf(v, 0.f);
          if(OBF) Cbf[(size_t)row*Nd + col] = f2bf(v);
          else    C  [(size_t)row*Nd + col] = v;
        }
      }
    }
  }
}

// ---------------- GAT: wa = W @ a (folded attention vectors) ----------------
template<int L>
__global__ __launch_bounds__(256) void k_wa(const float* __restrict__ W,
                                            const float* __restrict__ a_s, const float* __restrict__ a_d,
                                            float* __restrict__ wa_s, float* __restrict__ wa_d, int rows){
  int wid  = (int)((blockIdx.x*256u + threadIdx.x) >> 6);
  int lane = threadIdx.x & 63;
  if(wid >= rows) return;
  float s = 0.f, d = 0.f;
  #pragma unroll
  for(int j=0;j<L/64;j++){
    int c = lane + j*64;
    float v = W[(size_t)wid*L + c];
    s += v * a_s[c];
    d += v * a_d[c];
  }
  #pragma unroll
  for(int off=32; off; off>>=1){ s += __shfl_down(s, off); d += __shfl_down(d, off); }
  if(lane==0){ wa_s[wid] = s; wa_d[wid] = d; }
}

// ---------------- GAT: logits from fp32 GEMM input: as_[i] = F[i,:]·wa_s ----------------
template<int K>
__global__ __launch_bounds__(256) void k_dotsF(const float* __restrict__ F,
                                               const float* __restrict__ wa_s, const float* __restrict__ wa_d,
                                               float* __restrict__ as_, float* __restrict__ ad_, int n){
  int wid  = (int)((blockIdx.x*256u + threadIdx.x) >> 6);
  int lane = threadIdx.x & 63;
  if(wid >= n) return;
  float s = 0.f, d = 0.f;
  #pragma unroll
  for(int j=0;j<K/64;j++){
    int c = lane + j*64;
    float v = F[(size_t)wid*K + c];
    s += v * wa_s[c];
    d += v * wa_d[c];
  }
  #pragma unroll
  for(int off=32; off; off>>=1){ s += __shfl_down(s, off); d += __shfl_down(d, off); }
  if(lane==0){ as_[wid] = s; ad_[wid] = d; }
}

// ---------------- GAT: per-node softmax max & sum, single pass (self-loop included) ----------------
__global__ __launch_bounds__(256) void k_ms(const float* __restrict__ as_, const float* __restrict__ ad_,
                                            const int* __restrict__ offs, const int* __restrict__ esrc,
                                            float* __restrict__ m_, float* __restrict__ S_, int n){
  int i = blockIdx.x*blockDim.x + threadIdx.x;
  if(i >= n) return;
  float adi = ad_[i];
  float m = lrelu(as_[i] + adi);    // self
  float S = 1.f;
  int b = offs[i], e = offs[i+1];
  for(int t=b; t<e; t++){
    float l = lrelu(as_[esrc[t]] + adi);
    if(l > m){ S = S*__expf(m - l) + 1.f; m = l; }
    else      S += __expf(l - m);
  }
  m_[i] = m; S_[i] = S;
}

// ---------------- GAT: weighted aggregation, bf16 rows (self-loop included) ----------------
template<int ACT>
__global__ __launch_bounds__(256) void k_gat_agg_bf256(const unsigned short* __restrict__ hP,
                                                       const float* __restrict__ as_, const float* __restrict__ ad_,
                                                       const float* __restrict__ m_, const float* __restrict__ S_,
                                                       const int* __restrict__ offs, const int* __restrict__ esrc,
                                                       const float* __restrict__ bias, float* __restrict__ out, int n){
  int wid  = (int)((blockIdx.x*256u + threadIdx.x) >> 6);
  int lane = threadIdx.x & 63;
  if(wid >= n) return;
  float adi = ad_[wid], mi = m_[wid];
  float inv = 1.f / (S_[wid] + 1e-16f);
  float w0 = __expf(lrelu(as_[wid] + adi) - mi);   // self
  u16x4 rs = *(const u16x4*)(hP + (size_t)wid*256 + 4*lane);
  float a0 = w0*bf2f(rs[0]), a1 = w0*bf2f(rs[1]), a2 = w0*bf2f(rs[2]), a3 = w0*bf2f(rs[3]);
  int e0 = offs[wid], e1 = offs[wid+1];
  int t = e0;
  for(; t+1 < e1; t += 2){
    int s0 = esrc[t], s1 = esrc[t+1];
    u16x4 r0 = *(const u16x4*)(hP + (size_t)s0*256 + 4*lane);
    u16x4 r1 = *(const u16x4*)(hP + (size_t)s1*256 + 4*lane);
    float wa = __expf(lrelu(as_[s0] + adi) - mi);
    float wb = __expf(lrelu(as_[s1] + adi) - mi);
    a0 += wa*bf2f(r0[0]) + wb*bf2f(r1[0]);
    a1 += wa*bf2f(r0[1]) + wb*bf2f(r1[1]);
    a2 += wa*bf2f(r0[2]) + wb*bf2f(r1[2]);
    a3 += wa*bf2f(r0[3]) + wb*bf2f(r1[3]);
  }
  for(; t < e1; t++){
    int s = esrc[t];
    u16x4 r = *(const u16x4*)(hP + (size_t)s*256 + 4*lane);
    float wa = __expf(lrelu(as_[s] + adi) - mi);
    a0 += wa*bf2f(r[0]); a1 += wa*bf2f(r[1]); a2 += wa*bf2f(r[2]); a3 += wa*bf2f(r[3]);
  }
  float4 b4 = *(const float4*)(bias + 4*lane);
  float4 o;
  o.x = a0*inv + b4.x; o.y = a1*inv + b4.y; o.z = a2*inv + b4.z; o.w = a3*inv + b4.w;
  if(ACT){ o.x=fmaxf(o.x,0.f); o.y=fmaxf(o.y,0.f); o.z=fmaxf(o.z,0.f); o.w=fmaxf(o.w,0.f); }
  *(float4*)(out + (size_t)wid*256 + 4*lane) = o;
}

template<int ACT>
__global__ __launch_bounds__(256) void k_gat_agg_bf128(const unsigned short* __restrict__ hP,
                                                       const float* __restrict__ as_, const float* __restrict__ ad_,
                                                       const float* __restrict__ m_, const float* __restrict__ S_,
                                                       const int* __restrict__ offs, const int* __restrict__ esrc,
                                                       const float* __restrict__ bias, float* __restrict__ out, int n){
  int wid  = (int)((blockIdx.x*256u + threadIdx.x) >> 6);
  int lane = threadIdx.x & 63;
  if(wid >= n) return;
  float adi = ad_[wid], mi = m_[wid];
  float inv = 1.f / (S_[wid] + 1e-16f);
  float w0 = __expf(lrelu(as_[wid] + adi) - mi);   // self
  u16x2 rs = *(const u16x2*)(hP + (size_t)wid*128 + 2*lane);
  float a0 = w0*bf2f(rs[0]), a1 = w0*bf2f(rs[1]);
  int e0 = offs[wid], e1 = offs[wid+1];
  int t = e0;
  for(; t+3 < e1; t += 4){
    int s0 = esrc[t], s1 = esrc[t+1], s2 = esrc[t+2], s3 = esrc[t+3];
    u16x2 r0 = *(const u16x2*)(hP + (size_t)s0*128 + 2*lane);
    u16x2 r1 = *(const u16x2*)(hP + (size_t)s1*128 + 2*lane);
    u16x2 r2 = *(const u16x2*)(hP + (size_t)s2*128 + 2*lane);
    u16x2 r3 = *(const u16x2*)(hP + (size_t)s3*128 + 2*lane);
    float wa = __expf(lrelu(as_[s0] + adi) - mi);
    float wb = __expf(lrelu(as_[s1] + adi) - mi);
    float wc = __expf(lrelu(as_[s2] + adi) - mi);
    float wd = __expf(lrelu(as_[s3] + adi) - mi);
    a0 += wa*bf2f(r0[0]) + wb*bf2f(r1[0]) + wc*bf2f(r2[0]) + wd*bf2f(r3[0]);
    a1 += wa*bf2f(r0[1]) + wb*bf2f(r1[1]) + wc*bf2f(r2[1]) + wd*bf2f(r3[1]);
  }
  for(; t < e1; t++){
    int s = esrc[t];
    u16x2 r = *(const u16x2*)(hP + (size_t)s*128 + 2*lane);
    float wa = __expf(lrelu(as_[s] + adi) - mi);
    a0 += wa*bf2f(r[0]); a1 += wa*bf2f(r[1]);
  }
  float2 b2 = *(const float2*)(bias + 2*lane);
  float2 o;
  o.x = a0*inv + b2.x; o.y = a1*inv + b2.y;
  if(ACT){ o.x=fmaxf(o.x,0.f); o.y=fmaxf(o.y,0.f); }
  *(float2*)(out + (size_t)wid*128 + 2*lane) = o;
}

extern "C" void kernel_launch(void* const* d_in, const int* in_sizes, int n_in,
                              void* d_out, int out_size, void* d_ws, size_t ws_size,
                              hipStream_t stream){
  const float* x        = (const float*)d_in[0];
  const int*   ei       = (const int*)  d_in[1];
  const float* gin1_w1  = (const float*)d_in[3];
  const float* gin1_b1  = (const float*)d_in[4];
  const float* gin1_w2  = (const float*)d_in[5];
  const float* gin1_b2  = (const float*)d_in[6];
  const float* gin2_w1  = (const float*)d_in[7];
  const float* gin2_b1  = (const float*)d_in[8];
  const float* gin2_w2  = (const float*)d_in[9];
  const float* gin2_b2  = (const float*)d_in[10];
  const float* gat1_w   = (const float*)d_in[11];
  const float* gat1_as  = (const float*)d_in[12];
  const float* gat1_ad  = (const float*)d_in[13];
  const float* gat1_b   = (const float*)d_in[14];
  const float* gat2_w   = (const float*)d_in[15];
  const float* gat2_as  = (const float*)d_in[16];
  const float* gat2_ad  = (const float*)d_in[17];
  const float* gat2_b   = (const float*)d_in[18];

  const int n = in_sizes[0] / 10;
  const int E = in_sizes[1] / 2;
  const int* src = ei;
  const int* dst = ei + E;
  const int Mc = (n + 15) / 16;
  const int nb = (n + 1023) / 1024;    // scan chunks

  // workspace carve (256B aligned)
  char* w = (char*)d_ws;
  auto carve = [&](size_t bytes)->char*{ char* p = w; w += (bytes + 255) & ~(size_t)255; return p; };
  int*   esrc = (int*)  carve((size_t)E*4);
  int*   offs = (int*)  carve((size_t)(n+1)*4);
  int*   deg  = (int*)  carve((size_t)n*4);
  int*   cur  = (int*)  carve((size_t)n*4);
  int*   part = (int*)  carve((size_t)n*4);
  int*   bsum = (int*)  carve((size_t)1024*4);
  float* F1   = (float*)carve((size_t)n*128*4);
  float* F2   = (float*)carve((size_t)n*256*4);
  unsigned short* Hbf = (unsigned short*)carve((size_t)n*64*2);
  unsigned short* Pbf = (unsigned short*)carve((size_t)n*256*2);
  float* as_  = (float*)carve((size_t)n*4);
  float* ad_  = (float*)carve((size_t)n*4);
  float* m_   = (float*)carve((size_t)n*4);
  float* S_   = (float*)carve((size_t)n*4);
  float* waS  = (float*)carve(256*4);
  float* waD  = (float*)carve(256*4);
  unsigned short* AfH = (unsigned short*)carve((size_t)Mc*8*512*2);  // Kc<=8
  unsigned short* AfL = (unsigned short*)carve((size_t)Mc*8*512*2);
  unsigned short* BfH = (unsigned short*)carve((size_t)64*512*2);    // Nc*Kc<=64 frags
  unsigned short* BfL = (unsigned short*)carve((size_t)64*512*2);

  const int TPB = 256;
  int ebk = (E + TPB - 1) / TPB;
  int nbk = (n + TPB - 1) / TPB;
  int wbk = (n + 3) / 4;               // 4 waves per 256-thread block

  auto run_gemm = [&](const float* Afp, const float* Bfp, const float* bias,
                      float* Cf, unsigned short* Cb,
                      int K, int Nd, int act){
    int Kc = (K + 31) / 32, Nc = Nd / 16;
    int afr = Mc * Kc, bfr = Nc * Kc;
    k_prepA<<<(afr*64 + 255)/256, 256, 0, stream>>>(Afp, AfH, AfL, n, K, Mc, Kc);
    k_prepB<<<(bfr*64 + 255)/256, 256, 0, stream>>>(Bfp, BfH, BfL, K, Nd, Kc, Nc);
    dim3 g((Mc + 7)/8, Nd/64);
    if(Cb){
      if(act) k_mgemm<1,true ,true ><<<g, TPB, 0, stream>>>(AfH, AfL, BfH, BfL, bias, nullptr, Cb, n, Nd, Kc, Mc);
      else    k_mgemm<0,false,true ><<<g, TPB, 0, stream>>>(AfH, AfL, BfH, BfL, nullptr, nullptr, Cb, n, Nd, Kc, Mc);
    } else {
      if(act) k_mgemm<1,true ,false><<<g, TPB, 0, stream>>>(AfH, AfL, BfH, BfL, bias, Cf, nullptr, n, Nd, Kc, Mc);
      else    k_mgemm<0,true ,false><<<g, TPB, 0, stream>>>(AfH, AfL, BfH, BfL, bias, Cf, nullptr, n, Nd, Kc, Mc);
    }
  };

  // CSR build
  hipMemsetAsync(deg, 0, (size_t)n*4, stream);
  hipMemsetAsync(cur, 0, (size_t)n*4, stream);
  k_deg<<<ebk, TPB, 0, stream>>>(dst, deg, E);
  k_scan1<<<nb, 1024, 0, stream>>>(deg, part, bsum, n);
  k_scan2<<<1, 1024, 0, stream>>>(bsum, nb);
  k_scan3<<<(n + 1023)/1024, 1024, 0, stream>>>(part, bsum, offs, n, E);
  k_fill<<<ebk, TPB, 0, stream>>>(src, dst, offs, cur, esrc, E);

  // GIN1: agg(x) -> F1[N,10]; 10->64 relu -> F2; 64->64 +bias +relu(outer) -> Hbf (bf16 hA)
  k_agg<10><<<wbk, TPB, 0, stream>>>(x, offs, esrc, F1, n);
  run_gemm(F1, gin1_w1, gin1_b1, F2, nullptr, 10, 64, 1);
  run_gemm(F2, gin1_w2, gin1_b2, nullptr, Hbf, 64, 64, 1);

  // GIN2: agg(hA) -> F1[N,64]; 64->128 relu -> F2; 128->128 -> F1 (hB, fp32)
  k_agg_bf<64><<<wbk, TPB, 0, stream>>>(Hbf, offs, esrc, F1, n);
  run_gemm(F1, gin2_w1, gin2_b1, F2, nullptr, 64, 128, 1);
  run_gemm(F2, gin2_w2, gin2_b2, F1, nullptr, 128, 128, 0);

  // GAT1: logits via hB @ (W @ a) in fp32; proj 128->256 -> Pbf (bf16); ms; agg -> F2
  k_wa<256><<<(128+3)/4, TPB, 0, stream>>>(gat1_w, gat1_as, gat1_ad, waS, waD, 128);
  k_dotsF<128><<<wbk, TPB, 0, stream>>>(F1, waS, waD, as_, ad_, n);
  run_gemm(F1, gat1_w, nullptr, nullptr, Pbf, 128, 256, 0);
  k_ms<<<nbk, TPB, 0, stream>>>(as_, ad_, offs, esrc, m_, S_, n);
  k_gat_agg_bf256<1><<<wbk, TPB, 0, stream>>>(Pbf, as_, ad_, m_, S_, offs, esrc, gat1_b, F2, n);

  // GAT2: logits via out1 @ (W @ a) in fp32; proj 256->128 -> Pbf; ms; agg -> d_out
  k_wa<128><<<(256+3)/4, TPB, 0, stream>>>(gat2_w, gat2_as, gat2_ad, waS, waD, 256);
  k_dotsF<256><<<wbk, TPB, 0, stream>>>(F2, waS, waD, as_, ad_, n);
  run_gemm(F2, gat2_w, nullptr, nullptr, Pbf, 256, 128, 0);
  k_ms<<<nbk, TPB, 0, stream>>>(as_, ad_, offs, esrc, m_, S_, n);
  k_gat_agg_bf128<0><<<nbk*0 + wbk, TPB, 0, stream>>>(Pbf, as_, ad_, m_, S_, offs, esrc, gat2_b, (float*)d_out, n);
}

// Round 6
// 516.479 us; speedup vs baseline: 1.9412x; 1.0210x over previous
//
#include <hip/hip_runtime.h>
#include <math.h>

__device__ __forceinline__ float lrelu(float x){ return x > 0.f ? x : 0.2f*x; }

typedef short s16x8 __attribute__((ext_vector_type(8)));
typedef float f32x4 __attribute__((ext_vector_type(4)));
typedef unsigned short u16x8 __attribute__((ext_vector_type(8)));
typedef unsigned short u16x4 __attribute__((ext_vector_type(4)));
typedef unsigned short u16x2 __attribute__((ext_vector_type(2)));

__device__ __forceinline__ f32x4 bmma(s16x8 a, s16x8 b, f32x4 c){
  return __builtin_amdgcn_mfma_f32_16x16x32_bf16(a, b, c, 0, 0, 0);
}

__device__ __forceinline__ unsigned short f2bf(float f){
  unsigned u = __float_as_uint(f);
  unsigned r = (u + 0x7fffu + ((u >> 16) & 1u)) >> 16;
  return (unsigned short)r;
}
__device__ __forceinline__ float bf2f(unsigned short h){
  return __uint_as_float(((unsigned)h) << 16);
}

// ---------------- CSR build ----------------
__global__ void k_deg(const int* __restrict__ dst, int* __restrict__ deg, int E){
  int e = blockIdx.x*blockDim.x + threadIdx.x;
  if(e < E) atomicAdd(&deg[dst[e]], 1);
}

__global__ __launch_bounds__(1024) void k_scan1(const int* __restrict__ deg,
                                                int* __restrict__ part,
                                                int* __restrict__ bsum, int n){
  int i = blockIdx.x*1024 + threadIdx.x;
  int lane = threadIdx.x & 63, wv = threadIdx.x >> 6;
  int v = (i < n) ? deg[i] : 0;
  int s = v;
  #pragma unroll
  for(int off=1; off<64; off<<=1){
    int t = __shfl_up(s, off);
    if(lane >= off) s += t;
  }
  __shared__ int wsum[16];
  if(lane==63) wsum[wv] = s;
  __syncthreads();
  if(wv==0 && lane<16){
    int t = wsum[lane], ss = t;
    #pragma unroll
    for(int off=1; off<16; off<<=1){
      int u = __shfl_up(ss, off);
      if(lane >= off) ss += u;
    }
    wsum[lane] = ss - t;                 // exclusive wave offsets
    if(lane==15) bsum[blockIdx.x] = ss;  // block total
  }
  __syncthreads();
  if(i < n) part[i] = s - v + wsum[wv];  // exclusive within block
}

__global__ __launch_bounds__(1024) void k_scan2(int* __restrict__ bsum, int nb){
  int i = threadIdx.x;
  int lane = i & 63, wv = i >> 6;
  int v = (i < nb) ? bsum[i] : 0;
  int s = v;
  #pragma unroll
  for(int off=1; off<64; off<<=1){
    int t = __shfl_up(s, off);
    if(lane >= off) s += t;
  }
  __shared__ int wsum[16];
  if(lane==63) wsum[wv] = s;
  __syncthreads();
  if(wv==0 && lane<16){
    int t = wsum[lane], ss = t;
    #pragma unroll
    for(int off=1; off<16; off<<=1){
      int u = __shfl_up(ss, off);
      if(lane >= off) ss += u;
    }
    wsum[lane] = ss - t;
  }
  __syncthreads();
  if(i < nb) bsum[i] = s - v + wsum[wv];
}

__global__ void k_scan3(const int* __restrict__ part, const int* __restrict__ bsum,
                        int* __restrict__ offs, int n, int E){
  int i = blockIdx.x*blockDim.x + threadIdx.x;
  if(i < n) offs[i] = part[i] + bsum[i >> 10];
  if(i == 0) offs[n] = E;
}

__global__ void k_fill(const int* __restrict__ src, const int* __restrict__ dst,
                       const int* __restrict__ offs, int* __restrict__ cur,
                       int* __restrict__ esrc, int E){
  int e = blockIdx.x*blockDim.x + threadIdx.x;
  if(e < E){
    int d = dst[e];
    int pos = offs[d] + atomicAdd(&cur[d], 1);
    esrc[pos] = src[e];
  }
}

// ---------------- GIN aggregation (fp32 input, layer 1 only, D=10) ----------------
template<int D>
__global__ __launch_bounds__(256) void k_agg(const float* __restrict__ xin,
                                             const int* __restrict__ offs,
                                             const int* __restrict__ esrc,
                                             float* __restrict__ out, int n){
  int wid  = (int)((blockIdx.x*256u + threadIdx.x) >> 6);
  int lane = threadIdx.x & 63;
  if(wid >= n) return;
  constexpr int NC = (D + 63) / 64;
  float acc[NC];
  #pragma unroll
  for(int j=0;j<NC;j++){ int c = lane + j*64; acc[j] = (c<D) ? xin[(size_t)wid*D + c] : 0.f; }
  int e0 = offs[wid], e1 = offs[wid+1];
  for(int t=e0; t<e1; t++){
    int s = esrc[t];
    const float* row = xin + (size_t)s*D;
    #pragma unroll
    for(int j=0;j<NC;j++){ int c = lane + j*64; if(c<D) acc[j] += row[c]; }
  }
  #pragma unroll
  for(int j=0;j<NC;j++){ int c = lane + j*64; if(c<D) out[(size_t)wid*D + c] = acc[j]; }
}

// ---------------- GIN aggregation, bf16 rows, half-wave split (D=64) ----------------
// lanes 0-31 process even-slot edges, 32-63 odd-slot; each lane loads u16x2 (4B).
__global__ __launch_bounds__(256) void k_agg_bf64(const unsigned short* __restrict__ xin,
                                                  const int* __restrict__ offs,
                                                  const int* __restrict__ esrc,
                                                  float* __restrict__ out, int n){
  int wid  = (int)((blockIdx.x*256u + threadIdx.x) >> 6);
  int lane = threadIdx.x & 63;
  if(wid >= n) return;
  int half = lane >> 5, hl = lane & 31;
  float a0 = 0.f, a1 = 0.f;
  int e0 = offs[wid], e1 = offs[wid+1];
  int t = e0;
  for(; t+3 < e1; t += 4){
    int sA = esrc[t + half], sB = esrc[t + 2 + half];
    u16x2 rA = *(const u16x2*)(xin + (size_t)sA*64 + 2*hl);
    u16x2 rB = *(const u16x2*)(xin + (size_t)sB*64 + 2*hl);
    a0 += bf2f(rA[0]) + bf2f(rB[0]);
    a1 += bf2f(rA[1]) + bf2f(rB[1]);
  }
  for(; t < e1; t += 2){
    int idx = t + half;
    bool ok = idx < e1;
    int s = esrc[ok ? idx : e0];
    u16x2 r = *(const u16x2*)(xin + (size_t)s*64 + 2*hl);
    float w = ok ? 1.f : 0.f;
    a0 += w*bf2f(r[0]);
    a1 += w*bf2f(r[1]);
  }
  a0 += __shfl_down(a0, 32);
  a1 += __shfl_down(a1, 32);
  if(half == 0){
    u16x2 rs = *(const u16x2*)(xin + (size_t)wid*64 + 2*hl);
    float2 o;
    o.x = a0 + bf2f(rs[0]);
    o.y = a1 + bf2f(rs[1]);
    *(float2*)(out + (size_t)wid*64 + 2*hl) = o;
  }
}

// ---------------- split-bf16 fragment prep ----------------
__global__ __launch_bounds__(256) void k_prepA(const float* __restrict__ A,
                                               unsigned short* __restrict__ hi,
                                               unsigned short* __restrict__ lo,
                                               int M, int K, int Mc, int Kc){
  int gid = blockIdx.x*256 + threadIdx.x;
  int lane = gid & 63;
  int fid  = gid >> 6;                 // fid = mc*Kc + kc
  if(fid >= Mc*Kc) return;
  int mc = fid / Kc, kc = fid - mc*Kc;
  int row = mc*16 + (lane & 15);
  int k0  = kc*32 + (lane >> 4)*8;
  s16x8 h, l;
  if(row < M){
    const float* ap = A + (size_t)row*K + k0;
    #pragma unroll
    for(int j=0;j<8;j++){
      float v = (k0 + j < K) ? ap[j] : 0.f;
      unsigned short hb = f2bf(v);
      float r = v - bf2f(hb);
      h[j] = (short)hb; l[j] = (short)f2bf(r);
    }
  } else {
    #pragma unroll
    for(int j=0;j<8;j++){ h[j]=0; l[j]=0; }
  }
  size_t off = (size_t)fid*512 + (size_t)lane*8;
  *(s16x8*)(hi + off) = h;
  *(s16x8*)(lo + off) = l;
}

__global__ __launch_bounds__(256) void k_prepB(const float* __restrict__ B,
                                               unsigned short* __restrict__ hi,
                                               unsigned short* __restrict__ lo,
                                               int K, int Nd, int Kc, int Nc){
  int gid = blockIdx.x*256 + threadIdx.x;
  int lane = gid & 63;
  int fid  = gid >> 6;                 // fid = nc*Kc + kc
  if(fid >= Nc*Kc) return;
  int nc = fid / Kc, kc = fid - nc*Kc;
  int col = nc*16 + (lane & 15);
  int k0  = kc*32 + (lane >> 4)*8;
  s16x8 h, l;
  #pragma unroll
  for(int j=0;j<8;j++){
    int k = k0 + j;
    float v = (k < K) ? B[(size_t)k*Nd + col] : 0.f;
    unsigned short hb = f2bf(v);
    float r = v - bf2f(hb);
    h[j] = (short)hb; l[j] = (short)f2bf(r);
  }
  size_t off = (size_t)fid*512 + (size_t)lane*8;
  *(s16x8*)(hi + off) = h;
  *(s16x8*)(lo + off) = l;
}

// ---------------- split-bf16 MFMA GEMM ----------------
template<int ACT, bool HASBIAS, bool OBF>
__global__ __launch_bounds__(256) void k_mgemm(const unsigned short* __restrict__ Ahi,
                                               const unsigned short* __restrict__ Alo,
                                               const unsigned short* __restrict__ Bhi,
                                               const unsigned short* __restrict__ Blo,
                                               const float* __restrict__ bias,
                                               float* __restrict__ C,
                                               unsigned short* __restrict__ Cbf,
                                               int M, int Nd, int Kc, int Mc){
  int tid = threadIdx.x;
  int wid = tid >> 6, lane = tid & 63;
  int wm = wid >> 1, wn = wid & 1;
  int mcb = blockIdx.x*8 + wm*4;
  int ncb = blockIdx.y*4 + wn*2;

  f32x4 acc[4][2];
  #pragma unroll
  for(int f=0;f<4;f++)
    #pragma unroll
    for(int g=0;g<2;g++) acc[f][g] = (f32x4){0.f,0.f,0.f,0.f};

  for(int kc=0; kc<Kc; kc++){
    s16x8 ah[4], al[4], bh[2], bl[2];
    #pragma unroll
    for(int f=0;f<4;f++){
      int mcf = mcb + f; if(mcf > Mc-1) mcf = Mc-1;     // clamp (stores guarded by row<M)
      size_t off = ((size_t)mcf*Kc + kc)*512 + (size_t)lane*8;
      ah[f] = *(const s16x8*)(Ahi + off);
      al[f] = *(const s16x8*)(Alo + off);
    }
    #pragma unroll
    for(int g=0;g<2;g++){
      size_t off = ((size_t)(ncb+g)*Kc + kc)*512 + (size_t)lane*8;
      bh[g] = *(const s16x8*)(Bhi + off);
      bl[g] = *(const s16x8*)(Blo + off);
    }
    #pragma unroll
    for(int f=0;f<4;f++)
      #pragma unroll
      for(int g=0;g<2;g++){
        acc[f][g] = bmma(ah[f], bh[g], acc[f][g]);
        acc[f][g] = bmma(ah[f], bl[g], acc[f][g]);
        acc[f][g] = bmma(al[f], bh[g], acc[f][g]);
      }
  }

  // epilogue: C/D layout col=lane&15, row=(lane>>4)*4+reg
  #pragma unroll
  for(int g=0;g<2;g++){
    int col = (ncb+g)*16 + (lane & 15);
    float bv = HASBIAS ? bias[col] : 0.f;
    #pragma unroll
    for(int f=0;f<4;f++){
      int row0 = (mcb+f)*16 + (lane>>4)*4;
      #pragma unroll
      for(int r=0;r<4;r++){
        int row = row0 + r;
        if(row < M){
          float v = acc[f][g][r] + bv;
          if(ACT) v = fmaxf(v, 0.f);
          if(OBF) Cbf[(size_t)row*Nd + col] = f2bf(v);
          else    C  [(size_t)row*Nd + col] = v;
        }
      }
    }
  }
}

// ---------------- GAT: wa = W @ a (folded attention vectors) ----------------
template<int L>
__global__ __launch_bounds__(256) void k_wa(const float* __restrict__ W,
                                            const float* __restrict__ a_s, const float* __restrict__ a_d,
                                            float* __restrict__ wa_s, float* __restrict__ wa_d, int rows){
  int wid  = (int)((blockIdx.x*256u + threadIdx.x) >> 6);
  int lane = threadIdx.x & 63;
  if(wid >= rows) return;
  float s = 0.f, d = 0.f;
  #pragma unroll
  for(int j=0;j<L/64;j++){
    int c = lane + j*64;
    float v = W[(size_t)wid*L + c];
    s += v * a_s[c];
    d += v * a_d[c];
  }
  #pragma unroll
  for(int off=32; off; off>>=1){ s += __shfl_down(s, off); d += __shfl_down(d, off); }
  if(lane==0){ wa_s[wid] = s; wa_d[wid] = d; }
}

// ---------------- GAT: logits from fp32 GEMM input ----------------
template<int K>
__global__ __launch_bounds__(256) void k_dotsF(const float* __restrict__ F,
                                               const float* __restrict__ wa_s, const float* __restrict__ wa_d,
                                               float* __restrict__ as_, float* __restrict__ ad_, int n){
  int wid  = (int)((blockIdx.x*256u + threadIdx.x) >> 6);
  int lane = threadIdx.x & 63;
  if(wid >= n) return;
  float s = 0.f, d = 0.f;
  #pragma unroll
  for(int j=0;j<K/64;j++){
    int c = lane + j*64;
    float v = F[(size_t)wid*K + c];
    s += v * wa_s[c];
    d += v * wa_d[c];
  }
  #pragma unroll
  for(int off=32; off; off>>=1){ s += __shfl_down(s, off); d += __shfl_down(d, off); }
  if(lane==0){ as_[wid] = s; ad_[wid] = d; }
}

// ---------------- GAT: per-node softmax max & sum, two-pass unrolled ----------------
__global__ __launch_bounds__(256) void k_ms(const float* __restrict__ as_, const float* __restrict__ ad_,
                                            const int* __restrict__ offs, const int* __restrict__ esrc,
                                            float* __restrict__ m_, float* __restrict__ S_, int n){
  int i = blockIdx.x*blockDim.x + threadIdx.x;
  if(i >= n) return;
  float adi = ad_[i];
  float lself = lrelu(as_[i] + adi);
  int b = offs[i], e = offs[i+1];
  float m0 = lself, m1 = -1e30f, m2 = -1e30f, m3 = -1e30f;
  int t = b;
  for(; t+3 < e; t += 4){
    m0 = fmaxf(m0, lrelu(as_[esrc[t  ]] + adi));
    m1 = fmaxf(m1, lrelu(as_[esrc[t+1]] + adi));
    m2 = fmaxf(m2, lrelu(as_[esrc[t+2]] + adi));
    m3 = fmaxf(m3, lrelu(as_[esrc[t+3]] + adi));
  }
  for(; t < e; t++) m0 = fmaxf(m0, lrelu(as_[esrc[t]] + adi));
  float m = fmaxf(fmaxf(m0, m1), fmaxf(m2, m3));
  float S = __expf(lself - m);
  t = b;
  for(; t+1 < e; t += 2){
    S += __expf(lrelu(as_[esrc[t  ]] + adi) - m);
    S += __expf(lrelu(as_[esrc[t+1]] + adi) - m);
  }
  for(; t < e; t++) S += __expf(lrelu(as_[esrc[t]] + adi) - m);
  m_[i] = m; S_[i] = S;
}

// ---------------- GAT agg D=256, half-wave split, u16x8 (16B) per lane ----------------
template<int ACT>
__global__ __launch_bounds__(256) void k_gat_agg_bf256(const unsigned short* __restrict__ hP,
                                                       const float* __restrict__ as_, const float* __restrict__ ad_,
                                                       const float* __restrict__ m_, const float* __restrict__ S_,
                                                       const int* __restrict__ offs, const int* __restrict__ esrc,
                                                       const float* __restrict__ bias, float* __restrict__ out, int n){
  int wid  = (int)((blockIdx.x*256u + threadIdx.x) >> 6);
  int lane = threadIdx.x & 63;
  if(wid >= n) return;
  int half = lane >> 5, hl = lane & 31;
  float adi = ad_[wid], mi = m_[wid];
  float inv = 1.f / (S_[wid] + 1e-16f);
  float acc[8];
  #pragma unroll
  for(int k=0;k<8;k++) acc[k] = 0.f;
  int e0 = offs[wid], e1 = offs[wid+1];
  int t = e0;
  for(; t+3 < e1; t += 4){
    int sA = esrc[t + half], sB = esrc[t + 2 + half];
    u16x8 rA = *(const u16x8*)(hP + (size_t)sA*256 + 8*hl);
    u16x8 rB = *(const u16x8*)(hP + (size_t)sB*256 + 8*hl);
    float wA = __expf(lrelu(as_[sA] + adi) - mi);
    float wB = __expf(lrelu(as_[sB] + adi) - mi);
    #pragma unroll
    for(int k=0;k<8;k++) acc[k] += wA*bf2f(rA[k]) + wB*bf2f(rB[k]);
  }
  for(; t < e1; t += 2){
    int idx = t + half;
    bool ok = idx < e1;
    int s = esrc[ok ? idx : e0];
    u16x8 r = *(const u16x8*)(hP + (size_t)s*256 + 8*hl);
    float w = ok ? __expf(lrelu(as_[s] + adi) - mi) : 0.f;
    #pragma unroll
    for(int k=0;k<8;k++) acc[k] += w*bf2f(r[k]);
  }
  #pragma unroll
  for(int k=0;k<8;k++) acc[k] += __shfl_down(acc[k], 32);
  if(half == 0){
    float w0 = __expf(lrelu(as_[wid] + adi) - mi);   // self loop
    u16x8 rs = *(const u16x8*)(hP + (size_t)wid*256 + 8*hl);
    float4 b0 = *(const float4*)(bias + 8*hl);
    float4 b1 = *(const float4*)(bias + 8*hl + 4);
    float4 o0, o1;
    o0.x = (acc[0] + w0*bf2f(rs[0]))*inv + b0.x;
    o0.y = (acc[1] + w0*bf2f(rs[1]))*inv + b0.y;
    o0.z = (acc[2] + w0*bf2f(rs[2]))*inv + b0.z;
    o0.w = (acc[3] + w0*bf2f(rs[3]))*inv + b0.w;
    o1.x = (acc[4] + w0*bf2f(rs[4]))*inv + b1.x;
    o1.y = (acc[5] + w0*bf2f(rs[5]))*inv + b1.y;
    o1.z = (acc[6] + w0*bf2f(rs[6]))*inv + b1.z;
    o1.w = (acc[7] + w0*bf2f(rs[7]))*inv + b1.w;
    if(ACT){
      o0.x=fmaxf(o0.x,0.f); o0.y=fmaxf(o0.y,0.f); o0.z=fmaxf(o0.z,0.f); o0.w=fmaxf(o0.w,0.f);
      o1.x=fmaxf(o1.x,0.f); o1.y=fmaxf(o1.y,0.f); o1.z=fmaxf(o1.z,0.f); o1.w=fmaxf(o1.w,0.f);
    }
    *(float4*)(out + (size_t)wid*256 + 8*hl)     = o0;
    *(float4*)(out + (size_t)wid*256 + 8*hl + 4) = o1;
  }
}

// ---------------- GAT agg D=128, half-wave split, u16x4 (8B) per lane ----------------
template<int ACT>
__global__ __launch_bounds__(256) void k_gat_agg_bf128(const unsigned short* __restrict__ hP,
                                                       const float* __restrict__ as_, const float* __restrict__ ad_,
                                                       const float* __restrict__ m_, const float* __restrict__ S_,
                                                       const int* __restrict__ offs, const int* __restrict__ esrc,
                                                       const float* __restrict__ bias, float* __restrict__ out, int n){
  int wid  = (int)((blockIdx.x*256u + threadIdx.x) >> 6);
  int lane = threadIdx.x & 63;
  if(wid >= n) return;
  int half = lane >> 5, hl = lane & 31;
  float adi = ad_[wid], mi = m_[wid];
  float inv = 1.f / (S_[wid] + 1e-16f);
  float acc[4];
  #pragma unroll
  for(int k=0;k<4;k++) acc[k] = 0.f;
  int e0 = offs[wid], e1 = offs[wid+1];
  int t = e0;
  for(; t+3 < e1; t += 4){
    int sA = esrc[t + half], sB = esrc[t + 2 + half];
    u16x4 rA = *(const u16x4*)(hP + (size_t)sA*128 + 4*hl);
    u16x4 rB = *(const u16x4*)(hP + (size_t)sB*128 + 4*hl);
    float wA = __expf(lrelu(as_[sA] + adi) - mi);
    float wB = __expf(lrelu(as_[sB] + adi) - mi);
    #pragma unroll
    for(int k=0;k<4;k++) acc[k] += wA*bf2f(rA[k]) + wB*bf2f(rB[k]);
  }
  for(; t < e1; t += 2){
    int idx = t + half;
    bool ok = idx < e1;
    int s = esrc[ok ? idx : e0];
    u16x4 r = *(const u16x4*)(hP + (size_t)s*128 + 4*hl);
    float w = ok ? __expf(lrelu(as_[s] + adi) - mi) : 0.f;
    #pragma unroll
    for(int k=0;k<4;k++) acc[k] += w*bf2f(r[k]);
  }
  #pragma unroll
  for(int k=0;k<4;k++) acc[k] += __shfl_down(acc[k], 32);
  if(half == 0){
    float w0 = __expf(lrelu(as_[wid] + adi) - mi);   // self loop
    u16x4 rs = *(const u16x4*)(hP + (size_t)wid*128 + 4*hl);
    float4 b4 = *(const float4*)(bias + 4*hl);
    float4 o;
    o.x = (acc[0] + w0*bf2f(rs[0]))*inv + b4.x;
    o.y = (acc[1] + w0*bf2f(rs[1]))*inv + b4.y;
    o.z = (acc[2] + w0*bf2f(rs[2]))*inv + b4.z;
    o.w = (acc[3] + w0*bf2f(rs[3]))*inv + b4.w;
    if(ACT){ o.x=fmaxf(o.x,0.f); o.y=fmaxf(o.y,0.f); o.z=fmaxf(o.z,0.f); o.w=fmaxf(o.w,0.f); }
    *(float4*)(out + (size_t)wid*128 + 4*hl) = o;
  }
}

extern "C" void kernel_launch(void* const* d_in, const int* in_sizes, int n_in,
                              void* d_out, int out_size, void* d_ws, size_t ws_size,
                              hipStream_t stream){
  const float* x        = (const float*)d_in[0];
  const int*   ei       = (const int*)  d_in[1];
  const float* gin1_w1  = (const float*)d_in[3];
  const float* gin1_b1  = (const float*)d_in[4];
  const float* gin1_w2  = (const float*)d_in[5];
  const float* gin1_b2  = (const float*)d_in[6];
  const float* gin2_w1  = (const float*)d_in[7];
  const float* gin2_b1  = (const float*)d_in[8];
  const float* gin2_w2  = (const float*)d_in[9];
  const float* gin2_b2  = (const float*)d_in[10];
  const float* gat1_w   = (const float*)d_in[11];
  const float* gat1_as  = (const float*)d_in[12];
  const float* gat1_ad  = (const float*)d_in[13];
  const float* gat1_b   = (const float*)d_in[14];
  const float* gat2_w   = (const float*)d_in[15];
  const float* gat2_as  = (const float*)d_in[16];
  const float* gat2_ad  = (const float*)d_in[17];
  const float* gat2_b   = (const float*)d_in[18];

  const int n = in_sizes[0] / 10;
  const int E = in_sizes[1] / 2;
  const int* src = ei;
  const int* dst = ei + E;
  const int Mc = (n + 15) / 16;
  const int nb = (n + 1023) / 1024;    // scan chunks

  // workspace carve (256B aligned)
  char* w = (char*)d_ws;
  auto carve = [&](size_t bytes)->char*{ char* p = w; w += (bytes + 255) & ~(size_t)255; return p; };
  int*   esrc = (int*)  carve((size_t)E*4);
  int*   offs = (int*)  carve((size_t)(n+1)*4);
  int*   deg  = (int*)  carve((size_t)n*4);
  int*   cur  = (int*)  carve((size_t)n*4);
  int*   part = (int*)  carve((size_t)n*4);
  int*   bsum = (int*)  carve((size_t)1024*4);
  float* F1   = (float*)carve((size_t)n*128*4);
  float* F2   = (float*)carve((size_t)n*256*4);
  unsigned short* Hbf = (unsigned short*)carve((size_t)n*64*2);
  unsigned short* Pbf = (unsigned short*)carve((size_t)n*256*2);
  float* as_  = (float*)carve((size_t)n*4);
  float* ad_  = (float*)carve((size_t)n*4);
  float* m_   = (float*)carve((size_t)n*4);
  float* S_   = (float*)carve((size_t)n*4);
  float* waS  = (float*)carve(256*4);
  float* waD  = (float*)carve(256*4);
  unsigned short* AfH = (unsigned short*)carve((size_t)Mc*8*512*2);  // Kc<=8
  unsigned short* AfL = (unsigned short*)carve((size_t)Mc*8*512*2);
  unsigned short* BfH = (unsigned short*)carve((size_t)64*512*2);    // Nc*Kc<=64 frags
  unsigned short* BfL = (unsigned short*)carve((size_t)64*512*2);

  const int TPB = 256;
  int ebk = (E + TPB - 1) / TPB;
  int nbk = (n + TPB - 1) / TPB;
  int wbk = (n + 3) / 4;               // 4 waves per 256-thread block

  auto run_gemm = [&](const float* Afp, const float* Bfp, const float* bias,
                      float* Cf, unsigned short* Cb,
                      int K, int Nd, int act){
    int Kc = (K + 31) / 32, Nc = Nd / 16;
    int afr = Mc * Kc, bfr = Nc * Kc;
    k_prepA<<<(afr*64 + 255)/256, 256, 0, stream>>>(Afp, AfH, AfL, n, K, Mc, Kc);
    k_prepB<<<(bfr*64 + 255)/256, 256, 0, stream>>>(Bfp, BfH, BfL, K, Nd, Kc, Nc);
    dim3 g((Mc + 7)/8, Nd/64);
    if(Cb){
      if(act) k_mgemm<1,true ,true ><<<g, TPB, 0, stream>>>(AfH, AfL, BfH, BfL, bias, nullptr, Cb, n, Nd, Kc, Mc);
      else    k_mgemm<0,false,true ><<<g, TPB, 0, stream>>>(AfH, AfL, BfH, BfL, nullptr, nullptr, Cb, n, Nd, Kc, Mc);
    } else {
      if(act) k_mgemm<1,true ,false><<<g, TPB, 0, stream>>>(AfH, AfL, BfH, BfL, bias, Cf, nullptr, n, Nd, Kc, Mc);
      else    k_mgemm<0,true ,false><<<g, TPB, 0, stream>>>(AfH, AfL, BfH, BfL, bias, Cf, nullptr, n, Nd, Kc, Mc);
    }
  };

  // CSR build
  hipMemsetAsync(deg, 0, (size_t)n*4, stream);
  hipMemsetAsync(cur, 0, (size_t)n*4, stream);
  k_deg<<<ebk, TPB, 0, stream>>>(dst, deg, E);
  k_scan1<<<nb, 1024, 0, stream>>>(deg, part, bsum, n);
  k_scan2<<<1, 1024, 0, stream>>>(bsum, nb);
  k_scan3<<<(n + 1023)/1024, 1024, 0, stream>>>(part, bsum, offs, n, E);
  k_fill<<<ebk, TPB, 0, stream>>>(src, dst, offs, cur, esrc, E);

  // GIN1: agg(x) -> F1[N,10]; 10->64 relu -> F2; 64->64 +bias +relu(outer) -> Hbf (bf16 hA)
  k_agg<10><<<wbk, TPB, 0, stream>>>(x, offs, esrc, F1, n);
  run_gemm(F1, gin1_w1, gin1_b1, F2, nullptr, 10, 64, 1);
  run_gemm(F2, gin1_w2, gin1_b2, nullptr, Hbf, 64, 64, 1);

  // GIN2: agg(hA) -> F1[N,64]; 64->128 relu -> F2; 128->128 -> F1 (hB, fp32)
  k_agg_bf64<<<wbk, TPB, 0, stream>>>(Hbf, offs, esrc, F1, n);
  run_gemm(F1, gin2_w1, gin2_b1, F2, nullptr, 64, 128, 1);
  run_gemm(F2, gin2_w2, gin2_b2, F1, nullptr, 128, 128, 0);

  // GAT1: logits via hB @ (W @ a) in fp32; proj 128->256 -> Pbf (bf16); ms; agg -> F2
  k_wa<256><<<(128+3)/4, TPB, 0, stream>>>(gat1_w, gat1_as, gat1_ad, waS, waD, 128);
  k_dotsF<128><<<wbk, TPB, 0, stream>>>(F1, waS, waD, as_, ad_, n);
  run_gemm(F1, gat1_w, nullptr, nullptr, Pbf, 128, 256, 0);
  k_ms<<<nbk, TPB, 0, stream>>>(as_, ad_, offs, esrc, m_, S_, n);
  k_gat_agg_bf256<1><<<wbk, TPB, 0, stream>>>(Pbf, as_, ad_, m_, S_, offs, esrc, gat1_b, F2, n);

  // GAT2: logits via out1 @ (W @ a) in fp32; proj 256->128 -> Pbf; ms; agg -> d_out
  k_wa<128><<<(256+3)/4, TPB, 0, stream>>>(gat2_w, gat2_as, gat2_ad, waS, waD, 256);
  k_dotsF<256><<<wbk, TPB, 0, stream>>>(F2, waS, waD, as_, ad_, n);
  run_gemm(F2, gat2_w, nullptr, nullptr, Pbf, 256, 128, 0);
  k_ms<<<nbk, TPB, 0, stream>>>(as_, ad_, offs, esrc, m_, S_, n);
  k_gat_agg_bf128<0><<<wbk, TPB, 0, stream>>>(Pbf, as_, ad_, m_, S_, offs, esrc, gat2_b, (float*)d_out, n);
}

// Round 7
// 448.205 us; speedup vs baseline: 2.2368x; 1.1523x over previous
//
#include <hip/hip_runtime.h>
#include <math.h>

__device__ __forceinline__ float lrelu(float x){ return x > 0.f ? x : 0.2f*x; }

typedef short s16x8 __attribute__((ext_vector_type(8)));
typedef float f32x4 __attribute__((ext_vector_type(4)));
typedef unsigned short u16x8 __attribute__((ext_vector_type(8)));

__device__ __forceinline__ f32x4 bmma(s16x8 a, s16x8 b, f32x4 c){
  return __builtin_amdgcn_mfma_f32_16x16x32_bf16(a, b, c, 0, 0, 0);
}

__device__ __forceinline__ unsigned short f2bf(float f){
  unsigned u = __float_as_uint(f);
  unsigned r = (u + 0x7fffu + ((u >> 16) & 1u)) >> 16;
  return (unsigned short)r;
}
__device__ __forceinline__ float bf2f(unsigned short h){
  return __uint_as_float(((unsigned)h) << 16);
}

// ---------------- CSR build ----------------
__global__ void k_deg(const int* __restrict__ dst, int* __restrict__ deg, int E){
  int e = blockIdx.x*blockDim.x + threadIdx.x;
  if(e < E) atomicAdd(&deg[dst[e]], 1);
}

__global__ __launch_bounds__(1024) void k_scan1(const int* __restrict__ deg,
                                                int* __restrict__ part,
                                                int* __restrict__ bsum, int n){
  int i = blockIdx.x*1024 + threadIdx.x;
  int lane = threadIdx.x & 63, wv = threadIdx.x >> 6;
  int v = (i < n) ? deg[i] : 0;
  int s = v;
  #pragma unroll
  for(int off=1; off<64; off<<=1){
    int t = __shfl_up(s, off);
    if(lane >= off) s += t;
  }
  __shared__ int wsum[16];
  if(lane==63) wsum[wv] = s;
  __syncthreads();
  if(wv==0 && lane<16){
    int t = wsum[lane], ss = t;
    #pragma unroll
    for(int off=1; off<16; off<<=1){
      int u = __shfl_up(ss, off);
      if(lane >= off) ss += u;
    }
    wsum[lane] = ss - t;
    if(lane==15) bsum[blockIdx.x] = ss;
  }
  __syncthreads();
  if(i < n) part[i] = s - v + wsum[wv];
}

__global__ __launch_bounds__(1024) void k_scan2(int* __restrict__ bsum, int nb){
  int i = threadIdx.x;
  int lane = i & 63, wv = i >> 6;
  int v = (i < nb) ? bsum[i] : 0;
  int s = v;
  #pragma unroll
  for(int off=1; off<64; off<<=1){
    int t = __shfl_up(s, off);
    if(lane >= off) s += t;
  }
  __shared__ int wsum[16];
  if(lane==63) wsum[wv] = s;
  __syncthreads();
  if(wv==0 && lane<16){
    int t = wsum[lane], ss = t;
    #pragma unroll
    for(int off=1; off<16; off<<=1){
      int u = __shfl_up(ss, off);
      if(lane >= off) ss += u;
    }
    wsum[lane] = ss - t;
  }
  __syncthreads();
  if(i < nb) bsum[i] = s - v + wsum[wv];
}

__global__ void k_scan3(const int* __restrict__ part, const int* __restrict__ bsum,
                        int* __restrict__ offs, int n, int E){
  int i = blockIdx.x*blockDim.x + threadIdx.x;
  if(i < n) offs[i] = part[i] + bsum[i >> 10];
  if(i == 0) offs[n] = E;
}

__global__ void k_fill(const int* __restrict__ src, const int* __restrict__ dst,
                       const int* __restrict__ offs, int* __restrict__ cur,
                       int* __restrict__ esrc, int E){
  int e = blockIdx.x*blockDim.x + threadIdx.x;
  if(e < E){
    int d = dst[e];
    int pos = offs[d] + atomicAdd(&cur[d], 1);
    esrc[pos] = src[e];
  }
}

// ---------------- GIN1 aggregation (fp32, D=10) ----------------
template<int D>
__global__ __launch_bounds__(256) void k_agg(const float* __restrict__ xin,
                                             const int* __restrict__ offs,
                                             const int* __restrict__ esrc,
                                             float* __restrict__ out, int n){
  int wid  = (int)((blockIdx.x*256u + threadIdx.x) >> 6);
  int lane = threadIdx.x & 63;
  if(wid >= n) return;
  constexpr int NC = (D + 63) / 64;
  float acc[NC];
  #pragma unroll
  for(int j=0;j<NC;j++){ int c = lane + j*64; acc[j] = (c<D) ? xin[(size_t)wid*D + c] : 0.f; }
  int e0 = offs[wid], e1 = offs[wid+1];
  for(int t=e0; t<e1; t++){
    int s = esrc[t];
    const float* row = xin + (size_t)s*D;
    #pragma unroll
    for(int j=0;j<NC;j++){ int c = lane + j*64; if(c<D) acc[j] += row[c]; }
  }
  #pragma unroll
  for(int j=0;j<NC;j++){ int c = lane + j*64; if(c<D) out[(size_t)wid*D + c] = acc[j]; }
}

// ---------------- GIN2 agg: bf16 rows D=64, eighth-wave split, frag-epilogue ----------------
__global__ __launch_bounds__(256) void k_gin2_agg(const unsigned short* __restrict__ xin,
                                                  const int* __restrict__ offs,
                                                  const int* __restrict__ esrc,
                                                  unsigned short* __restrict__ fhi,
                                                  unsigned short* __restrict__ flo, int n){
  int wid  = (int)((blockIdx.x*256u + threadIdx.x) >> 6);
  int lane = threadIdx.x & 63;
  if(wid >= n) return;
  int g = lane >> 3, sub = lane & 7;   // 8 groups x 8 lanes; 8 edges in flight
  float acc[8];
  #pragma unroll
  for(int k=0;k<8;k++) acc[k] = 0.f;
  int e0 = offs[wid], e1 = offs[wid+1];
  int t = e0;
  for(; t+7 < e1; t += 8){
    int s = esrc[t + g];
    u16x8 r = *(const u16x8*)(xin + (size_t)s*64 + 8*sub);
    #pragma unroll
    for(int k=0;k<8;k++) acc[k] += bf2f(r[k]);
  }
  if(t < e1){
    int idx = t + g;
    bool ok = idx < e1;
    int s = esrc[ok ? idx : e0];
    u16x8 r = *(const u16x8*)(xin + (size_t)s*64 + 8*sub);
    float w = ok ? 1.f : 0.f;
    #pragma unroll
    for(int k=0;k<8;k++) acc[k] += w*bf2f(r[k]);
  }
  #pragma unroll
  for(int off=32; off>=8; off>>=1)
    #pragma unroll
    for(int k=0;k<8;k++) acc[k] += __shfl_down(acc[k], off);
  if(lane < 8){
    u16x8 rs = *(const u16x8*)(xin + (size_t)wid*64 + 8*sub);
    u16x8 h, l;
    #pragma unroll
    for(int k=0;k<8;k++){
      float o = acc[k] + bf2f(rs[k]);
      unsigned short hb = f2bf(o);
      h[k] = hb; l[k] = f2bf(o - bf2f(hb));
    }
    int mc = wid >> 4;
    size_t base = ((size_t)(mc*2 + (sub>>2))*64 + (wid & 15) + (sub & 3)*16) * 8;
    *(u16x8*)(fhi + base) = h;
    *(u16x8*)(flo + base) = l;
  }
}

// ---------------- split-bf16 fragment prep ----------------
__global__ __launch_bounds__(256) void k_prepA(const float* __restrict__ A,
                                               unsigned short* __restrict__ hi,
                                               unsigned short* __restrict__ lo,
                                               int M, int K, int Mc, int Kc){
  int gid = blockIdx.x*256 + threadIdx.x;
  int lane = gid & 63;
  int fid  = gid >> 6;
  if(fid >= Mc*Kc) return;
  int mc = fid / Kc, kc = fid - mc*Kc;
  int row = mc*16 + (lane & 15);
  int k0  = kc*32 + (lane >> 4)*8;
  s16x8 h, l;
  if(row < M){
    const float* ap = A + (size_t)row*K + k0;
    #pragma unroll
    for(int j=0;j<8;j++){
      float v = (k0 + j < K) ? ap[j] : 0.f;
      unsigned short hb = f2bf(v);
      float r = v - bf2f(hb);
      h[j] = (short)hb; l[j] = (short)f2bf(r);
    }
  } else {
    #pragma unroll
    for(int j=0;j<8;j++){ h[j]=0; l[j]=0; }
  }
  size_t off = (size_t)fid*512 + (size_t)lane*8;
  *(s16x8*)(hi + off) = h;
  *(s16x8*)(lo + off) = l;
}

__global__ __launch_bounds__(256) void k_prepB(const float* __restrict__ B,
                                               unsigned short* __restrict__ hi,
                                               unsigned short* __restrict__ lo,
                                               int K, int Nd, int Kc, int Nc){
  int gid = blockIdx.x*256 + threadIdx.x;
  int lane = gid & 63;
  int fid  = gid >> 6;
  if(fid >= Nc*Kc) return;
  int nc = fid / Kc, kc = fid - nc*Kc;
  int col = nc*16 + (lane & 15);
  int k0  = kc*32 + (lane >> 4)*8;
  s16x8 h, l;
  #pragma unroll
  for(int j=0;j<8;j++){
    int k = k0 + j;
    float v = (k < K) ? B[(size_t)k*Nd + col] : 0.f;
    unsigned short hb = f2bf(v);
    float r = v - bf2f(hb);
    h[j] = (short)hb; l[j] = (short)f2bf(r);
  }
  size_t off = (size_t)fid*512 + (size_t)lane*8;
  *(s16x8*)(hi + off) = h;
  *(s16x8*)(lo + off) = l;
}

// ---------------- split-bf16 MFMA GEMM ----------------
template<int ACT, bool HASBIAS, bool OBF>
__global__ __launch_bounds__(256) void k_mgemm(const unsigned short* __restrict__ Ahi,
                                               const unsigned short* __restrict__ Alo,
                                               const unsigned short* __restrict__ Bhi,
                                               const unsigned short* __restrict__ Blo,
                                               const float* __restrict__ bias,
                                               float* __restrict__ C,
                                               unsigned short* __restrict__ Cbf,
                                               int M, int Nd, int Kc, int Mc){
  int tid = threadIdx.x;
  int wid = tid >> 6, lane = tid & 63;
  int wm = wid >> 1, wn = wid & 1;
  int mcb = blockIdx.x*8 + wm*4;
  int ncb = blockIdx.y*4 + wn*2;

  f32x4 acc[4][2];
  #pragma unroll
  for(int f=0;f<4;f++)
    #pragma unroll
    for(int g=0;g<2;g++) acc[f][g] = (f32x4){0.f,0.f,0.f,0.f};

  for(int kc=0; kc<Kc; kc++){
    s16x8 ah[4], al[4], bh[2], bl[2];
    #pragma unroll
    for(int f=0;f<4;f++){
      int mcf = mcb + f; if(mcf > Mc-1) mcf = Mc-1;
      size_t off = ((size_t)mcf*Kc + kc)*512 + (size_t)lane*8;
      ah[f] = *(const s16x8*)(Ahi + off);
      al[f] = *(const s16x8*)(Alo + off);
    }
    #pragma unroll
    for(int g=0;g<2;g++){
      size_t off = ((size_t)(ncb+g)*Kc + kc)*512 + (size_t)lane*8;
      bh[g] = *(const s16x8*)(Bhi + off);
      bl[g] = *(const s16x8*)(Blo + off);
    }
    #pragma unroll
    for(int f=0;f<4;f++)
      #pragma unroll
      for(int g=0;g<2;g++){
        acc[f][g] = bmma(ah[f], bh[g], acc[f][g]);
        acc[f][g] = bmma(ah[f], bl[g], acc[f][g]);
        acc[f][g] = bmma(al[f], bh[g], acc[f][g]);
      }
  }

  #pragma unroll
  for(int g=0;g<2;g++){
    int col = (ncb+g)*16 + (lane & 15);
    float bv = HASBIAS ? bias[col] : 0.f;
    #pragma unroll
    for(int f=0;f<4;f++){
      int row0 = (mcb+f)*16 + (lane>>4)*4;
      #pragma unroll
      for(int r=0;r<4;r++){
        int row = row0 + r;
        if(row < M){
          float v = acc[f][g][r] + bv;
          if(ACT) v = fmaxf(v, 0.f);
          if(OBF) Cbf[(size_t)row*Nd + col] = f2bf(v);
          else    C  [(size_t)row*Nd + col] = v;
        }
      }
    }
  }
}

// ---------------- GAT: wa = W @ a ----------------
template<int L>
__global__ __launch_bounds__(256) void k_wa(const float* __restrict__ W,
                                            const float* __restrict__ a_s, const float* __restrict__ a_d,
                                            float* __restrict__ wa_s, float* __restrict__ wa_d, int rows){
  int wid  = (int)((blockIdx.x*256u + threadIdx.x) >> 6);
  int lane = threadIdx.x & 63;
  if(wid >= rows) return;
  float s = 0.f, d = 0.f;
  #pragma unroll
  for(int j=0;j<L/64;j++){
    int c = lane + j*64;
    float v = W[(size_t)wid*L + c];
    s += v * a_s[c];
    d += v * a_d[c];
  }
  #pragma unroll
  for(int off=32; off; off>>=1){ s += __shfl_down(s, off); d += __shfl_down(d, off); }
  if(lane==0){ wa_s[wid] = s; wa_d[wid] = d; }
}

// ---------------- GAT1 logits from fp32 hB ----------------
template<int K>
__global__ __launch_bounds__(256) void k_dotsF(const float* __restrict__ F,
                                               const float* __restrict__ wa_s, const float* __restrict__ wa_d,
                                               float* __restrict__ as_, float* __restrict__ ad_, int n){
  int wid  = (int)((blockIdx.x*256u + threadIdx.x) >> 6);
  int lane = threadIdx.x & 63;
  if(wid >= n) return;
  float s = 0.f, d = 0.f;
  #pragma unroll
  for(int j=0;j<K/64;j++){
    int c = lane + j*64;
    float v = F[(size_t)wid*K + c];
    s += v * wa_s[c];
    d += v * wa_d[c];
  }
  #pragma unroll
  for(int off=32; off; off>>=1){ s += __shfl_down(s, off); d += __shfl_down(d, off); }
  if(lane==0){ as_[wid] = s; ad_[wid] = d; }
}

// ---------------- GAT1 agg: D=256, half-wave, online softmax, frag+logit epilogue ----------------
__global__ __launch_bounds__(256) void k_gat1_agg(const unsigned short* __restrict__ hP,
                                                  const float* __restrict__ as_, const float* __restrict__ ad_,
                                                  const int* __restrict__ offs, const int* __restrict__ esrc,
                                                  const float* __restrict__ bias,
                                                  const float* __restrict__ waS2, const float* __restrict__ waD2,
                                                  unsigned short* __restrict__ fhi, unsigned short* __restrict__ flo,
                                                  float* __restrict__ as2, float* __restrict__ ad2, int n){
  int wid  = (int)((blockIdx.x*256u + threadIdx.x) >> 6);
  int lane = threadIdx.x & 63;
  if(wid >= n) return;
  int half = lane >> 5, hl = lane & 31;
  float adi = ad_[wid];
  u16x8 rs = *(const u16x8*)(hP + (size_t)wid*256 + 8*hl);
  float m, S, acc[8];
  if(half == 0){
    m = lrelu(as_[wid] + adi); S = 1.f;
    #pragma unroll
    for(int k=0;k<8;k++) acc[k] = bf2f(rs[k]);
  } else {
    m = -3e38f; S = 0.f;
    #pragma unroll
    for(int k=0;k<8;k++) acc[k] = 0.f;
  }
  int e0 = offs[wid], e1 = offs[wid+1];
  int t = e0;
  for(; t+7 < e1; t += 8){
    int s0 = esrc[t + half], s1 = esrc[t+2+half], s2 = esrc[t+4+half], s3 = esrc[t+6+half];
    u16x8 r0 = *(const u16x8*)(hP + (size_t)s0*256 + 8*hl);
    u16x8 r1 = *(const u16x8*)(hP + (size_t)s1*256 + 8*hl);
    u16x8 r2 = *(const u16x8*)(hP + (size_t)s2*256 + 8*hl);
    u16x8 r3 = *(const u16x8*)(hP + (size_t)s3*256 + 8*hl);
    float l0 = lrelu(as_[s0] + adi), l1 = lrelu(as_[s1] + adi);
    float l2 = lrelu(as_[s2] + adi), l3 = lrelu(as_[s3] + adi);
    float lm = fmaxf(fmaxf(l0,l1), fmaxf(l2,l3));
    if(lm > m + 8.f){
      float sc = __expf(m - lm); S *= sc;
      #pragma unroll
      for(int k=0;k<8;k++) acc[k] *= sc;
      m = lm;
    }
    float w0 = __expf(l0 - m), w1 = __expf(l1 - m), w2 = __expf(l2 - m), w3 = __expf(l3 - m);
    S += w0 + w1 + w2 + w3;
    #pragma unroll
    for(int k=0;k<8;k++)
      acc[k] += w0*bf2f(r0[k]) + w1*bf2f(r1[k]) + w2*bf2f(r2[k]) + w3*bf2f(r3[k]);
  }
  while(t < e1){
    int idx = t + half;
    bool ok = idx < e1;
    int s = esrc[ok ? idx : e0];
    u16x8 r = *(const u16x8*)(hP + (size_t)s*256 + 8*hl);
    float l = ok ? lrelu(as_[s] + adi) : -3e38f;
    if(l > m + 8.f){
      float sc = __expf(m - l); S *= sc;
      #pragma unroll
      for(int k=0;k<8;k++) acc[k] *= sc;
      m = l;
    }
    float w = __expf(l - m);
    S += w;
    #pragma unroll
    for(int k=0;k<8;k++) acc[k] += w*bf2f(r[k]);
    t += 2;
  }
  // merge halves
  float mo = __shfl_down(m, 32), So = __shfl_down(S, 32);
  float ao[8];
  #pragma unroll
  for(int k=0;k<8;k++) ao[k] = __shfl_down(acc[k], 32);
  if(half == 0){
    float M = fmaxf(m, mo);
    float sc0 = __expf(m - M), sc1 = __expf(mo - M);
    float Sf = S*sc0 + So*sc1;
    float inv = 1.f/(Sf + 1e-16f);
    float o[8];
    #pragma unroll
    for(int k=0;k<8;k++){
      float v = (acc[k]*sc0 + ao[k]*sc1)*inv + bias[8*hl + k];
      o[k] = fmaxf(v, 0.f);
    }
    // GAT2 logits
    float sv = 0.f, dv = 0.f;
    #pragma unroll
    for(int k=0;k<8;k++){ sv += o[k]*waS2[8*hl+k]; dv += o[k]*waD2[8*hl+k]; }
    #pragma unroll
    for(int off=16; off; off>>=1){ sv += __shfl_down(sv, off); dv += __shfl_down(dv, off); }
    if(hl == 0){ as2[wid] = sv; ad2[wid] = dv; }
    // GAT2 A-fragment write (K=256, Kc=8)
    u16x8 h, l;
    #pragma unroll
    for(int k=0;k<8;k++){
      unsigned short hb = f2bf(o[k]);
      h[k] = hb; l[k] = f2bf(o[k] - bf2f(hb));
    }
    int mc = wid >> 4;
    size_t base = ((size_t)(mc*8 + (hl>>2))*64 + (wid & 15) + (hl & 3)*16) * 8;
    *(u16x8*)(fhi + base) = h;
    *(u16x8*)(flo + base) = l;
  }
}

// ---------------- GAT2 agg: D=128, quarter-wave, online softmax, fp32 out ----------------
__global__ __launch_bounds__(256) void k_gat2_agg(const unsigned short* __restrict__ hP,
                                                  const float* __restrict__ as_, const float* __restrict__ ad_,
                                                  const int* __restrict__ offs, const int* __restrict__ esrc,
                                                  const float* __restrict__ bias, float* __restrict__ out, int n){
  int wid  = (int)((blockIdx.x*256u + threadIdx.x) >> 6);
  int lane = threadIdx.x & 63;
  if(wid >= n) return;
  int q = lane >> 4, sub = lane & 15;
  float adi = ad_[wid];
  u16x8 rs = *(const u16x8*)(hP + (size_t)wid*128 + 8*sub);
  float m, S, acc[8];
  if(q == 0){
    m = lrelu(as_[wid] + adi); S = 1.f;
    #pragma unroll
    for(int k=0;k<8;k++) acc[k] = bf2f(rs[k]);
  } else {
    m = -3e38f; S = 0.f;
    #pragma unroll
    for(int k=0;k<8;k++) acc[k] = 0.f;
  }
  int e0 = offs[wid], e1 = offs[wid+1];
  int t = e0;
  for(; t+7 < e1; t += 8){
    int s0 = esrc[t + q], s1 = esrc[t + 4 + q];
    u16x8 r0 = *(const u16x8*)(hP + (size_t)s0*128 + 8*sub);
    u16x8 r1 = *(const u16x8*)(hP + (size_t)s1*128 + 8*sub);
    float l0 = lrelu(as_[s0] + adi), l1 = lrelu(as_[s1] + adi);
    float lm = fmaxf(l0, l1);
    if(lm > m + 8.f){
      float sc = __expf(m - lm); S *= sc;
      #pragma unroll
      for(int k=0;k<8;k++) acc[k] *= sc;
      m = lm;
    }
    float w0 = __expf(l0 - m), w1 = __expf(l1 - m);
    S += w0 + w1;
    #pragma unroll
    for(int k=0;k<8;k++) acc[k] += w0*bf2f(r0[k]) + w1*bf2f(r1[k]);
  }
  while(t < e1){
    int idx = t + q;
    bool ok = idx < e1;
    int s = esrc[ok ? idx : e0];
    u16x8 r = *(const u16x8*)(hP + (size_t)s*128 + 8*sub);
    float l = ok ? lrelu(as_[s] + adi) : -3e38f;
    if(l > m + 8.f){
      float sc = __expf(m - l); S *= sc;
      #pragma unroll
      for(int k=0;k<8;k++) acc[k] *= sc;
      m = l;
    }
    float w = __expf(l - m);
    S += w;
    #pragma unroll
    for(int k=0;k<8;k++) acc[k] += w*bf2f(r[k]);
    t += 4;
  }
  // merge 4 groups: step 32 then 16
  #pragma unroll
  for(int off=32; off>=16; off>>=1){
    float mo = __shfl_down(m, off), So = __shfl_down(S, off);
    float ao[8];
    #pragma unroll
    for(int k=0;k<8;k++) ao[k] = __shfl_down(acc[k], off);
    float M = fmaxf(m, mo);
    float sc0 = __expf(m - M), sc1 = __expf(mo - M);
    S = S*sc0 + So*sc1;
    #pragma unroll
    for(int k=0;k<8;k++) acc[k] = acc[k]*sc0 + ao[k]*sc1;
    m = M;
  }
  if(lane < 16){
    float inv = 1.f/(S + 1e-16f);
    float4 o0, o1;
    o0.x = acc[0]*inv + bias[8*sub  ]; o0.y = acc[1]*inv + bias[8*sub+1];
    o0.z = acc[2]*inv + bias[8*sub+2]; o0.w = acc[3]*inv + bias[8*sub+3];
    o1.x = acc[4]*inv + bias[8*sub+4]; o1.y = acc[5]*inv + bias[8*sub+5];
    o1.z = acc[6]*inv + bias[8*sub+6]; o1.w = acc[7]*inv + bias[8*sub+7];
    *(float4*)(out + (size_t)wid*128 + 8*sub)     = o0;
    *(float4*)(out + (size_t)wid*128 + 8*sub + 4) = o1;
  }
}

extern "C" void kernel_launch(void* const* d_in, const int* in_sizes, int n_in,
                              void* d_out, int out_size, void* d_ws, size_t ws_size,
                              hipStream_t stream){
  const float* x        = (const float*)d_in[0];
  const int*   ei       = (const int*)  d_in[1];
  const float* gin1_w1  = (const float*)d_in[3];
  const float* gin1_b1  = (const float*)d_in[4];
  const float* gin1_w2  = (const float*)d_in[5];
  const float* gin1_b2  = (const float*)d_in[6];
  const float* gin2_w1  = (const float*)d_in[7];
  const float* gin2_b1  = (const float*)d_in[8];
  const float* gin2_w2  = (const float*)d_in[9];
  const float* gin2_b2  = (const float*)d_in[10];
  const float* gat1_w   = (const float*)d_in[11];
  const float* gat1_as  = (const float*)d_in[12];
  const float* gat1_ad  = (const float*)d_in[13];
  const float* gat1_b   = (const float*)d_in[14];
  const float* gat2_w   = (const float*)d_in[15];
  const float* gat2_as  = (const float*)d_in[16];
  const float* gat2_ad  = (const float*)d_in[17];
  const float* gat2_b   = (const float*)d_in[18];

  const int n = in_sizes[0] / 10;
  const int E = in_sizes[1] / 2;
  const int* src = ei;
  const int* dst = ei + E;
  const int Mc = (n + 15) / 16;
  const int nb = (n + 1023) / 1024;

  char* w = (char*)d_ws;
  auto carve = [&](size_t bytes)->char*{ char* p = w; w += (bytes + 255) & ~(size_t)255; return p; };
  int*   esrc = (int*)  carve((size_t)E*4);
  int*   offs = (int*)  carve((size_t)(n+1)*4);
  int*   deg  = (int*)  carve((size_t)n*4);
  int*   cur  = (int*)  carve((size_t)n*4);
  int*   part = (int*)  carve((size_t)n*4);
  int*   bsum = (int*)  carve((size_t)1024*4);
  float* F1   = (float*)carve((size_t)n*128*4);
  float* F2   = (float*)carve((size_t)n*128*4);
  unsigned short* Hbf  = (unsigned short*)carve((size_t)n*64*2);
  unsigned short* Pbf  = (unsigned short*)carve((size_t)n*256*2);
  unsigned short* Pbf2 = (unsigned short*)carve((size_t)n*128*2);
  float* as_  = (float*)carve((size_t)n*4);
  float* ad_  = (float*)carve((size_t)n*4);
  float* as2_ = (float*)carve((size_t)n*4);
  float* ad2_ = (float*)carve((size_t)n*4);
  float* waS  = (float*)carve(256*4);
  float* waD  = (float*)carve(256*4);
  float* waS2 = (float*)carve(256*4);
  float* waD2 = (float*)carve(256*4);
  unsigned short* AfH = (unsigned short*)carve((size_t)Mc*8*512*2);
  unsigned short* AfL = (unsigned short*)carve((size_t)Mc*8*512*2);
  unsigned short* BfH = (unsigned short*)carve((size_t)64*512*2);
  unsigned short* BfL = (unsigned short*)carve((size_t)64*512*2);

  const int TPB = 256;
  int ebk = (E + TPB - 1) / TPB;
  int wbk = (n + 3) / 4;

  auto run_gemm = [&](const float* Afp, const float* Bfp, const float* bias,
                      float* Cf, unsigned short* Cb, int K, int Nd, int act){
    int Kc = (K + 31) / 32, Nc = Nd / 16;
    int afr = Mc * Kc, bfr = Nc * Kc;
    k_prepA<<<(afr*64 + 255)/256, 256, 0, stream>>>(Afp, AfH, AfL, n, K, Mc, Kc);
    k_prepB<<<(bfr*64 + 255)/256, 256, 0, stream>>>(Bfp, BfH, BfL, K, Nd, Kc, Nc);
    dim3 g((Mc + 7)/8, Nd/64);
    if(Cb){
      if(act) k_mgemm<1,true ,true ><<<g, TPB, 0, stream>>>(AfH, AfL, BfH, BfL, bias, nullptr, Cb, n, Nd, Kc, Mc);
      else    k_mgemm<0,false,true ><<<g, TPB, 0, stream>>>(AfH, AfL, BfH, BfL, nullptr, nullptr, Cb, n, Nd, Kc, Mc);
    } else {
      if(act) k_mgemm<1,true ,false><<<g, TPB, 0, stream>>>(AfH, AfL, BfH, BfL, bias, Cf, nullptr, n, Nd, Kc, Mc);
      else    k_mgemm<0,true ,false><<<g, TPB, 0, stream>>>(AfH, AfL, BfH, BfL, bias, Cf, nullptr, n, Nd, Kc, Mc);
    }
  };

  // CSR build
  hipMemsetAsync(deg, 0, (size_t)n*4, stream);
  hipMemsetAsync(cur, 0, (size_t)n*4, stream);
  k_deg<<<ebk, TPB, 0, stream>>>(dst, deg, E);
  k_scan1<<<nb, 1024, 0, stream>>>(deg, part, bsum, n);
  k_scan2<<<1, 1024, 0, stream>>>(bsum, nb);
  k_scan3<<<(n + 1023)/1024, 1024, 0, stream>>>(part, bsum, offs, n, E);
  k_fill<<<ebk, TPB, 0, stream>>>(src, dst, offs, cur, esrc, E);

  // GIN1: agg(x) -> F1[N,10]; 10->64 relu -> F2; 64->64 +bias+relu -> Hbf (bf16 row-major)
  k_agg<10><<<wbk, TPB, 0, stream>>>(x, offs, esrc, F1, n);
  run_gemm(F1, gin1_w1, gin1_b1, F2, nullptr, 10, 64, 1);
  run_gemm(F2, gin1_w2, gin1_b2, nullptr, Hbf, 64, 64, 1);

  // GIN2: agg(Hbf) -> A-frags (Kc=2) directly; mgemm 64->128 relu -> F2; 128->128 -> F1 (hB)
  k_gin2_agg<<<wbk, TPB, 0, stream>>>(Hbf, offs, esrc, AfH, AfL, n);
  {
    int K = 64, Nd = 128, Kc = 2, Nc = Nd/16;
    k_prepB<<<(Nc*Kc*64 + 255)/256, 256, 0, stream>>>(gin2_w1, BfH, BfL, K, Nd, Kc, Nc);
    dim3 g((Mc + 7)/8, Nd/64);
    k_mgemm<1,true,false><<<g, TPB, 0, stream>>>(AfH, AfL, BfH, BfL, gin2_b1, F2, nullptr, n, Nd, Kc, Mc);
  }
  run_gemm(F2, gin2_w2, gin2_b2, F1, nullptr, 128, 128, 0);

  // folded attention vectors (both layers)
  k_wa<256><<<(128+3)/4, TPB, 0, stream>>>(gat1_w, gat1_as, gat1_ad, waS, waD, 128);
  k_wa<128><<<(256+3)/4, TPB, 0, stream>>>(gat2_w, gat2_as, gat2_ad, waS2, waD2, 256);

  // GAT1: logits from fp32 hB; proj 128->256 -> Pbf; fused agg+softmax -> GAT2 A-frags + GAT2 logits
  k_dotsF<128><<<wbk, TPB, 0, stream>>>(F1, waS, waD, as_, ad_, n);
  run_gemm(F1, gat1_w, nullptr, nullptr, Pbf, 128, 256, 0);
  k_gat1_agg<<<wbk, TPB, 0, stream>>>(Pbf, as_, ad_, offs, esrc, gat1_b, waS2, waD2,
                                      AfH, AfL, as2_, ad2_, n);

  // GAT2: proj 256->128 from frags -> Pbf2; fused agg+softmax -> d_out
  {
    int K = 256, Nd = 128, Kc = 8, Nc = Nd/16;
    k_prepB<<<(Nc*Kc*64 + 255)/256, 256, 0, stream>>>(gat2_w, BfH, BfL, K, Nd, Kc, Nc);
    dim3 g((Mc + 7)/8, Nd/64);
    k_mgemm<0,false,true><<<g, TPB, 0, stream>>>(AfH, AfL, BfH, BfL, nullptr, nullptr, Pbf2, n, Nd, Kc, Mc);
  }
  k_gat2_agg<<<wbk, TPB, 0, stream>>>(Pbf2, as2_, ad2_, offs, esrc, gat2_b, (float*)d_out, n);
}

// Round 8
// 412.410 us; speedup vs baseline: 2.4310x; 1.0868x over previous
//
#include <hip/hip_runtime.h>
#include <math.h>

__device__ __forceinline__ float lrelu(float x){ return x > 0.f ? x : 0.2f*x; }

typedef short s16x8 __attribute__((ext_vector_type(8)));
typedef float f32x4 __attribute__((ext_vector_type(4)));
typedef unsigned short u16x8 __attribute__((ext_vector_type(8)));

__device__ __forceinline__ f32x4 bmma(s16x8 a, s16x8 b, f32x4 c){
  return __builtin_amdgcn_mfma_f32_16x16x32_bf16(a, b, c, 0, 0, 0);
}

__device__ __forceinline__ unsigned short f2bf(float f){
  unsigned u = __float_as_uint(f);
  unsigned r = (u + 0x7fffu + ((u >> 16) & 1u)) >> 16;
  return (unsigned short)r;
}
__device__ __forceinline__ float bf2f(unsigned short h){
  return __uint_as_float(((unsigned)h) << 16);
}

// ---------------- CSR build ----------------
__global__ void k_deg(const int* __restrict__ dst, int* __restrict__ deg, int E){
  int e = blockIdx.x*blockDim.x + threadIdx.x;
  if(e < E) atomicAdd(&deg[dst[e]], 1);
}

__global__ __launch_bounds__(1024) void k_scan1(const int* __restrict__ deg,
                                                int* __restrict__ part,
                                                int* __restrict__ bsum, int n){
  int i = blockIdx.x*1024 + threadIdx.x;
  int lane = threadIdx.x & 63, wv = threadIdx.x >> 6;
  int v = (i < n) ? deg[i] : 0;
  int s = v;
  #pragma unroll
  for(int off=1; off<64; off<<=1){
    int t = __shfl_up(s, off);
    if(lane >= off) s += t;
  }
  __shared__ int wsum[16];
  if(lane==63) wsum[wv] = s;
  __syncthreads();
  if(wv==0 && lane<16){
    int t = wsum[lane], ss = t;
    #pragma unroll
    for(int off=1; off<16; off<<=1){
      int u = __shfl_up(ss, off);
      if(lane >= off) ss += u;
    }
    wsum[lane] = ss - t;
    if(lane==15) bsum[blockIdx.x] = ss;
  }
  __syncthreads();
  if(i < n) part[i] = s - v + wsum[wv];
}

__global__ __launch_bounds__(1024) void k_scan2(int* __restrict__ bsum, int nb){
  int i = threadIdx.x;
  int lane = i & 63, wv = i >> 6;
  int v = (i < nb) ? bsum[i] : 0;
  int s = v;
  #pragma unroll
  for(int off=1; off<64; off<<=1){
    int t = __shfl_up(s, off);
    if(lane >= off) s += t;
  }
  __shared__ int wsum[16];
  if(lane==63) wsum[wv] = s;
  __syncthreads();
  if(wv==0 && lane<16){
    int t = wsum[lane], ss = t;
    #pragma unroll
    for(int off=1; off<16; off<<=1){
      int u = __shfl_up(ss, off);
      if(lane >= off) ss += u;
    }
    wsum[lane] = ss - t;
  }
  __syncthreads();
  if(i < nb) bsum[i] = s - v + wsum[wv];
}

__global__ void k_scan3(const int* __restrict__ part, const int* __restrict__ bsum,
                        int* __restrict__ offs, int n, int E){
  int i = blockIdx.x*blockDim.x + threadIdx.x;
  if(i < n) offs[i] = part[i] + bsum[i >> 10];
  if(i == 0) offs[n] = E;
}

__global__ void k_fill(const int* __restrict__ src, const int* __restrict__ dst,
                       const int* __restrict__ offs, int* __restrict__ cur,
                       int* __restrict__ esrc, int E){
  int e = blockIdx.x*blockDim.x + threadIdx.x;
  if(e < E){
    int d = dst[e];
    int pos = offs[d] + atomicAdd(&cur[d], 1);
    esrc[pos] = src[e];
  }
}

// ---------------- GIN1 aggregation (fp32, D=10) ----------------
template<int D>
__global__ __launch_bounds__(256) void k_agg(const float* __restrict__ xin,
                                             const int* __restrict__ offs,
                                             const int* __restrict__ esrc,
                                             float* __restrict__ out, int n){
  int wid  = (int)((blockIdx.x*256u + threadIdx.x) >> 6);
  int lane = threadIdx.x & 63;
  if(wid >= n) return;
  constexpr int NC = (D + 63) / 64;
  float acc[NC];
  #pragma unroll
  for(int j=0;j<NC;j++){ int c = lane + j*64; acc[j] = (c<D) ? xin[(size_t)wid*D + c] : 0.f; }
  int e0 = offs[wid], e1 = offs[wid+1];
  for(int t=e0; t<e1; t++){
    int s = esrc[t];
    const float* row = xin + (size_t)s*D;
    #pragma unroll
    for(int j=0;j<NC;j++){ int c = lane + j*64; if(c<D) acc[j] += row[c]; }
  }
  #pragma unroll
  for(int j=0;j<NC;j++){ int c = lane + j*64; if(c<D) out[(size_t)wid*D + c] = acc[j]; }
}

// ---------------- GIN2 agg: bf16 rows D=64, eighth-wave split, frag-epilogue ----------------
__global__ __launch_bounds__(256) void k_gin2_agg(const unsigned short* __restrict__ xin,
                                                  const int* __restrict__ offs,
                                                  const int* __restrict__ esrc,
                                                  unsigned short* __restrict__ fhi,
                                                  unsigned short* __restrict__ flo, int n){
  int wid  = (int)((blockIdx.x*256u + threadIdx.x) >> 6);
  int lane = threadIdx.x & 63;
  if(wid >= n) return;
  int g = lane >> 3, sub = lane & 7;
  float acc[8];
  #pragma unroll
  for(int k=0;k<8;k++) acc[k] = 0.f;
  int e0 = offs[wid], e1 = offs[wid+1];
  int t = e0;
  for(; t+7 < e1; t += 8){
    int s = esrc[t + g];
    u16x8 r = *(const u16x8*)(xin + (size_t)s*64 + 8*sub);
    #pragma unroll
    for(int k=0;k<8;k++) acc[k] += bf2f(r[k]);
  }
  if(t < e1){
    int idx = t + g;
    bool ok = idx < e1;
    int s = esrc[ok ? idx : e0];
    u16x8 r = *(const u16x8*)(xin + (size_t)s*64 + 8*sub);
    float w = ok ? 1.f : 0.f;
    #pragma unroll
    for(int k=0;k<8;k++) acc[k] += w*bf2f(r[k]);
  }
  #pragma unroll
  for(int off=32; off>=8; off>>=1)
    #pragma unroll
    for(int k=0;k<8;k++) acc[k] += __shfl_down(acc[k], off);
  if(lane < 8){
    u16x8 rs = *(const u16x8*)(xin + (size_t)wid*64 + 8*sub);
    u16x8 h, l;
    #pragma unroll
    for(int k=0;k<8;k++){
      float o = acc[k] + bf2f(rs[k]);
      unsigned short hb = f2bf(o);
      h[k] = hb; l[k] = f2bf(o - bf2f(hb));
    }
    int mc = wid >> 4;
    size_t base = ((size_t)(mc*2 + (sub>>2))*64 + (wid & 15) + (sub & 3)*16) * 8;
    *(u16x8*)(fhi + base) = h;
    *(u16x8*)(flo + base) = l;
  }
}

// ---------------- split-bf16 fragment prep ----------------
__global__ __launch_bounds__(256) void k_prepA(const float* __restrict__ A,
                                               unsigned short* __restrict__ hi,
                                               unsigned short* __restrict__ lo,
                                               int M, int K, int Mc, int Kc){
  int gid = blockIdx.x*256 + threadIdx.x;
  int lane = gid & 63;
  int fid  = gid >> 6;
  if(fid >= Mc*Kc) return;
  int mc = fid / Kc, kc = fid - mc*Kc;
  int row = mc*16 + (lane & 15);
  int k0  = kc*32 + (lane >> 4)*8;
  s16x8 h, l;
  if(row < M){
    const float* ap = A + (size_t)row*K + k0;
    #pragma unroll
    for(int j=0;j<8;j++){
      float v = (k0 + j < K) ? ap[j] : 0.f;
      unsigned short hb = f2bf(v);
      float r = v - bf2f(hb);
      h[j] = (short)hb; l[j] = (short)f2bf(r);
    }
  } else {
    #pragma unroll
    for(int j=0;j<8;j++){ h[j]=0; l[j]=0; }
  }
  size_t off = (size_t)fid*512 + (size_t)lane*8;
  *(s16x8*)(hi + off) = h;
  *(s16x8*)(lo + off) = l;
}

__global__ __launch_bounds__(256) void k_prepB(const float* __restrict__ B,
                                               unsigned short* __restrict__ hi,
                                               unsigned short* __restrict__ lo,
                                               int K, int Nd, int Kc, int Nc){
  int gid = blockIdx.x*256 + threadIdx.x;
  int lane = gid & 63;
  int fid  = gid >> 6;
  if(fid >= Nc*Kc) return;
  int nc = fid / Kc, kc = fid - nc*Kc;
  int col = nc*16 + (lane & 15);
  int k0  = kc*32 + (lane >> 4)*8;
  s16x8 h, l;
  #pragma unroll
  for(int j=0;j<8;j++){
    int k = k0 + j;
    float v = (k < K) ? B[(size_t)k*Nd + col] : 0.f;
    unsigned short hb = f2bf(v);
    float r = v - bf2f(hb);
    h[j] = (short)hb; l[j] = (short)f2bf(r);
  }
  size_t off = (size_t)fid*512 + (size_t)lane*8;
  *(s16x8*)(hi + off) = h;
  *(s16x8*)(lo + off) = l;
}

// ---------------- split-bf16 MFMA GEMM ----------------
// OMODE: 0 = fp32 C, 1 = bf16 row-major, 2 = A-frag out (next GEMM), 3 = frag out + atomic dots
template<int ACT, bool HASBIAS, int OMODE>
__global__ __launch_bounds__(256) void k_mgemm(const unsigned short* __restrict__ Ahi,
                                               const unsigned short* __restrict__ Alo,
                                               const unsigned short* __restrict__ Bhi,
                                               const unsigned short* __restrict__ Blo,
                                               const float* __restrict__ bias,
                                               float* __restrict__ C,
                                               unsigned short* __restrict__ Cbf,
                                               unsigned short* __restrict__ foh,
                                               unsigned short* __restrict__ fol,
                                               const float* __restrict__ dwS,
                                               const float* __restrict__ dwD,
                                               float* __restrict__ dotS,
                                               float* __restrict__ dotD,
                                               int M, int Nd, int Kc, int Mc){
  int tid = threadIdx.x;
  int wid = tid >> 6, lane = tid & 63;
  int wm = wid >> 1, wn = wid & 1;
  int mcb = blockIdx.x*8 + wm*4;
  int ncb = blockIdx.y*4 + wn*2;

  f32x4 acc[4][2];
  #pragma unroll
  for(int f=0;f<4;f++)
    #pragma unroll
    for(int g=0;g<2;g++) acc[f][g] = (f32x4){0.f,0.f,0.f,0.f};

  for(int kc=0; kc<Kc; kc++){
    s16x8 ah[4], al[4], bh[2], bl[2];
    #pragma unroll
    for(int f=0;f<4;f++){
      int mcf = mcb + f; if(mcf > Mc-1) mcf = Mc-1;
      size_t off = ((size_t)mcf*Kc + kc)*512 + (size_t)lane*8;
      ah[f] = *(const s16x8*)(Ahi + off);
      al[f] = *(const s16x8*)(Alo + off);
    }
    #pragma unroll
    for(int g=0;g<2;g++){
      size_t off = ((size_t)(ncb+g)*Kc + kc)*512 + (size_t)lane*8;
      bh[g] = *(const s16x8*)(Bhi + off);
      bl[g] = *(const s16x8*)(Blo + off);
    }
    #pragma unroll
    for(int f=0;f<4;f++)
      #pragma unroll
      for(int g=0;g<2;g++){
        acc[f][g] = bmma(ah[f], bh[g], acc[f][g]);
        acc[f][g] = bmma(ah[f], bl[g], acc[f][g]);
        acc[f][g] = bmma(al[f], bh[g], acc[f][g]);
      }
  }

  if constexpr(OMODE <= 1){
    #pragma unroll
    for(int g=0;g<2;g++){
      int col = (ncb+g)*16 + (lane & 15);
      float bv = HASBIAS ? bias[col] : 0.f;
      #pragma unroll
      for(int f=0;f<4;f++){
        int row0 = (mcb+f)*16 + (lane>>4)*4;
        #pragma unroll
        for(int r=0;r<4;r++){
          int row = row0 + r;
          if(row < M){
            float v = acc[f][g][r] + bv;
            if(ACT) v = fmaxf(v, 0.f);
            if(OMODE==1) Cbf[(size_t)row*Nd + col] = f2bf(v);
            else         C  [(size_t)row*Nd + col] = v;
          }
        }
      }
    }
  } else {
    // transpose 64x32 wave tile via LDS, emit split-bf16 A-frags (+optional dots)
    __shared__ float tile[4][64][33];
    #pragma unroll
    for(int g=0;g<2;g++){
      float bv = HASBIAS ? bias[(ncb+g)*16 + (lane&15)] : 0.f;
      int ck = g*16 + (lane & 15);
      #pragma unroll
      for(int f=0;f<4;f++){
        int rb = f*16 + (lane>>4)*4;
        #pragma unroll
        for(int r=0;r<4;r++){
          float v = acc[f][g][r] + bv;
          if(ACT) v = fmaxf(v, 0.f);
          tile[wid][rb + r][ck] = v;
        }
      }
    }
    asm volatile("" ::: "memory");   // keep LDS write->read order (same wave, lockstep)
    int Kcn = Nd >> 5;
    int kcn = ncb >> 1;
    int rr = lane & 15, cb = lane >> 4;
    #pragma unroll
    for(int f=0;f<4;f++){
      int mcf = mcb + f;
      if(mcf >= Mc) continue;      // skip clamped duplicates (M == Mc*16)
      float o[8];
      #pragma unroll
      for(int j=0;j<8;j++) o[j] = tile[wid][f*16 + rr][cb*8 + j];
      u16x8 h, l;
      #pragma unroll
      for(int j=0;j<8;j++){
        unsigned short hb = f2bf(o[j]);
        h[j] = hb; l[j] = f2bf(o[j] - bf2f(hb));
      }
      size_t base = ((size_t)mcf*Kcn + kcn)*512 + (size_t)lane*8;
      *(u16x8*)(foh + base) = h;
      *(u16x8*)(fol + base) = l;
      if constexpr(OMODE == 3){
        float sv = 0.f, dv = 0.f;
        #pragma unroll
        for(int j=0;j<8;j++){
          int col = kcn*32 + cb*8 + j;
          sv += o[j]*dwS[col]; dv += o[j]*dwD[col];
        }
        sv += __shfl_xor(sv, 16); sv += __shfl_xor(sv, 32);
        dv += __shfl_xor(dv, 16); dv += __shfl_xor(dv, 32);
        if(cb == 0){
          int row = mcf*16 + rr;
          atomicAdd(dotS + row, sv);
          atomicAdd(dotD + row, dv);
        }
      }
    }
  }
}

// ---------------- GAT: wa = W @ a ----------------
template<int L>
__global__ __launch_bounds__(256) void k_wa(const float* __restrict__ W,
                                            const float* __restrict__ a_s, const float* __restrict__ a_d,
                                            float* __restrict__ wa_s, float* __restrict__ wa_d, int rows){
  int wid  = (int)((blockIdx.x*256u + threadIdx.x) >> 6);
  int lane = threadIdx.x & 63;
  if(wid >= rows) return;
  float s = 0.f, d = 0.f;
  #pragma unroll
  for(int j=0;j<L/64;j++){
    int c = lane + j*64;
    float v = W[(size_t)wid*L + c];
    s += v * a_s[c];
    d += v * a_d[c];
  }
  #pragma unroll
  for(int off=32; off; off>>=1){ s += __shfl_down(s, off); d += __shfl_down(d, off); }
  if(lane==0){ wa_s[wid] = s; wa_d[wid] = d; }
}

// ---------------- GAT1 agg: D=256, half-wave, online softmax, frag+logit epilogue ----------------
__global__ __launch_bounds__(256) void k_gat1_agg(const unsigned short* __restrict__ hP,
                                                  const float* __restrict__ as_, const float* __restrict__ ad_,
                                                  const int* __restrict__ offs, const int* __restrict__ esrc,
                                                  const float* __restrict__ bias,
                                                  const float* __restrict__ waS2, const float* __restrict__ waD2,
                                                  unsigned short* __restrict__ fhi, unsigned short* __restrict__ flo,
                                                  float* __restrict__ as2, float* __restrict__ ad2, int n){
  int wid  = (int)((blockIdx.x*256u + threadIdx.x) >> 6);
  int lane = threadIdx.x & 63;
  if(wid >= n) return;
  int half = lane >> 5, hl = lane & 31;
  float adi = ad_[wid];
  u16x8 rs = *(const u16x8*)(hP + (size_t)wid*256 + 8*hl);
  float m, S, acc[8];
  if(half == 0){
    m = lrelu(as_[wid] + adi); S = 1.f;
    #pragma unroll
    for(int k=0;k<8;k++) acc[k] = bf2f(rs[k]);
  } else {
    m = -3e38f; S = 0.f;
    #pragma unroll
    for(int k=0;k<8;k++) acc[k] = 0.f;
  }
  int e0 = offs[wid], e1 = offs[wid+1];
  int t = e0;
  for(; t+7 < e1; t += 8){
    int s0 = esrc[t + half], s1 = esrc[t+2+half], s2 = esrc[t+4+half], s3 = esrc[t+6+half];
    u16x8 r0 = *(const u16x8*)(hP + (size_t)s0*256 + 8*hl);
    u16x8 r1 = *(const u16x8*)(hP + (size_t)s1*256 + 8*hl);
    u16x8 r2 = *(const u16x8*)(hP + (size_t)s2*256 + 8*hl);
    u16x8 r3 = *(const u16x8*)(hP + (size_t)s3*256 + 8*hl);
    float l0 = lrelu(as_[s0] + adi), l1 = lrelu(as_[s1] + adi);
    float l2 = lrelu(as_[s2] + adi), l3 = lrelu(as_[s3] + adi);
    float lm = fmaxf(fmaxf(l0,l1), fmaxf(l2,l3));
    if(lm > m + 8.f){
      float sc = __expf(m - lm); S *= sc;
      #pragma unroll
      for(int k=0;k<8;k++) acc[k] *= sc;
      m = lm;
    }
    float w0 = __expf(l0 - m), w1 = __expf(l1 - m), w2 = __expf(l2 - m), w3 = __expf(l3 - m);
    S += w0 + w1 + w2 + w3;
    #pragma unroll
    for(int k=0;k<8;k++)
      acc[k] += w0*bf2f(r0[k]) + w1*bf2f(r1[k]) + w2*bf2f(r2[k]) + w3*bf2f(r3[k]);
  }
  while(t < e1){
    int idx = t + half;
    bool ok = idx < e1;
    int s = esrc[ok ? idx : e0];
    u16x8 r = *(const u16x8*)(hP + (size_t)s*256 + 8*hl);
    float l = ok ? lrelu(as_[s] + adi) : -3e38f;
    if(l > m + 8.f){
      float sc = __expf(m - l); S *= sc;
      #pragma unroll
      for(int k=0;k<8;k++) acc[k] *= sc;
      m = l;
    }
    float w = __expf(l - m);
    S += w;
    #pragma unroll
    for(int k=0;k<8;k++) acc[k] += w*bf2f(r[k]);
    t += 2;
  }
  float mo = __shfl_down(m, 32), So = __shfl_down(S, 32);
  float ao[8];
  #pragma unroll
  for(int k=0;k<8;k++) ao[k] = __shfl_down(acc[k], 32);
  if(half == 0){
    float M = fmaxf(m, mo);
    float sc0 = __expf(m - M), sc1 = __expf(mo - M);
    float Sf = S*sc0 + So*sc1;
    float inv = 1.f/(Sf + 1e-16f);
    float o[8];
    #pragma unroll
    for(int k=0;k<8;k++){
      float v = (acc[k]*sc0 + ao[k]*sc1)*inv + bias[8*hl + k];
      o[k] = fmaxf(v, 0.f);
    }
    float sv = 0.f, dv = 0.f;
    #pragma unroll
    for(int k=0;k<8;k++){ sv += o[k]*waS2[8*hl+k]; dv += o[k]*waD2[8*hl+k]; }
    #pragma unroll
    for(int off=16; off; off>>=1){ sv += __shfl_down(sv, off); dv += __shfl_down(dv, off); }
    if(hl == 0){ as2[wid] = sv; ad2[wid] = dv; }
    u16x8 h, l;
    #pragma unroll
    for(int k=0;k<8;k++){
      unsigned short hb = f2bf(o[k]);
      h[k] = hb; l[k] = f2bf(o[k] - bf2f(hb));
    }
    int mc = wid >> 4;
    size_t base = ((size_t)(mc*8 + (hl>>2))*64 + (wid & 15) + (hl & 3)*16) * 8;
    *(u16x8*)(fhi + base) = h;
    *(u16x8*)(flo + base) = l;
  }
}

// ---------------- GAT2 agg: D=128, quarter-wave, online softmax, fp32 out ----------------
__global__ __launch_bounds__(256) void k_gat2_agg(const unsigned short* __restrict__ hP,
                                                  const float* __restrict__ as_, const float* __restrict__ ad_,
                                                  const int* __restrict__ offs, const int* __restrict__ esrc,
                                                  const float* __restrict__ bias, float* __restrict__ out, int n){
  int wid  = (int)((blockIdx.x*256u + threadIdx.x) >> 6);
  int lane = threadIdx.x & 63;
  if(wid >= n) return;
  int q = lane >> 4, sub = lane & 15;
  float adi = ad_[wid];
  u16x8 rs = *(const u16x8*)(hP + (size_t)wid*128 + 8*sub);
  float m, S, acc[8];
  if(q == 0){
    m = lrelu(as_[wid] + adi); S = 1.f;
    #pragma unroll
    for(int k=0;k<8;k++) acc[k] = bf2f(rs[k]);
  } else {
    m = -3e38f; S = 0.f;
    #pragma unroll
    for(int k=0;k<8;k++) acc[k] = 0.f;
  }
  int e0 = offs[wid], e1 = offs[wid+1];
  int t = e0;
  for(; t+7 < e1; t += 8){
    int s0 = esrc[t + q], s1 = esrc[t + 4 + q];
    u16x8 r0 = *(const u16x8*)(hP + (size_t)s0*128 + 8*sub);
    u16x8 r1 = *(const u16x8*)(hP + (size_t)s1*128 + 8*sub);
    float l0 = lrelu(as_[s0] + adi), l1 = lrelu(as_[s1] + adi);
    float lm = fmaxf(l0, l1);
    if(lm > m + 8.f){
      float sc = __expf(m - lm); S *= sc;
      #pragma unroll
      for(int k=0;k<8;k++) acc[k] *= sc;
      m = lm;
    }
    float w0 = __expf(l0 - m), w1 = __expf(l1 - m);
    S += w0 + w1;
    #pragma unroll
    for(int k=0;k<8;k++) acc[k] += w0*bf2f(r0[k]) + w1*bf2f(r1[k]);
  }
  while(t < e1){
    int idx = t + q;
    bool ok = idx < e1;
    int s = esrc[ok ? idx : e0];
    u16x8 r = *(const u16x8*)(hP + (size_t)s*128 + 8*sub);
    float l = ok ? lrelu(as_[s] + adi) : -3e38f;
    if(l > m + 8.f){
      float sc = __expf(m - l); S *= sc;
      #pragma unroll
      for(int k=0;k<8;k++) acc[k] *= sc;
      m = l;
    }
    float w = __expf(l - m);
    S += w;
    #pragma unroll
    for(int k=0;k<8;k++) acc[k] += w*bf2f(r[k]);
    t += 4;
  }
  #pragma unroll
  for(int off=32; off>=16; off>>=1){
    float mo = __shfl_down(m, off), So = __shfl_down(S, off);
    float ao[8];
    #pragma unroll
    for(int k=0;k<8;k++) ao[k] = __shfl_down(acc[k], off);
    float M = fmaxf(m, mo);
    float sc0 = __expf(m - M), sc1 = __expf(mo - M);
    S = S*sc0 + So*sc1;
    #pragma unroll
    for(int k=0;k<8;k++) acc[k] = acc[k]*sc0 + ao[k]*sc1;
    m = M;
  }
  if(lane < 16){
    float inv = 1.f/(S + 1e-16f);
    float4 o0, o1;
    o0.x = acc[0]*inv + bias[8*sub  ]; o0.y = acc[1]*inv + bias[8*sub+1];
    o0.z = acc[2]*inv + bias[8*sub+2]; o0.w = acc[3]*inv + bias[8*sub+3];
    o1.x = acc[4]*inv + bias[8*sub+4]; o1.y = acc[5]*inv + bias[8*sub+5];
    o1.z = acc[6]*inv + bias[8*sub+6]; o1.w = acc[7]*inv + bias[8*sub+7];
    *(float4*)(out + (size_t)wid*128 + 8*sub)     = o0;
    *(float4*)(out + (size_t)wid*128 + 8*sub + 4) = o1;
  }
}

extern "C" void kernel_launch(void* const* d_in, const int* in_sizes, int n_in,
                              void* d_out, int out_size, void* d_ws, size_t ws_size,
                              hipStream_t stream){
  const float* x        = (const float*)d_in[0];
  const int*   ei       = (const int*)  d_in[1];
  const float* gin1_w1  = (const float*)d_in[3];
  const float* gin1_b1  = (const float*)d_in[4];
  const float* gin1_w2  = (const float*)d_in[5];
  const float* gin1_b2  = (const float*)d_in[6];
  const float* gin2_w1  = (const float*)d_in[7];
  const float* gin2_b1  = (const float*)d_in[8];
  const float* gin2_w2  = (const float*)d_in[9];
  const float* gin2_b2  = (const float*)d_in[10];
  const float* gat1_w   = (const float*)d_in[11];
  const float* gat1_as  = (const float*)d_in[12];
  const float* gat1_ad  = (const float*)d_in[13];
  const float* gat1_b   = (const float*)d_in[14];
  const float* gat2_w   = (const float*)d_in[15];
  const float* gat2_as  = (const float*)d_in[16];
  const float* gat2_ad  = (const float*)d_in[17];
  const float* gat2_b   = (const float*)d_in[18];

  const int n = in_sizes[0] / 10;
  const int E = in_sizes[1] / 2;
  const int* src = ei;
  const int* dst = ei + E;
  const int Mc = (n + 15) / 16;
  const int nb = (n + 1023) / 1024;

  char* w = (char*)d_ws;
  auto carve = [&](size_t bytes)->char*{ char* p = w; w += (bytes + 255) & ~(size_t)255; return p; };
  int*   esrc = (int*)  carve((size_t)E*4);
  int*   offs = (int*)  carve((size_t)(n+1)*4);
  int*   deg  = (int*)  carve((size_t)n*4);
  int*   cur  = (int*)  carve((size_t)n*4);
  int*   part = (int*)  carve((size_t)n*4);
  int*   bsum = (int*)  carve((size_t)1024*4);
  float* F1   = (float*)carve((size_t)n*16*4);
  float* F2   = (float*)carve((size_t)n*64*4);
  unsigned short* Hbf  = (unsigned short*)carve((size_t)n*64*2);
  unsigned short* Pbf  = (unsigned short*)carve((size_t)n*256*2);
  unsigned short* Pbf2 = (unsigned short*)carve((size_t)n*128*2);
  float* as_  = (float*)carve((size_t)n*4);
  float* ad_  = (float*)carve((size_t)n*4);
  float* as2_ = (float*)carve((size_t)n*4);
  float* ad2_ = (float*)carve((size_t)n*4);
  float* waS  = (float*)carve(256*4);
  float* waD  = (float*)carve(256*4);
  float* waS2 = (float*)carve(256*4);
  float* waD2 = (float*)carve(256*4);
  unsigned short* FAh = (unsigned short*)carve((size_t)Mc*8*512*2);
  unsigned short* FAl = (unsigned short*)carve((size_t)Mc*8*512*2);
  unsigned short* FBh = (unsigned short*)carve((size_t)Mc*8*512*2);
  unsigned short* FBl = (unsigned short*)carve((size_t)Mc*8*512*2);
  unsigned short* BfH = (unsigned short*)carve((size_t)64*512*2);
  unsigned short* BfL = (unsigned short*)carve((size_t)64*512*2);

  const int TPB = 256;
  int ebk = (E + TPB - 1) / TPB;
  int wbk = (n + 3) / 4;
  int gx  = (Mc + 7) / 8;

  // CSR build
  hipMemsetAsync(deg, 0, (size_t)n*4, stream);
  hipMemsetAsync(cur, 0, (size_t)n*4, stream);
  k_deg<<<ebk, TPB, 0, stream>>>(dst, deg, E);
  k_scan1<<<nb, 1024, 0, stream>>>(deg, part, bsum, n);
  k_scan2<<<1, 1024, 0, stream>>>(bsum, nb);
  k_scan3<<<(n + 1023)/1024, 1024, 0, stream>>>(part, bsum, offs, n, E);
  k_fill<<<ebk, TPB, 0, stream>>>(src, dst, offs, cur, esrc, E);

  // folded attention vectors (early, independent)
  k_wa<256><<<(128+3)/4, TPB, 0, stream>>>(gat1_w, gat1_as, gat1_ad, waS, waD, 128);
  k_wa<128><<<(256+3)/4, TPB, 0, stream>>>(gat2_w, gat2_as, gat2_ad, waS2, waD2, 256);

  // GIN1: agg(x) -> F1[N,10]; 10->64 relu -> F2 fp32; 64->64 +bias+relu -> Hbf bf16 row-major
  k_agg<10><<<wbk, TPB, 0, stream>>>(x, offs, esrc, F1, n);
  k_prepA<<<(Mc*1*64 + 255)/256, 256, 0, stream>>>(F1, FBh, FBl, n, 10, Mc, 1);
  k_prepB<<<(4*1*64 + 255)/256, 256, 0, stream>>>(gin1_w1, BfH, BfL, 10, 64, 1, 4);
  k_mgemm<1,true,0><<<dim3(gx,1), TPB, 0, stream>>>(FBh, FBl, BfH, BfL, gin1_b1,
      F2, nullptr, nullptr, nullptr, nullptr, nullptr, nullptr, nullptr, n, 64, 1, Mc);
  k_prepA<<<(Mc*2*64 + 255)/256, 256, 0, stream>>>(F2, FBh, FBl, n, 64, Mc, 2);
  k_prepB<<<(4*2*64 + 255)/256, 256, 0, stream>>>(gin1_w2, BfH, BfL, 64, 64, 2, 4);
  k_mgemm<1,true,1><<<dim3(gx,1), TPB, 0, stream>>>(FBh, FBl, BfH, BfL, gin1_b2,
      nullptr, Hbf, nullptr, nullptr, nullptr, nullptr, nullptr, nullptr, n, 64, 2, Mc);

  // GIN2: agg(Hbf) -> FA frags (Kc=2); 64->128 relu -> FB frags (Kcn=4);
  //       128->128 +bias -> FA frags (Kcn=4) + fused GAT1 logits (atomic dots)
  k_gin2_agg<<<wbk, TPB, 0, stream>>>(Hbf, offs, esrc, FAh, FAl, n);
  k_prepB<<<(8*2*64 + 255)/256, 256, 0, stream>>>(gin2_w1, BfH, BfL, 64, 128, 2, 8);
  k_mgemm<1,true,2><<<dim3(gx,2), TPB, 0, stream>>>(FAh, FAl, BfH, BfL, gin2_b1,
      nullptr, nullptr, FBh, FBl, nullptr, nullptr, nullptr, nullptr, n, 128, 2, Mc);
  hipMemsetAsync(as_, 0, (size_t)n*4, stream);
  hipMemsetAsync(ad_, 0, (size_t)n*4, stream);
  k_prepB<<<(8*4*64 + 255)/256, 256, 0, stream>>>(gin2_w2, BfH, BfL, 128, 128, 4, 8);
  k_mgemm<0,true,3><<<dim3(gx,2), TPB, 0, stream>>>(FBh, FBl, BfH, BfL, gin2_b2,
      nullptr, nullptr, FAh, FAl, waS, waD, as_, ad_, n, 128, 4, Mc);

  // GAT1: proj 128->256 -> Pbf bf16 row-major; fused agg+softmax -> FB frags (Kc=8) + GAT2 logits
  k_prepB<<<(16*4*64 + 255)/256, 256, 0, stream>>>(gat1_w, BfH, BfL, 128, 256, 4, 16);
  k_mgemm<0,false,1><<<dim3(gx,4), TPB, 0, stream>>>(FAh, FAl, BfH, BfL, nullptr,
      nullptr, Pbf, nullptr, nullptr, nullptr, nullptr, nullptr, nullptr, n, 256, 4, Mc);
  k_gat1_agg<<<wbk, TPB, 0, stream>>>(Pbf, as_, ad_, offs, esrc, gat1_b, waS2, waD2,
                                      FBh, FBl, as2_, ad2_, n);

  // GAT2: proj 256->128 -> Pbf2; fused agg+softmax -> d_out
  k_prepB<<<(8*8*64 + 255)/256, 256, 0, stream>>>(gat2_w, BfH, BfL, 256, 128, 8, 8);
  k_mgemm<0,false,1><<<dim3(gx,2), TPB, 0, stream>>>(FBh, FBl, BfH, BfL, nullptr,
      nullptr, Pbf2, nullptr, nullptr, nullptr, nullptr, nullptr, nullptr, n, 128, 8, Mc);
  k_gat2_agg<<<wbk, TPB, 0, stream>>>(Pbf2, as2_, ad2_, offs, esrc, gat2_b, (float*)d_out, n);
}

// Round 9
// 376.201 us; speedup vs baseline: 2.6650x; 1.0962x over previous
//
#include <hip/hip_runtime.h>
#include <math.h>

__device__ __forceinline__ float lrelu(float x){ return x > 0.f ? x : 0.2f*x; }

typedef short s16x8 __attribute__((ext_vector_type(8)));
typedef float f32x4 __attribute__((ext_vector_type(4)));
typedef unsigned short u16x8 __attribute__((ext_vector_type(8)));

__device__ __forceinline__ f32x4 bmma(s16x8 a, s16x8 b, f32x4 c){
  return __builtin_amdgcn_mfma_f32_16x16x32_bf16(a, b, c, 0, 0, 0);
}

__device__ __forceinline__ unsigned short f2bf(float f){
  unsigned u = __float_as_uint(f);
  unsigned r = (u + 0x7fffu + ((u >> 16) & 1u)) >> 16;
  return (unsigned short)r;
}
__device__ __forceinline__ float bf2f(unsigned short h){
  return __uint_as_float(((unsigned)h) << 16);
}

// ---------------- CSR build ----------------
__global__ void k_deg(const int* __restrict__ dst, int* __restrict__ deg, int E){
  int e = blockIdx.x*blockDim.x + threadIdx.x;
  if(e < E) atomicAdd(&deg[dst[e]], 1);
}

__global__ __launch_bounds__(1024) void k_scan1(const int* __restrict__ deg,
                                                int* __restrict__ part,
                                                int* __restrict__ bsum, int n){
  int i = blockIdx.x*1024 + threadIdx.x;
  int lane = threadIdx.x & 63, wv = threadIdx.x >> 6;
  int v = (i < n) ? deg[i] : 0;
  int s = v;
  #pragma unroll
  for(int off=1; off<64; off<<=1){
    int t = __shfl_up(s, off);
    if(lane >= off) s += t;
  }
  __shared__ int wsum[16];
  if(lane==63) wsum[wv] = s;
  __syncthreads();
  if(wv==0 && lane<16){
    int t = wsum[lane], ss = t;
    #pragma unroll
    for(int off=1; off<16; off<<=1){
      int u = __shfl_up(ss, off);
      if(lane >= off) ss += u;
    }
    wsum[lane] = ss - t;
    if(lane==15) bsum[blockIdx.x] = ss;
  }
  __syncthreads();
  if(i < n) part[i] = s - v + wsum[wv];
}

__global__ __launch_bounds__(1024) void k_scan2(int* __restrict__ bsum, int nb){
  int i = threadIdx.x;
  int lane = i & 63, wv = i >> 6;
  int v = (i < nb) ? bsum[i] : 0;
  int s = v;
  #pragma unroll
  for(int off=1; off<64; off<<=1){
    int t = __shfl_up(s, off);
    if(lane >= off) s += t;
  }
  __shared__ int wsum[16];
  if(lane==63) wsum[wv] = s;
  __syncthreads();
  if(wv==0 && lane<16){
    int t = wsum[lane], ss = t;
    #pragma unroll
    for(int off=1; off<16; off<<=1){
      int u = __shfl_up(ss, off);
      if(lane >= off) ss += u;
    }
    wsum[lane] = ss - t;
  }
  __syncthreads();
  if(i < nb) bsum[i] = s - v + wsum[wv];
}

__global__ void k_scan3(const int* __restrict__ part, const int* __restrict__ bsum,
                        int* __restrict__ offs, int n, int E){
  int i = blockIdx.x*blockDim.x + threadIdx.x;
  if(i < n) offs[i] = part[i] + bsum[i >> 10];
  if(i == 0) offs[n] = E;
}

__global__ void k_fill(const int* __restrict__ src, const int* __restrict__ dst,
                       const int* __restrict__ offs, int* __restrict__ cur,
                       int* __restrict__ esrc, int E){
  int e = blockIdx.x*blockDim.x + threadIdx.x;
  if(e < E){
    int d = dst[e];
    int pos = offs[d] + atomicAdd(&cur[d], 1);
    esrc[pos] = src[e];
  }
}

// ---------------- GIN1 aggregation (fp32, D=10) ----------------
template<int D>
__global__ __launch_bounds__(256) void k_agg(const float* __restrict__ xin,
                                             const int* __restrict__ offs,
                                             const int* __restrict__ esrc,
                                             float* __restrict__ out, int n){
  int wid  = (int)((blockIdx.x*256u + threadIdx.x) >> 6);
  int lane = threadIdx.x & 63;
  if(wid >= n) return;
  constexpr int NC = (D + 63) / 64;
  float acc[NC];
  #pragma unroll
  for(int j=0;j<NC;j++){ int c = lane + j*64; acc[j] = (c<D) ? xin[(size_t)wid*D + c] : 0.f; }
  int e0 = offs[wid], e1 = offs[wid+1];
  for(int t=e0; t<e1; t++){
    int s = esrc[t];
    const float* row = xin + (size_t)s*D;
    #pragma unroll
    for(int j=0;j<NC;j++){ int c = lane + j*64; if(c<D) acc[j] += row[c]; }
  }
  #pragma unroll
  for(int j=0;j<NC;j++){ int c = lane + j*64; if(c<D) out[(size_t)wid*D + c] = acc[j]; }
}

// ---------------- GIN2 agg: bf16 rows D=64, eighth-wave split, frag-epilogue ----------------
__global__ __launch_bounds__(256) void k_gin2_agg(const unsigned short* __restrict__ xin,
                                                  const int* __restrict__ offs,
                                                  const int* __restrict__ esrc,
                                                  unsigned short* __restrict__ fhi,
                                                  unsigned short* __restrict__ flo, int n){
  int wid  = (int)((blockIdx.x*256u + threadIdx.x) >> 6);
  int lane = threadIdx.x & 63;
  if(wid >= n) return;
  int g = lane >> 3, sub = lane & 7;
  float acc[8];
  #pragma unroll
  for(int k=0;k<8;k++) acc[k] = 0.f;
  int e0 = offs[wid], e1 = offs[wid+1];
  int t = e0;
  for(; t+7 < e1; t += 8){
    int s = esrc[t + g];
    u16x8 r = *(const u16x8*)(xin + (size_t)s*64 + 8*sub);
    #pragma unroll
    for(int k=0;k<8;k++) acc[k] += bf2f(r[k]);
  }
  if(t < e1){
    int idx = t + g;
    bool ok = idx < e1;
    int s = esrc[ok ? idx : e0];
    u16x8 r = *(const u16x8*)(xin + (size_t)s*64 + 8*sub);
    float w = ok ? 1.f : 0.f;
    #pragma unroll
    for(int k=0;k<8;k++) acc[k] += w*bf2f(r[k]);
  }
  #pragma unroll
  for(int off=32; off>=8; off>>=1)
    #pragma unroll
    for(int k=0;k<8;k++) acc[k] += __shfl_down(acc[k], off);
  if(lane < 8){
    u16x8 rs = *(const u16x8*)(xin + (size_t)wid*64 + 8*sub);
    u16x8 h, l;
    #pragma unroll
    for(int k=0;k<8;k++){
      float o = acc[k] + bf2f(rs[k]);
      unsigned short hb = f2bf(o);
      h[k] = hb; l[k] = f2bf(o - bf2f(hb));
    }
    int mc = wid >> 4;
    size_t base = ((size_t)(mc*2 + (sub>>2))*64 + (wid & 15) + (sub & 3)*16) * 8;
    *(u16x8*)(fhi + base) = h;
    *(u16x8*)(flo + base) = l;
  }
}

// ---------------- split-bf16 fragment prep ----------------
__global__ __launch_bounds__(256) void k_prepA(const float* __restrict__ A,
                                               unsigned short* __restrict__ hi,
                                               unsigned short* __restrict__ lo,
                                               int M, int K, int Mc, int Kc){
  int gid = blockIdx.x*256 + threadIdx.x;
  int lane = gid & 63;
  int fid  = gid >> 6;
  if(fid >= Mc*Kc) return;
  int mc = fid / Kc, kc = fid - mc*Kc;
  int row = mc*16 + (lane & 15);
  int k0  = kc*32 + (lane >> 4)*8;
  s16x8 h, l;
  if(row < M){
    const float* ap = A + (size_t)row*K + k0;
    #pragma unroll
    for(int j=0;j<8;j++){
      float v = (k0 + j < K) ? ap[j] : 0.f;
      unsigned short hb = f2bf(v);
      float r = v - bf2f(hb);
      h[j] = (short)hb; l[j] = (short)f2bf(r);
    }
  } else {
    #pragma unroll
    for(int j=0;j<8;j++){ h[j]=0; l[j]=0; }
  }
  size_t off = (size_t)fid*512 + (size_t)lane*8;
  *(s16x8*)(hi + off) = h;
  *(s16x8*)(lo + off) = l;
}

__global__ __launch_bounds__(256) void k_prepB(const float* __restrict__ B,
                                               unsigned short* __restrict__ hi,
                                               unsigned short* __restrict__ lo,
                                               int K, int Nd, int Kc, int Nc){
  int gid = blockIdx.x*256 + threadIdx.x;
  int lane = gid & 63;
  int fid  = gid >> 6;
  if(fid >= Nc*Kc) return;
  int nc = fid / Kc, kc = fid - nc*Kc;
  int col = nc*16 + (lane & 15);
  int k0  = kc*32 + (lane >> 4)*8;
  s16x8 h, l;
  #pragma unroll
  for(int j=0;j<8;j++){
    int k = k0 + j;
    float v = (k < K) ? B[(size_t)k*Nd + col] : 0.f;
    unsigned short hb = f2bf(v);
    float r = v - bf2f(hb);
    h[j] = (short)hb; l[j] = (short)f2bf(r);
  }
  size_t off = (size_t)fid*512 + (size_t)lane*8;
  *(s16x8*)(hi + off) = h;
  *(s16x8*)(lo + off) = l;
}

// ---------------- split-bf16 MFMA GEMM ----------------
// OMODE: 0 fp32 C | 1 bf16 row-major | 2 A-frag out | 3 A-frag out + atomic dots
//        4 bf16 row-major (via LDS transpose) + atomic dots
template<int ACT, bool HASBIAS, int OMODE>
__global__ __launch_bounds__(256) void k_mgemm(const unsigned short* __restrict__ Ahi,
                                               const unsigned short* __restrict__ Alo,
                                               const unsigned short* __restrict__ Bhi,
                                               const unsigned short* __restrict__ Blo,
                                               const float* __restrict__ bias,
                                               float* __restrict__ C,
                                               unsigned short* __restrict__ Cbf,
                                               unsigned short* __restrict__ foh,
                                               unsigned short* __restrict__ fol,
                                               const float* __restrict__ dwS,
                                               const float* __restrict__ dwD,
                                               float* __restrict__ dotS,
                                               float* __restrict__ dotD,
                                               int M, int Nd, int Kc, int Mc){
  int tid = threadIdx.x;
  int wid = tid >> 6, lane = tid & 63;
  int wm = wid >> 1, wn = wid & 1;
  int mcb = blockIdx.x*8 + wm*4;
  int ncb = blockIdx.y*4 + wn*2;

  f32x4 acc[4][2];
  #pragma unroll
  for(int f=0;f<4;f++)
    #pragma unroll
    for(int g=0;g<2;g++) acc[f][g] = (f32x4){0.f,0.f,0.f,0.f};

  for(int kc=0; kc<Kc; kc++){
    s16x8 ah[4], al[4], bh[2], bl[2];
    #pragma unroll
    for(int f=0;f<4;f++){
      int mcf = mcb + f; if(mcf > Mc-1) mcf = Mc-1;
      size_t off = ((size_t)mcf*Kc + kc)*512 + (size_t)lane*8;
      ah[f] = *(const s16x8*)(Ahi + off);
      al[f] = *(const s16x8*)(Alo + off);
    }
    #pragma unroll
    for(int g=0;g<2;g++){
      size_t off = ((size_t)(ncb+g)*Kc + kc)*512 + (size_t)lane*8;
      bh[g] = *(const s16x8*)(Bhi + off);
      bl[g] = *(const s16x8*)(Blo + off);
    }
    #pragma unroll
    for(int f=0;f<4;f++)
      #pragma unroll
      for(int g=0;g<2;g++){
        acc[f][g] = bmma(ah[f], bh[g], acc[f][g]);
        acc[f][g] = bmma(ah[f], bl[g], acc[f][g]);
        acc[f][g] = bmma(al[f], bh[g], acc[f][g]);
      }
  }

  if constexpr(OMODE <= 1){
    #pragma unroll
    for(int g=0;g<2;g++){
      int col = (ncb+g)*16 + (lane & 15);
      float bv = HASBIAS ? bias[col] : 0.f;
      #pragma unroll
      for(int f=0;f<4;f++){
        int row0 = (mcb+f)*16 + (lane>>4)*4;
        #pragma unroll
        for(int r=0;r<4;r++){
          int row = row0 + r;
          if(row < M){
            float v = acc[f][g][r] + bv;
            if(ACT) v = fmaxf(v, 0.f);
            if(OMODE==1) Cbf[(size_t)row*Nd + col] = f2bf(v);
            else         C  [(size_t)row*Nd + col] = v;
          }
        }
      }
    }
  } else {
    // transpose 64x32 wave tile via LDS -> row-contiguous o[8] per lane
    __shared__ float tile[4][64][33];
    #pragma unroll
    for(int g=0;g<2;g++){
      float bv = HASBIAS ? bias[(ncb+g)*16 + (lane&15)] : 0.f;
      int ck = g*16 + (lane & 15);
      #pragma unroll
      for(int f=0;f<4;f++){
        int rb = f*16 + (lane>>4)*4;
        #pragma unroll
        for(int r=0;r<4;r++){
          float v = acc[f][g][r] + bv;
          if(ACT) v = fmaxf(v, 0.f);
          tile[wid][rb + r][ck] = v;
        }
      }
    }
    asm volatile("" ::: "memory");
    int Kcn = Nd >> 5;
    int kcn = ncb >> 1;
    int rr = lane & 15, cb = lane >> 4;
    #pragma unroll
    for(int f=0;f<4;f++){
      int mcf = mcb + f;
      if(mcf >= Mc) continue;
      float o[8];
      #pragma unroll
      for(int j=0;j<8;j++) o[j] = tile[wid][f*16 + rr][cb*8 + j];
      if constexpr(OMODE == 4){
        u16x8 hb;
        #pragma unroll
        for(int j=0;j<8;j++) hb[j] = f2bf(o[j]);
        int row = mcf*16 + rr;
        *(u16x8*)(Cbf + (size_t)row*Nd + kcn*32 + cb*8) = hb;
      } else {
        u16x8 h, l;
        #pragma unroll
        for(int j=0;j<8;j++){
          unsigned short hb = f2bf(o[j]);
          h[j] = hb; l[j] = f2bf(o[j] - bf2f(hb));
        }
        size_t base = ((size_t)mcf*Kcn + kcn)*512 + (size_t)lane*8;
        *(u16x8*)(foh + base) = h;
        *(u16x8*)(fol + base) = l;
      }
      if constexpr(OMODE == 3 || OMODE == 4){
        float sv = 0.f, dv = 0.f;
        #pragma unroll
        for(int j=0;j<8;j++){
          int col = kcn*32 + cb*8 + j;
          sv += o[j]*dwS[col]; dv += o[j]*dwD[col];
        }
        sv += __shfl_xor(sv, 16); sv += __shfl_xor(sv, 32);
        dv += __shfl_xor(dv, 16); dv += __shfl_xor(dv, 32);
        if(cb == 0){
          int row = mcf*16 + rr;
          atomicAdd(dotS + row, sv);
          atomicAdd(dotD + row, dv);
        }
      }
    }
  }
}

// ---------------- GAT: wa = W @ a ----------------
template<int L>
__global__ __launch_bounds__(256) void k_wa(const float* __restrict__ W,
                                            const float* __restrict__ a_s, const float* __restrict__ a_d,
                                            float* __restrict__ wa_s, float* __restrict__ wa_d, int rows){
  int wid  = (int)((blockIdx.x*256u + threadIdx.x) >> 6);
  int lane = threadIdx.x & 63;
  if(wid >= rows) return;
  float s = 0.f, d = 0.f;
  #pragma unroll
  for(int j=0;j<L/64;j++){
    int c = lane + j*64;
    float v = W[(size_t)wid*L + c];
    s += v * a_s[c];
    d += v * a_d[c];
  }
  #pragma unroll
  for(int off=32; off; off>>=1){ s += __shfl_down(s, off); d += __shfl_down(d, off); }
  if(lane==0){ wa_s[wid] = s; wa_d[wid] = d; }
}

// ---------------- GAT1 pre-projection agg: D=128 bf16, quarter-wave, online softmax, frag out ----------------
__global__ __launch_bounds__(256) void k_gat1_aggpre(const unsigned short* __restrict__ hB,
                                                     const float* __restrict__ as_, const float* __restrict__ ad_,
                                                     const int* __restrict__ offs, const int* __restrict__ esrc,
                                                     unsigned short* __restrict__ fhi, unsigned short* __restrict__ flo,
                                                     int n){
  int wid  = (int)((blockIdx.x*256u + threadIdx.x) >> 6);
  int lane = threadIdx.x & 63;
  if(wid >= n) return;
  int q = lane >> 4, sub = lane & 15;
  float adi = ad_[wid];
  u16x8 rs = *(const u16x8*)(hB + (size_t)wid*128 + 8*sub);
  float m, S, acc[8];
  if(q == 0){
    m = lrelu(as_[wid] + adi); S = 1.f;
    #pragma unroll
    for(int k=0;k<8;k++) acc[k] = bf2f(rs[k]);
  } else {
    m = -3e38f; S = 0.f;
    #pragma unroll
    for(int k=0;k<8;k++) acc[k] = 0.f;
  }
  int e0 = offs[wid], e1 = offs[wid+1];
  int t = e0;
  for(; t+7 < e1; t += 8){
    int s0 = esrc[t + q], s1 = esrc[t + 4 + q];
    u16x8 r0 = *(const u16x8*)(hB + (size_t)s0*128 + 8*sub);
    u16x8 r1 = *(const u16x8*)(hB + (size_t)s1*128 + 8*sub);
    float l0 = lrelu(as_[s0] + adi), l1 = lrelu(as_[s1] + adi);
    float lm = fmaxf(l0, l1);
    if(lm > m + 8.f){
      float sc = __expf(m - lm); S *= sc;
      #pragma unroll
      for(int k=0;k<8;k++) acc[k] *= sc;
      m = lm;
    }
    float w0 = __expf(l0 - m), w1 = __expf(l1 - m);
    S += w0 + w1;
    #pragma unroll
    for(int k=0;k<8;k++) acc[k] += w0*bf2f(r0[k]) + w1*bf2f(r1[k]);
  }
  while(t < e1){
    int idx = t + q;
    bool ok = idx < e1;
    int s = esrc[ok ? idx : e0];
    u16x8 r = *(const u16x8*)(hB + (size_t)s*128 + 8*sub);
    float l = ok ? lrelu(as_[s] + adi) : -3e38f;
    if(l > m + 8.f){
      float sc = __expf(m - l); S *= sc;
      #pragma unroll
      for(int k=0;k<8;k++) acc[k] *= sc;
      m = l;
    }
    float w = __expf(l - m);
    S += w;
    #pragma unroll
    for(int k=0;k<8;k++) acc[k] += w*bf2f(r[k]);
    t += 4;
  }
  #pragma unroll
  for(int off=32; off>=16; off>>=1){
    float mo = __shfl_down(m, off), So = __shfl_down(S, off);
    float ao[8];
    #pragma unroll
    for(int k=0;k<8;k++) ao[k] = __shfl_down(acc[k], off);
    float M = fmaxf(m, mo);
    float sc0 = __expf(m - M), sc1 = __expf(mo - M);
    S = S*sc0 + So*sc1;
    #pragma unroll
    for(int k=0;k<8;k++) acc[k] = acc[k]*sc0 + ao[k]*sc1;
    m = M;
  }
  if(lane < 16){
    float inv = 1.f/(S + 1e-16f);
    u16x8 h, l;
    #pragma unroll
    for(int k=0;k<8;k++){
      float v = acc[k]*inv;
      unsigned short hb = f2bf(v);
      h[k] = hb; l[k] = f2bf(v - bf2f(hb));
    }
    int mc = wid >> 4;
    size_t base = ((size_t)(mc*4 + (sub>>2))*64 + (wid & 15) + (sub & 3)*16) * 8;
    *(u16x8*)(fhi + base) = h;
    *(u16x8*)(flo + base) = l;
  }
}

// ---------------- GAT2 agg: D=128, quarter-wave, online softmax, fp32 out ----------------
__global__ __launch_bounds__(256) void k_gat2_agg(const unsigned short* __restrict__ hP,
                                                  const float* __restrict__ as_, const float* __restrict__ ad_,
                                                  const int* __restrict__ offs, const int* __restrict__ esrc,
                                                  const float* __restrict__ bias, float* __restrict__ out, int n){
  int wid  = (int)((blockIdx.x*256u + threadIdx.x) >> 6);
  int lane = threadIdx.x & 63;
  if(wid >= n) return;
  int q = lane >> 4, sub = lane & 15;
  float adi = ad_[wid];
  u16x8 rs = *(const u16x8*)(hP + (size_t)wid*128 + 8*sub);
  float m, S, acc[8];
  if(q == 0){
    m = lrelu(as_[wid] + adi); S = 1.f;
    #pragma unroll
    for(int k=0;k<8;k++) acc[k] = bf2f(rs[k]);
  } else {
    m = -3e38f; S = 0.f;
    #pragma unroll
    for(int k=0;k<8;k++) acc[k] = 0.f;
  }
  int e0 = offs[wid], e1 = offs[wid+1];
  int t = e0;
  for(; t+7 < e1; t += 8){
    int s0 = esrc[t + q], s1 = esrc[t + 4 + q];
    u16x8 r0 = *(const u16x8*)(hP + (size_t)s0*128 + 8*sub);
    u16x8 r1 = *(const u16x8*)(hP + (size_t)s1*128 + 8*sub);
    float l0 = lrelu(as_[s0] + adi), l1 = lrelu(as_[s1] + adi);
    float lm = fmaxf(l0, l1);
    if(lm > m + 8.f){
      float sc = __expf(m - lm); S *= sc;
      #pragma unroll
      for(int k=0;k<8;k++) acc[k] *= sc;
      m = lm;
    }
    float w0 = __expf(l0 - m), w1 = __expf(l1 - m);
    S += w0 + w1;
    #pragma unroll
    for(int k=0;k<8;k++) acc[k] += w0*bf2f(r0[k]) + w1*bf2f(r1[k]);
  }
  while(t < e1){
    int idx = t + q;
    bool ok = idx < e1;
    int s = esrc[ok ? idx : e0];
    u16x8 r = *(const u16x8*)(hP + (size_t)s*128 + 8*sub);
    float l = ok ? lrelu(as_[s] + adi) : -3e38f;
    if(l > m + 8.f){
      float sc = __expf(m - l); S *= sc;
      #pragma unroll
      for(int k=0;k<8;k++) acc[k] *= sc;
      m = l;
    }
    float w = __expf(l - m);
    S += w;
    #pragma unroll
    for(int k=0;k<8;k++) acc[k] += w*bf2f(r[k]);
    t += 4;
  }
  #pragma unroll
  for(int off=32; off>=16; off>>=1){
    float mo = __shfl_down(m, off), So = __shfl_down(S, off);
    float ao[8];
    #pragma unroll
    for(int k=0;k<8;k++) ao[k] = __shfl_down(acc[k], off);
    float M = fmaxf(m, mo);
    float sc0 = __expf(m - M), sc1 = __expf(mo - M);
    S = S*sc0 + So*sc1;
    #pragma unroll
    for(int k=0;k<8;k++) acc[k] = acc[k]*sc0 + ao[k]*sc1;
    m = M;
  }
  if(lane < 16){
    float inv = 1.f/(S + 1e-16f);
    float4 o0, o1;
    o0.x = acc[0]*inv + bias[8*sub  ]; o0.y = acc[1]*inv + bias[8*sub+1];
    o0.z = acc[2]*inv + bias[8*sub+2]; o0.w = acc[3]*inv + bias[8*sub+3];
    o1.x = acc[4]*inv + bias[8*sub+4]; o1.y = acc[5]*inv + bias[8*sub+5];
    o1.z = acc[6]*inv + bias[8*sub+6]; o1.w = acc[7]*inv + bias[8*sub+7];
    *(float4*)(out + (size_t)wid*128 + 8*sub)     = o0;
    *(float4*)(out + (size_t)wid*128 + 8*sub + 4) = o1;
  }
}

extern "C" void kernel_launch(void* const* d_in, const int* in_sizes, int n_in,
                              void* d_out, int out_size, void* d_ws, size_t ws_size,
                              hipStream_t stream){
  const float* x        = (const float*)d_in[0];
  const int*   ei       = (const int*)  d_in[1];
  const float* gin1_w1  = (const float*)d_in[3];
  const float* gin1_b1  = (const float*)d_in[4];
  const float* gin1_w2  = (const float*)d_in[5];
  const float* gin1_b2  = (const float*)d_in[6];
  const float* gin2_w1  = (const float*)d_in[7];
  const float* gin2_b1  = (const float*)d_in[8];
  const float* gin2_w2  = (const float*)d_in[9];
  const float* gin2_b2  = (const float*)d_in[10];
  const float* gat1_w   = (const float*)d_in[11];
  const float* gat1_as  = (const float*)d_in[12];
  const float* gat1_ad  = (const float*)d_in[13];
  const float* gat1_b   = (const float*)d_in[14];
  const float* gat2_w   = (const float*)d_in[15];
  const float* gat2_as  = (const float*)d_in[16];
  const float* gat2_ad  = (const float*)d_in[17];
  const float* gat2_b   = (const float*)d_in[18];

  const int n = in_sizes[0] / 10;
  const int E = in_sizes[1] / 2;
  const int* src = ei;
  const int* dst = ei + E;
  const int Mc = (n + 15) / 16;
  const int nb = (n + 1023) / 1024;

  char* w = (char*)d_ws;
  auto carve = [&](size_t bytes)->char*{ char* p = w; w += (bytes + 255) & ~(size_t)255; return p; };
  int*   esrc = (int*)  carve((size_t)E*4);
  int*   offs = (int*)  carve((size_t)(n+1)*4);
  int*   deg  = (int*)  carve((size_t)n*4);
  int*   cur  = (int*)  carve((size_t)n*4);
  int*   part = (int*)  carve((size_t)n*4);
  int*   bsum = (int*)  carve((size_t)1024*4);
  float* F1   = (float*)carve((size_t)n*16*4);
  unsigned short* Hbf   = (unsigned short*)carve((size_t)n*64*2);
  unsigned short* hB2bf = (unsigned short*)carve((size_t)n*128*2);
  unsigned short* Pbf2  = (unsigned short*)carve((size_t)n*128*2);
  float* as_  = (float*)carve((size_t)n*4);
  float* ad_  = (float*)carve((size_t)n*4);
  float* as2_ = (float*)carve((size_t)n*4);
  float* ad2_ = (float*)carve((size_t)n*4);
  float* waS  = (float*)carve(256*4);
  float* waD  = (float*)carve(256*4);
  float* waS2 = (float*)carve(256*4);
  float* waD2 = (float*)carve(256*4);
  unsigned short* FAh = (unsigned short*)carve((size_t)Mc*8*512*2);
  unsigned short* FAl = (unsigned short*)carve((size_t)Mc*8*512*2);
  unsigned short* FBh = (unsigned short*)carve((size_t)Mc*8*512*2);
  unsigned short* FBl = (unsigned short*)carve((size_t)Mc*8*512*2);
  unsigned short* BfH = (unsigned short*)carve((size_t)64*512*2);
  unsigned short* BfL = (unsigned short*)carve((size_t)64*512*2);

  const int TPB = 256;
  int ebk = (E + TPB - 1) / TPB;
  int wbk = (n + 3) / 4;
  int gx  = (Mc + 7) / 8;

  // CSR build
  hipMemsetAsync(deg, 0, (size_t)n*4, stream);
  hipMemsetAsync(cur, 0, (size_t)n*4, stream);
  k_deg<<<ebk, TPB, 0, stream>>>(dst, deg, E);
  k_scan1<<<nb, 1024, 0, stream>>>(deg, part, bsum, n);
  k_scan2<<<1, 1024, 0, stream>>>(bsum, nb);
  k_scan3<<<(n + 1023)/1024, 1024, 0, stream>>>(part, bsum, offs, n, E);
  k_fill<<<ebk, TPB, 0, stream>>>(src, dst, offs, cur, esrc, E);

  // folded attention vectors
  k_wa<256><<<(128+3)/4, TPB, 0, stream>>>(gat1_w, gat1_as, gat1_ad, waS, waD, 128);
  k_wa<128><<<(256+3)/4, TPB, 0, stream>>>(gat2_w, gat2_as, gat2_ad, waS2, waD2, 256);

  // GIN1: agg(x) -> F1[N,10]; 10->64 relu -> FB frags (Kcn=2); 64->64 +bias+relu -> Hbf
  k_agg<10><<<wbk, TPB, 0, stream>>>(x, offs, esrc, F1, n);
  k_prepA<<<(Mc*1*64 + 255)/256, 256, 0, stream>>>(F1, FAh, FAl, n, 10, Mc, 1);
  k_prepB<<<(4*1*64 + 255)/256, 256, 0, stream>>>(gin1_w1, BfH, BfL, 10, 64, 1, 4);
  k_mgemm<1,true,2><<<dim3(gx,1), TPB, 0, stream>>>(FAh, FAl, BfH, BfL, gin1_b1,
      nullptr, nullptr, FBh, FBl, nullptr, nullptr, nullptr, nullptr, n, 64, 1, Mc);
  k_prepB<<<(4*2*64 + 255)/256, 256, 0, stream>>>(gin1_w2, BfH, BfL, 64, 64, 2, 4);
  k_mgemm<1,true,1><<<dim3(gx,1), TPB, 0, stream>>>(FBh, FBl, BfH, BfL, gin1_b2,
      nullptr, Hbf, nullptr, nullptr, nullptr, nullptr, nullptr, nullptr, n, 64, 2, Mc);

  // GIN2: agg(Hbf) -> FA frags (Kc=2); 64->128 relu -> FB frags (Kcn=4);
  //       128->128 +bias -> hB2bf row-major + GAT1 logits (atomic dots)
  k_gin2_agg<<<wbk, TPB, 0, stream>>>(Hbf, offs, esrc, FAh, FAl, n);
  k_prepB<<<(8*2*64 + 255)/256, 256, 0, stream>>>(gin2_w1, BfH, BfL, 64, 128, 2, 8);
  k_mgemm<1,true,2><<<dim3(gx,2), TPB, 0, stream>>>(FAh, FAl, BfH, BfL, gin2_b1,
      nullptr, nullptr, FBh, FBl, nullptr, nullptr, nullptr, nullptr, n, 128, 2, Mc);
  hipMemsetAsync(as_, 0, (size_t)n*4, stream);
  hipMemsetAsync(ad_, 0, (size_t)n*4, stream);
  k_prepB<<<(8*4*64 + 255)/256, 256, 0, stream>>>(gin2_w2, BfH, BfL, 128, 128, 4, 8);
  k_mgemm<0,true,4><<<dim3(gx,2), TPB, 0, stream>>>(FBh, FBl, BfH, BfL, gin2_b2,
      nullptr, hB2bf, nullptr, nullptr, waS, waD, as_, ad_, n, 128, 4, Mc);

  // GAT1: pre-projection fused agg+softmax (256B/edge) -> FA frags (Kc=4);
  //       proj 128->256 +bias+relu -> FB frags (Kcn=8) + GAT2 logits (atomic dots)
  k_gat1_aggpre<<<wbk, TPB, 0, stream>>>(hB2bf, as_, ad_, offs, esrc, FAh, FAl, n);
  hipMemsetAsync(as2_, 0, (size_t)n*4, stream);
  hipMemsetAsync(ad2_, 0, (size_t)n*4, stream);
  k_prepB<<<(16*4*64 + 255)/256, 256, 0, stream>>>(gat1_w, BfH, BfL, 128, 256, 4, 16);
  k_mgemm<1,true,3><<<dim3(gx,4), TPB, 0, stream>>>(FAh, FAl, BfH, BfL, gat1_b,
      nullptr, nullptr, FBh, FBl, waS2, waD2, as2_, ad2_, n, 256, 4, Mc);

  // GAT2: proj 256->128 -> Pbf2; fused agg+softmax -> d_out
  k_prepB<<<(8*8*64 + 255)/256, 256, 0, stream>>>(gat2_w, BfH, BfL, 256, 128, 8, 8);
  k_mgemm<0,false,1><<<dim3(gx,2), TPB, 0, stream>>>(FBh, FBl, BfH, BfL, nullptr,
      nullptr, Pbf2, nullptr, nullptr, nullptr, nullptr, nullptr, nullptr, n, 128, 8, Mc);
  k_gat2_agg<<<wbk, TPB, 0, stream>>>(Pbf2, as2_, ad2_, offs, esrc, gat2_b, (float*)d_out, n);
}

// Round 10
// 343.175 us; speedup vs baseline: 2.9214x; 1.0962x over previous
//
#include <hip/hip_runtime.h>
#include <math.h>

__device__ __forceinline__ float lrelu(float x){ return x > 0.f ? x : 0.2f*x; }

typedef short s16x8 __attribute__((ext_vector_type(8)));
typedef float f32x4 __attribute__((ext_vector_type(4)));
typedef unsigned short u16x8 __attribute__((ext_vector_type(8)));

__device__ __forceinline__ f32x4 bmma(s16x8 a, s16x8 b, f32x4 c){
  return __builtin_amdgcn_mfma_f32_16x16x32_bf16(a, b, c, 0, 0, 0);
}

__device__ __forceinline__ unsigned short f2bf(float f){
  unsigned u = __float_as_uint(f);
  unsigned r = (u + 0x7fffu + ((u >> 16) & 1u)) >> 16;
  return (unsigned short)r;
}
__device__ __forceinline__ float bf2f(unsigned short h){
  return __uint_as_float(((unsigned)h) << 16);
}

// ---------------- CSR build ----------------
__global__ void k_deg(const int* __restrict__ dst, int* __restrict__ deg, int E){
  int e = blockIdx.x*blockDim.x + threadIdx.x;
  if(e < E) atomicAdd(&deg[dst[e]], 1);
}

__global__ __launch_bounds__(1024) void k_scan1(const int* __restrict__ deg,
                                                int* __restrict__ part,
                                                int* __restrict__ bsum, int n){
  int i = blockIdx.x*1024 + threadIdx.x;
  int lane = threadIdx.x & 63, wv = threadIdx.x >> 6;
  int v = (i < n) ? deg[i] : 0;
  int s = v;
  #pragma unroll
  for(int off=1; off<64; off<<=1){
    int t = __shfl_up(s, off);
    if(lane >= off) s += t;
  }
  __shared__ int wsum[16];
  if(lane==63) wsum[wv] = s;
  __syncthreads();
  if(wv==0 && lane<16){
    int t = wsum[lane], ss = t;
    #pragma unroll
    for(int off=1; off<16; off<<=1){
      int u = __shfl_up(ss, off);
      if(lane >= off) ss += u;
    }
    wsum[lane] = ss - t;
    if(lane==15) bsum[blockIdx.x] = ss;
  }
  __syncthreads();
  if(i < n) part[i] = s - v + wsum[wv];
}

__global__ __launch_bounds__(1024) void k_scan2(int* __restrict__ bsum, int nb){
  int i = threadIdx.x;
  int lane = i & 63, wv = i >> 6;
  int v = (i < nb) ? bsum[i] : 0;
  int s = v;
  #pragma unroll
  for(int off=1; off<64; off<<=1){
    int t = __shfl_up(s, off);
    if(lane >= off) s += t;
  }
  __shared__ int wsum[16];
  if(lane==63) wsum[wv] = s;
  __syncthreads();
  if(wv==0 && lane<16){
    int t = wsum[lane], ss = t;
    #pragma unroll
    for(int off=1; off<16; off<<=1){
      int u = __shfl_up(ss, off);
      if(lane >= off) ss += u;
    }
    wsum[lane] = ss - t;
  }
  __syncthreads();
  if(i < nb) bsum[i] = s - v + wsum[wv];
}

// also zero-inits the 4 logit accumulators (used later by atomic dots)
__global__ void k_scan3(const int* __restrict__ part, const int* __restrict__ bsum,
                        int* __restrict__ offs,
                        float* __restrict__ z0, float* __restrict__ z1,
                        float* __restrict__ z2, float* __restrict__ z3,
                        int n, int E){
  int i = blockIdx.x*blockDim.x + threadIdx.x;
  if(i < n){
    offs[i] = part[i] + bsum[i >> 10];
    z0[i] = 0.f; z1[i] = 0.f; z2[i] = 0.f; z3[i] = 0.f;
  }
  if(i == 0) offs[n] = E;
}

__global__ void k_fill(const int* __restrict__ src, const int* __restrict__ dst,
                       const int* __restrict__ offs, int* __restrict__ cur,
                       int* __restrict__ esrc, int E){
  int e = blockIdx.x*blockDim.x + threadIdx.x;
  if(e < E){
    int d = dst[e];
    int pos = offs[d] + atomicAdd(&cur[d], 1);
    esrc[pos] = src[e];
  }
}

// ---------------- GIN agg: bf16 rows D=64, eighth-wave split, frag-epilogue ----------------
// out[i] = x[i] + sum_j x[j] (+bias, ReLU if BR) -> split-bf16 A-frags (Kc=2)
template<bool BR>
__global__ __launch_bounds__(256) void k_gin_agg(const unsigned short* __restrict__ xin,
                                                 const int* __restrict__ offs,
                                                 const int* __restrict__ esrc,
                                                 const float* __restrict__ bias,
                                                 unsigned short* __restrict__ fhi,
                                                 unsigned short* __restrict__ flo, int n){
  int wid  = (int)((blockIdx.x*256u + threadIdx.x) >> 6);
  int lane = threadIdx.x & 63;
  if(wid >= n) return;
  int g = lane >> 3, sub = lane & 7;
  float acc[8];
  #pragma unroll
  for(int k=0;k<8;k++) acc[k] = 0.f;
  int e0 = offs[wid], e1 = offs[wid+1];
  int t = e0;
  for(; t+7 < e1; t += 8){
    int s = esrc[t + g];
    u16x8 r = *(const u16x8*)(xin + (size_t)s*64 + 8*sub);
    #pragma unroll
    for(int k=0;k<8;k++) acc[k] += bf2f(r[k]);
  }
  if(t < e1){
    int idx = t + g;
    bool ok = idx < e1;
    int s = esrc[ok ? idx : e0];
    u16x8 r = *(const u16x8*)(xin + (size_t)s*64 + 8*sub);
    float w = ok ? 1.f : 0.f;
    #pragma unroll
    for(int k=0;k<8;k++) acc[k] += w*bf2f(r[k]);
  }
  #pragma unroll
  for(int off=32; off>=8; off>>=1)
    #pragma unroll
    for(int k=0;k<8;k++) acc[k] += __shfl_down(acc[k], off);
  if(lane < 8){
    u16x8 rs = *(const u16x8*)(xin + (size_t)wid*64 + 8*sub);
    u16x8 h, l;
    #pragma unroll
    for(int k=0;k<8;k++){
      float o = acc[k] + bf2f(rs[k]);
      if(BR) o = fmaxf(o + bias[8*sub + k], 0.f);
      unsigned short hb = f2bf(o);
      h[k] = hb; l[k] = f2bf(o - bf2f(hb));
    }
    int mc = wid >> 4;
    size_t base = ((size_t)(mc*2 + (sub>>2))*64 + (wid & 15) + (sub & 3)*16) * 8;
    *(u16x8*)(fhi + base) = h;
    *(u16x8*)(flo + base) = l;
  }
}

// ---------------- split-bf16 fragment prep ----------------
__global__ __launch_bounds__(256) void k_prepA(const float* __restrict__ A,
                                               unsigned short* __restrict__ hi,
                                               unsigned short* __restrict__ lo,
                                               int M, int K, int Mc, int Kc){
  int gid = blockIdx.x*256 + threadIdx.x;
  int lane = gid & 63;
  int fid  = gid >> 6;
  if(fid >= Mc*Kc) return;
  int mc = fid / Kc, kc = fid - mc*Kc;
  int row = mc*16 + (lane & 15);
  int k0  = kc*32 + (lane >> 4)*8;
  s16x8 h, l;
  if(row < M){
    const float* ap = A + (size_t)row*K + k0;
    #pragma unroll
    for(int j=0;j<8;j++){
      float v = (k0 + j < K) ? ap[j] : 0.f;
      unsigned short hb = f2bf(v);
      float r = v - bf2f(hb);
      h[j] = (short)hb; l[j] = (short)f2bf(r);
    }
  } else {
    #pragma unroll
    for(int j=0;j<8;j++){ h[j]=0; l[j]=0; }
  }
  size_t off = (size_t)fid*512 + (size_t)lane*8;
  *(s16x8*)(hi + off) = h;
  *(s16x8*)(lo + off) = l;
}

__global__ __launch_bounds__(256) void k_prepB(const float* __restrict__ B,
                                               unsigned short* __restrict__ hi,
                                               unsigned short* __restrict__ lo,
                                               int K, int Nd, int Kc, int Nc){
  int gid = blockIdx.x*256 + threadIdx.x;
  int lane = gid & 63;
  int fid  = gid >> 6;
  if(fid >= Nc*Kc) return;
  int nc = fid / Kc, kc = fid - nc*Kc;
  int col = nc*16 + (lane & 15);
  int k0  = kc*32 + (lane >> 4)*8;
  s16x8 h, l;
  #pragma unroll
  for(int j=0;j<8;j++){
    int k = k0 + j;
    float v = (k < K) ? B[(size_t)k*Nd + col] : 0.f;
    unsigned short hb = f2bf(v);
    float r = v - bf2f(hb);
    h[j] = (short)hb; l[j] = (short)f2bf(r);
  }
  size_t off = (size_t)fid*512 + (size_t)lane*8;
  *(s16x8*)(hi + off) = h;
  *(s16x8*)(lo + off) = l;
}

// ---------------- split-bf16 MFMA GEMM ----------------
// OMODE: 0 fp32 C | 1 bf16 row-major | 2 A-frag out | 3 A-frag out + atomic dots
//        4 bf16 row-major (via LDS transpose) + atomic dots
template<int ACT, bool HASBIAS, int OMODE>
__global__ __launch_bounds__(256) void k_mgemm(const unsigned short* __restrict__ Ahi,
                                               const unsigned short* __restrict__ Alo,
                                               const unsigned short* __restrict__ Bhi,
                                               const unsigned short* __restrict__ Blo,
                                               const float* __restrict__ bias,
                                               float* __restrict__ C,
                                               unsigned short* __restrict__ Cbf,
                                               unsigned short* __restrict__ foh,
                                               unsigned short* __restrict__ fol,
                                               const float* __restrict__ dwS,
                                               const float* __restrict__ dwD,
                                               float* __restrict__ dotS,
                                               float* __restrict__ dotD,
                                               int M, int Nd, int Kc, int Mc){
  int tid = threadIdx.x;
  int wid = tid >> 6, lane = tid & 63;
  int wm = wid >> 1, wn = wid & 1;
  int mcb = blockIdx.x*8 + wm*4;
  int ncb = blockIdx.y*4 + wn*2;

  f32x4 acc[4][2];
  #pragma unroll
  for(int f=0;f<4;f++)
    #pragma unroll
    for(int g=0;g<2;g++) acc[f][g] = (f32x4){0.f,0.f,0.f,0.f};

  for(int kc=0; kc<Kc; kc++){
    s16x8 ah[4], al[4], bh[2], bl[2];
    #pragma unroll
    for(int f=0;f<4;f++){
      int mcf = mcb + f; if(mcf > Mc-1) mcf = Mc-1;
      size_t off = ((size_t)mcf*Kc + kc)*512 + (size_t)lane*8;
      ah[f] = *(const s16x8*)(Ahi + off);
      al[f] = *(const s16x8*)(Alo + off);
    }
    #pragma unroll
    for(int g=0;g<2;g++){
      size_t off = ((size_t)(ncb+g)*Kc + kc)*512 + (size_t)lane*8;
      bh[g] = *(const s16x8*)(Bhi + off);
      bl[g] = *(const s16x8*)(Blo + off);
    }
    #pragma unroll
    for(int f=0;f<4;f++)
      #pragma unroll
      for(int g=0;g<2;g++){
        acc[f][g] = bmma(ah[f], bh[g], acc[f][g]);
        acc[f][g] = bmma(ah[f], bl[g], acc[f][g]);
        acc[f][g] = bmma(al[f], bh[g], acc[f][g]);
      }
  }

  if constexpr(OMODE <= 1){
    #pragma unroll
    for(int g=0;g<2;g++){
      int col = (ncb+g)*16 + (lane & 15);
      float bv = HASBIAS ? bias[col] : 0.f;
      #pragma unroll
      for(int f=0;f<4;f++){
        int row0 = (mcb+f)*16 + (lane>>4)*4;
        #pragma unroll
        for(int r=0;r<4;r++){
          int row = row0 + r;
          if(row < M){
            float v = acc[f][g][r] + bv;
            if(ACT) v = fmaxf(v, 0.f);
            if(OMODE==1) Cbf[(size_t)row*Nd + col] = f2bf(v);
            else         C  [(size_t)row*Nd + col] = v;
          }
        }
      }
    }
  } else {
    // transpose 64x32 wave tile via LDS -> row-contiguous o[8] per lane
    __shared__ float tile[4][64][33];
    #pragma unroll
    for(int g=0;g<2;g++){
      float bv = HASBIAS ? bias[(ncb+g)*16 + (lane&15)] : 0.f;
      int ck = g*16 + (lane & 15);
      #pragma unroll
      for(int f=0;f<4;f++){
        int rb = f*16 + (lane>>4)*4;
        #pragma unroll
        for(int r=0;r<4;r++){
          float v = acc[f][g][r] + bv;
          if(ACT) v = fmaxf(v, 0.f);
          tile[wid][rb + r][ck] = v;
        }
      }
    }
    asm volatile("" ::: "memory");
    int Kcn = Nd >> 5;
    int kcn = ncb >> 1;
    int rr = lane & 15, cb = lane >> 4;
    #pragma unroll
    for(int f=0;f<4;f++){
      int mcf = mcb + f;
      if(mcf >= Mc) continue;
      float o[8];
      #pragma unroll
      for(int j=0;j<8;j++) o[j] = tile[wid][f*16 + rr][cb*8 + j];
      if constexpr(OMODE == 4){
        u16x8 hb;
        #pragma unroll
        for(int j=0;j<8;j++) hb[j] = f2bf(o[j]);
        int row = mcf*16 + rr;
        *(u16x8*)(Cbf + (size_t)row*Nd + kcn*32 + cb*8) = hb;
      } else {
        u16x8 h, l;
        #pragma unroll
        for(int j=0;j<8;j++){
          unsigned short hb = f2bf(o[j]);
          h[j] = hb; l[j] = f2bf(o[j] - bf2f(hb));
        }
        size_t base = ((size_t)mcf*Kcn + kcn)*512 + (size_t)lane*8;
        *(u16x8*)(foh + base) = h;
        *(u16x8*)(fol + base) = l;
      }
      if constexpr(OMODE == 3 || OMODE == 4){
        float sv = 0.f, dv = 0.f;
        #pragma unroll
        for(int j=0;j<8;j++){
          int col = kcn*32 + cb*8 + j;
          sv += o[j]*dwS[col]; dv += o[j]*dwD[col];
        }
        sv += __shfl_xor(sv, 16); sv += __shfl_xor(sv, 32);
        dv += __shfl_xor(dv, 16); dv += __shfl_xor(dv, 32);
        if(cb == 0){
          int row = mcf*16 + rr;
          atomicAdd(dotS + row, sv);
          atomicAdd(dotD + row, dv);
        }
      }
    }
  }
}

// ---------------- GAT: wa = W @ a ----------------
template<int L>
__global__ __launch_bounds__(256) void k_wa(const float* __restrict__ W,
                                            const float* __restrict__ a_s, const float* __restrict__ a_d,
                                            float* __restrict__ wa_s, float* __restrict__ wa_d, int rows){
  int wid  = (int)((blockIdx.x*256u + threadIdx.x) >> 6);
  int lane = threadIdx.x & 63;
  if(wid >= rows) return;
  float s = 0.f, d = 0.f;
  #pragma unroll
  for(int j=0;j<L/64;j++){
    int c = lane + j*64;
    float v = W[(size_t)wid*L + c];
    s += v * a_s[c];
    d += v * a_d[c];
  }
  #pragma unroll
  for(int off=32; off; off>>=1){ s += __shfl_down(s, off); d += __shfl_down(d, off); }
  if(lane==0){ wa_s[wid] = s; wa_d[wid] = d; }
}

// ---------------- GAT1 pre-projection agg: D=128 bf16, quarter-wave, online softmax, frag out ----------------
__global__ __launch_bounds__(256) void k_gat1_aggpre(const unsigned short* __restrict__ hB,
                                                     const float* __restrict__ as_, const float* __restrict__ ad_,
                                                     const int* __restrict__ offs, const int* __restrict__ esrc,
                                                     unsigned short* __restrict__ fhi, unsigned short* __restrict__ flo,
                                                     int n){
  int wid  = (int)((blockIdx.x*256u + threadIdx.x) >> 6);
  int lane = threadIdx.x & 63;
  if(wid >= n) return;
  int q = lane >> 4, sub = lane & 15;
  float adi = ad_[wid];
  u16x8 rs = *(const u16x8*)(hB + (size_t)wid*128 + 8*sub);
  float m, S, acc[8];
  if(q == 0){
    m = lrelu(as_[wid] + adi); S = 1.f;
    #pragma unroll
    for(int k=0;k<8;k++) acc[k] = bf2f(rs[k]);
  } else {
    m = -3e38f; S = 0.f;
    #pragma unroll
    for(int k=0;k<8;k++) acc[k] = 0.f;
  }
  int e0 = offs[wid], e1 = offs[wid+1];
  int t = e0;
  for(; t+7 < e1; t += 8){
    int s0 = esrc[t + q], s1 = esrc[t + 4 + q];
    u16x8 r0 = *(const u16x8*)(hB + (size_t)s0*128 + 8*sub);
    u16x8 r1 = *(const u16x8*)(hB + (size_t)s1*128 + 8*sub);
    float l0 = lrelu(as_[s0] + adi), l1 = lrelu(as_[s1] + adi);
    float lm = fmaxf(l0, l1);
    if(lm > m + 8.f){
      float sc = __expf(m - lm); S *= sc;
      #pragma unroll
      for(int k=0;k<8;k++) acc[k] *= sc;
      m = lm;
    }
    float w0 = __expf(l0 - m), w1 = __expf(l1 - m);
    S += w0 + w1;
    #pragma unroll
    for(int k=0;k<8;k++) acc[k] += w0*bf2f(r0[k]) + w1*bf2f(r1[k]);
  }
  while(t < e1){
    int idx = t + q;
    bool ok = idx < e1;
    int s = esrc[ok ? idx : e0];
    u16x8 r = *(const u16x8*)(hB + (size_t)s*128 + 8*sub);
    float l = ok ? lrelu(as_[s] + adi) : -3e38f;
    if(l > m + 8.f){
      float sc = __expf(m - l); S *= sc;
      #pragma unroll
      for(int k=0;k<8;k++) acc[k] *= sc;
      m = l;
    }
    float w = __expf(l - m);
    S += w;
    #pragma unroll
    for(int k=0;k<8;k++) acc[k] += w*bf2f(r[k]);
    t += 4;
  }
  #pragma unroll
  for(int off=32; off>=16; off>>=1){
    float mo = __shfl_down(m, off), So = __shfl_down(S, off);
    float ao[8];
    #pragma unroll
    for(int k=0;k<8;k++) ao[k] = __shfl_down(acc[k], off);
    float M = fmaxf(m, mo);
    float sc0 = __expf(m - M), sc1 = __expf(mo - M);
    S = S*sc0 + So*sc1;
    #pragma unroll
    for(int k=0;k<8;k++) acc[k] = acc[k]*sc0 + ao[k]*sc1;
    m = M;
  }
  if(lane < 16){
    float inv = 1.f/(S + 1e-16f);
    u16x8 h, l;
    #pragma unroll
    for(int k=0;k<8;k++){
      float v = acc[k]*inv;
      unsigned short hb = f2bf(v);
      h[k] = hb; l[k] = f2bf(v - bf2f(hb));
    }
    int mc = wid >> 4;
    size_t base = ((size_t)(mc*4 + (sub>>2))*64 + (wid & 15) + (sub & 3)*16) * 8;
    *(u16x8*)(fhi + base) = h;
    *(u16x8*)(flo + base) = l;
  }
}

// ---------------- GAT2 agg: D=128, quarter-wave, online softmax, fp32 out ----------------
__global__ __launch_bounds__(256) void k_gat2_agg(const unsigned short* __restrict__ hP,
                                                  const float* __restrict__ as_, const float* __restrict__ ad_,
                                                  const int* __restrict__ offs, const int* __restrict__ esrc,
                                                  const float* __restrict__ bias, float* __restrict__ out, int n){
  int wid  = (int)((blockIdx.x*256u + threadIdx.x) >> 6);
  int lane = threadIdx.x & 63;
  if(wid >= n) return;
  int q = lane >> 4, sub = lane & 15;
  float adi = ad_[wid];
  u16x8 rs = *(const u16x8*)(hP + (size_t)wid*128 + 8*sub);
  float m, S, acc[8];
  if(q == 0){
    m = lrelu(as_[wid] + adi); S = 1.f;
    #pragma unroll
    for(int k=0;k<8;k++) acc[k] = bf2f(rs[k]);
  } else {
    m = -3e38f; S = 0.f;
    #pragma unroll
    for(int k=0;k<8;k++) acc[k] = 0.f;
  }
  int e0 = offs[wid], e1 = offs[wid+1];
  int t = e0;
  for(; t+7 < e1; t += 8){
    int s0 = esrc[t + q], s1 = esrc[t + 4 + q];
    u16x8 r0 = *(const u16x8*)(hP + (size_t)s0*128 + 8*sub);
    u16x8 r1 = *(const u16x8*)(hP + (size_t)s1*128 + 8*sub);
    float l0 = lrelu(as_[s0] + adi), l1 = lrelu(as_[s1] + adi);
    float lm = fmaxf(l0, l1);
    if(lm > m + 8.f){
      float sc = __expf(m - lm); S *= sc;
      #pragma unroll
      for(int k=0;k<8;k++) acc[k] *= sc;
      m = lm;
    }
    float w0 = __expf(l0 - m), w1 = __expf(l1 - m);
    S += w0 + w1;
    #pragma unroll
    for(int k=0;k<8;k++) acc[k] += w0*bf2f(r0[k]) + w1*bf2f(r1[k]);
  }
  while(t < e1){
    int idx = t + q;
    bool ok = idx < e1;
    int s = esrc[ok ? idx : e0];
    u16x8 r = *(const u16x8*)(hP + (size_t)s*128 + 8*sub);
    float l = ok ? lrelu(as_[s] + adi) : -3e38f;
    if(l > m + 8.f){
      float sc = __expf(m - l); S *= sc;
      #pragma unroll
      for(int k=0;k<8;k++) acc[k] *= sc;
      m = l;
    }
    float w = __expf(l - m);
    S += w;
    #pragma unroll
    for(int k=0;k<8;k++) acc[k] += w*bf2f(r[k]);
    t += 4;
  }
  #pragma unroll
  for(int off=32; off>=16; off>>=1){
    float mo = __shfl_down(m, off), So = __shfl_down(S, off);
    float ao[8];
    #pragma unroll
    for(int k=0;k<8;k++) ao[k] = __shfl_down(acc[k], off);
    float M = fmaxf(m, mo);
    float sc0 = __expf(m - M), sc1 = __expf(mo - M);
    S = S*sc0 + So*sc1;
    #pragma unroll
    for(int k=0;k<8;k++) acc[k] = acc[k]*sc0 + ao[k]*sc1;
    m = M;
  }
  if(lane < 16){
    float inv = 1.f/(S + 1e-16f);
    float4 o0, o1;
    o0.x = acc[0]*inv + bias[8*sub  ]; o0.y = acc[1]*inv + bias[8*sub+1];
    o0.z = acc[2]*inv + bias[8*sub+2]; o0.w = acc[3]*inv + bias[8*sub+3];
    o1.x = acc[4]*inv + bias[8*sub+4]; o1.y = acc[5]*inv + bias[8*sub+5];
    o1.z = acc[6]*inv + bias[8*sub+6]; o1.w = acc[7]*inv + bias[8*sub+7];
    *(float4*)(out + (size_t)wid*128 + 8*sub)     = o0;
    *(float4*)(out + (size_t)wid*128 + 8*sub + 4) = o1;
  }
}

extern "C" void kernel_launch(void* const* d_in, const int* in_sizes, int n_in,
                              void* d_out, int out_size, void* d_ws, size_t ws_size,
                              hipStream_t stream){
  const float* x        = (const float*)d_in[0];
  const int*   ei       = (const int*)  d_in[1];
  const float* gin1_w1  = (const float*)d_in[3];
  const float* gin1_b1  = (const float*)d_in[4];
  const float* gin1_w2  = (const float*)d_in[5];
  const float* gin1_b2  = (const float*)d_in[6];
  const float* gin2_w1  = (const float*)d_in[7];
  const float* gin2_b1  = (const float*)d_in[8];
  const float* gin2_w2  = (const float*)d_in[9];
  const float* gin2_b2  = (const float*)d_in[10];
  const float* gat1_w   = (const float*)d_in[11];
  const float* gat1_as  = (const float*)d_in[12];
  const float* gat1_ad  = (const float*)d_in[13];
  const float* gat1_b   = (const float*)d_in[14];
  const float* gat2_w   = (const float*)d_in[15];
  const float* gat2_as  = (const float*)d_in[16];
  const float* gat2_ad  = (const float*)d_in[17];
  const float* gat2_b   = (const float*)d_in[18];

  const int n = in_sizes[0] / 10;
  const int E = in_sizes[1] / 2;
  const int* src = ei;
  const int* dst = ei + E;
  const int Mc = (n + 15) / 16;
  const int nb = (n + 1023) / 1024;
  const size_t npad = ((size_t)n*4 + 255) & ~(size_t)255;

  char* w = (char*)d_ws;
  auto carve = [&](size_t bytes)->char*{ char* p = w; w += (bytes + 255) & ~(size_t)255; return p; };
  int*   esrc = (int*)  carve((size_t)E*4);
  int*   offs = (int*)  carve((size_t)(n+1)*4);
  int*   deg  = (int*)  carve(npad);          // deg & cur contiguous -> one memset
  int*   cur  = (int*)  carve(npad);
  int*   part = (int*)  carve((size_t)n*4);
  int*   bsum = (int*)  carve((size_t)1024*4);
  unsigned short* Ybf   = (unsigned short*)carve((size_t)n*64*2);
  unsigned short* Hbf   = (unsigned short*)carve((size_t)n*64*2);
  unsigned short* hB2bf = (unsigned short*)carve((size_t)n*128*2);
  unsigned short* Pbf2  = (unsigned short*)carve((size_t)n*128*2);
  float* as_  = (float*)carve((size_t)n*4);
  float* ad_  = (float*)carve((size_t)n*4);
  float* as2_ = (float*)carve((size_t)n*4);
  float* ad2_ = (float*)carve((size_t)n*4);
  float* waS  = (float*)carve(256*4);
  float* waD  = (float*)carve(256*4);
  float* waS2 = (float*)carve(256*4);
  float* waD2 = (float*)carve(256*4);
  unsigned short* FAh = (unsigned short*)carve((size_t)Mc*8*512*2);
  unsigned short* FAl = (unsigned short*)carve((size_t)Mc*8*512*2);
  unsigned short* FBh = (unsigned short*)carve((size_t)Mc*8*512*2);
  unsigned short* FBl = (unsigned short*)carve((size_t)Mc*8*512*2);
  unsigned short* BfH = (unsigned short*)carve((size_t)64*512*2);
  unsigned short* BfL = (unsigned short*)carve((size_t)64*512*2);

  const int TPB = 256;
  int ebk = (E + TPB - 1) / TPB;
  int wbk = (n + 3) / 4;
  int gx  = (Mc + 7) / 8;

  // CSR build (+ zero logit accumulators in scan3)
  hipMemsetAsync(deg, 0, npad*2, stream);
  k_deg<<<ebk, TPB, 0, stream>>>(dst, deg, E);
  k_scan1<<<nb, 1024, 0, stream>>>(deg, part, bsum, n);
  k_scan2<<<1, 1024, 0, stream>>>(bsum, nb);
  k_scan3<<<(n + 1023)/1024, 1024, 0, stream>>>(part, bsum, offs, as_, ad_, as2_, ad2_, n, E);
  k_fill<<<ebk, TPB, 0, stream>>>(src, dst, offs, cur, esrc, E);

  // folded attention vectors
  k_wa<256><<<(128+3)/4, TPB, 0, stream>>>(gat1_w, gat1_as, gat1_ad, waS, waD, 128);
  k_wa<128><<<(256+3)/4, TPB, 0, stream>>>(gat2_w, gat2_as, gat2_ad, waS2, waD2, 256);

  // GIN1 (projection-first): y = x@W1 -> Ybf bf16 row-major;
  //   agg(Ybf) +b1 +relu -> FB frags (Kc=2); 64->64 +b2+relu -> Hbf bf16 row-major
  k_prepA<<<(Mc*1*64 + 255)/256, 256, 0, stream>>>(x, FAh, FAl, n, 10, Mc, 1);
  k_prepB<<<(4*1*64 + 255)/256, 256, 0, stream>>>(gin1_w1, BfH, BfL, 10, 64, 1, 4);
  k_mgemm<0,false,1><<<dim3(gx,1), TPB, 0, stream>>>(FAh, FAl, BfH, BfL, nullptr,
      nullptr, Ybf, nullptr, nullptr, nullptr, nullptr, nullptr, nullptr, n, 64, 1, Mc);
  k_gin_agg<true><<<wbk, TPB, 0, stream>>>(Ybf, offs, esrc, gin1_b1, FBh, FBl, n);
  k_prepB<<<(4*2*64 + 255)/256, 256, 0, stream>>>(gin1_w2, BfH, BfL, 64, 64, 2, 4);
  k_mgemm<1,true,1><<<dim3(gx,1), TPB, 0, stream>>>(FBh, FBl, BfH, BfL, gin1_b2,
      nullptr, Hbf, nullptr, nullptr, nullptr, nullptr, nullptr, nullptr, n, 64, 2, Mc);

  // GIN2: agg(Hbf) -> FA frags (Kc=2); 64->128 relu -> FB frags (Kcn=4);
  //       128->128 +bias -> hB2bf row-major + GAT1 logits (atomic dots)
  k_gin_agg<false><<<wbk, TPB, 0, stream>>>(Hbf, offs, esrc, nullptr, FAh, FAl, n);
  k_prepB<<<(8*2*64 + 255)/256, 256, 0, stream>>>(gin2_w1, BfH, BfL, 64, 128, 2, 8);
  k_mgemm<1,true,2><<<dim3(gx,2), TPB, 0, stream>>>(FAh, FAl, BfH, BfL, gin2_b1,
      nullptr, nullptr, FBh, FBl, nullptr, nullptr, nullptr, nullptr, n, 128, 2, Mc);
  k_prepB<<<(8*4*64 + 255)/256, 256, 0, stream>>>(gin2_w2, BfH, BfL, 128, 128, 4, 8);
  k_mgemm<0,true,4><<<dim3(gx,2), TPB, 0, stream>>>(FBh, FBl, BfH, BfL, gin2_b2,
      nullptr, hB2bf, nullptr, nullptr, waS, waD, as_, ad_, n, 128, 4, Mc);

  // GAT1: pre-projection fused agg+softmax (256B/edge) -> FA frags (Kc=4);
  //       proj 128->256 +bias+relu -> FB frags (Kcn=8) + GAT2 logits (atomic dots)
  k_gat1_aggpre<<<wbk, TPB, 0, stream>>>(hB2bf, as_, ad_, offs, esrc, FAh, FAl, n);
  k_prepB<<<(16*4*64 + 255)/256, 256, 0, stream>>>(gat1_w, BfH, BfL, 128, 256, 4, 16);
  k_mgemm<1,true,3><<<dim3(gx,4), TPB, 0, stream>>>(FAh, FAl, BfH, BfL, gat1_b,
      nullptr, nullptr, FBh, FBl, waS2, waD2, as2_, ad2_, n, 256, 4, Mc);

  // GAT2: proj 256->128 -> Pbf2; fused agg+softmax -> d_out
  k_prepB<<<(8*8*64 + 255)/256, 256, 0, stream>>>(gat2_w, BfH, BfL, 256, 128, 8, 8);
  k_mgemm<0,false,1><<<dim3(gx,2), TPB, 0, stream>>>(FBh, FBl, BfH, BfL, nullptr,
      nullptr, Pbf2, nullptr, nullptr, nullptr, nullptr, nullptr, nullptr, n, 128, 8, Mc);
  k_gat2_agg<<<wbk, TPB, 0, stream>>>(Pbf2, as2_, ad2_, offs, esrc, gat2_b, (float*)d_out, n);
}

// Round 11
// 334.055 us; speedup vs baseline: 3.0012x; 1.0273x over previous
//
#include <hip/hip_runtime.h>
#include <math.h>

__device__ __forceinline__ float lrelu(float x){ return x > 0.f ? x : 0.2f*x; }

typedef short s16x8 __attribute__((ext_vector_type(8)));
typedef float f32x4 __attribute__((ext_vector_type(4)));
typedef unsigned short u16x8 __attribute__((ext_vector_type(8)));

__device__ __forceinline__ f32x4 bmma(s16x8 a, s16x8 b, f32x4 c){
  return __builtin_amdgcn_mfma_f32_16x16x32_bf16(a, b, c, 0, 0, 0);
}

__device__ __forceinline__ unsigned short f2bf(float f){
  unsigned u = __float_as_uint(f);
  unsigned r = (u + 0x7fffu + ((u >> 16) & 1u)) >> 16;
  return (unsigned short)r;
}
__device__ __forceinline__ float bf2f(unsigned short h){
  return __uint_as_float(((unsigned)h) << 16);
}

// ---------------- CSR build ----------------
__global__ void k_deg(const int* __restrict__ dst, int* __restrict__ deg, int E){
  int e = blockIdx.x*blockDim.x + threadIdx.x;
  if(e < E) atomicAdd(&deg[dst[e]], 1);
}

__global__ __launch_bounds__(1024) void k_scan1(const int* __restrict__ deg,
                                                int* __restrict__ part,
                                                int* __restrict__ bsum, int n){
  int i = blockIdx.x*1024 + threadIdx.x;
  int lane = threadIdx.x & 63, wv = threadIdx.x >> 6;
  int v = (i < n) ? deg[i] : 0;
  int s = v;
  #pragma unroll
  for(int off=1; off<64; off<<=1){
    int t = __shfl_up(s, off);
    if(lane >= off) s += t;
  }
  __shared__ int wsum[16];
  if(lane==63) wsum[wv] = s;
  __syncthreads();
  if(wv==0 && lane<16){
    int t = wsum[lane], ss = t;
    #pragma unroll
    for(int off=1; off<16; off<<=1){
      int u = __shfl_up(ss, off);
      if(lane >= off) ss += u;
    }
    wsum[lane] = ss - t;
    if(lane==15) bsum[blockIdx.x] = ss;
  }
  __syncthreads();
  if(i < n) part[i] = s - v + wsum[wv];
}

__global__ __launch_bounds__(1024) void k_scan2(int* __restrict__ bsum, int nb){
  int i = threadIdx.x;
  int lane = i & 63, wv = i >> 6;
  int v = (i < nb) ? bsum[i] : 0;
  int s = v;
  #pragma unroll
  for(int off=1; off<64; off<<=1){
    int t = __shfl_up(s, off);
    if(lane >= off) s += t;
  }
  __shared__ int wsum[16];
  if(lane==63) wsum[wv] = s;
  __syncthreads();
  if(wv==0 && lane<16){
    int t = wsum[lane], ss = t;
    #pragma unroll
    for(int off=1; off<16; off<<=1){
      int u = __shfl_up(ss, off);
      if(lane >= off) ss += u;
    }
    wsum[lane] = ss - t;
  }
  __syncthreads();
  if(i < nb) bsum[i] = s - v + wsum[wv];
}

// also zero-inits the 4 logit accumulators (used later by atomic dots)
__global__ void k_scan3(const int* __restrict__ part, const int* __restrict__ bsum,
                        int* __restrict__ offs,
                        float* __restrict__ z0, float* __restrict__ z1,
                        float* __restrict__ z2, float* __restrict__ z3,
                        int n, int E){
  int i = blockIdx.x*blockDim.x + threadIdx.x;
  if(i < n){
    offs[i] = part[i] + bsum[i >> 10];
    z0[i] = 0.f; z1[i] = 0.f; z2[i] = 0.f; z3[i] = 0.f;
  }
  if(i == 0) offs[n] = E;
}

// range-restricted placement pass: only edges with dst in [lo,hi) are placed.
// Keeps the live scatter region small enough to stay L2-resident -> writes merge.
__global__ void k_fill(const int* __restrict__ src, const int* __restrict__ dst,
                       const int* __restrict__ offs, int* __restrict__ cur,
                       int* __restrict__ esrc, int E, int lo, int hi){
  int e = blockIdx.x*blockDim.x + threadIdx.x;
  if(e < E){
    int d = dst[e];
    if(d >= lo && d < hi){
      int pos = offs[d] + atomicAdd(&cur[d], 1);
      esrc[pos] = src[e];
    }
  }
}

// ---------------- GIN agg: bf16 rows D=64, eighth-wave split, frag-epilogue ----------------
template<bool BR>
__global__ __launch_bounds__(256) void k_gin_agg(const unsigned short* __restrict__ xin,
                                                 const int* __restrict__ offs,
                                                 const int* __restrict__ esrc,
                                                 const float* __restrict__ bias,
                                                 unsigned short* __restrict__ fhi,
                                                 unsigned short* __restrict__ flo, int n){
  int wid  = (int)((blockIdx.x*256u + threadIdx.x) >> 6);
  int lane = threadIdx.x & 63;
  if(wid >= n) return;
  int g = lane >> 3, sub = lane & 7;
  float acc[8];
  #pragma unroll
  for(int k=0;k<8;k++) acc[k] = 0.f;
  int e0 = offs[wid], e1 = offs[wid+1];
  int t = e0;
  for(; t+15 < e1; t += 16){
    int sA = esrc[t + g], sB = esrc[t + 8 + g];
    u16x8 rA = *(const u16x8*)(xin + (size_t)sA*64 + 8*sub);
    u16x8 rB = *(const u16x8*)(xin + (size_t)sB*64 + 8*sub);
    #pragma unroll
    for(int k=0;k<8;k++) acc[k] += bf2f(rA[k]) + bf2f(rB[k]);
  }
  for(; t+7 < e1; t += 8){
    int s = esrc[t + g];
    u16x8 r = *(const u16x8*)(xin + (size_t)s*64 + 8*sub);
    #pragma unroll
    for(int k=0;k<8;k++) acc[k] += bf2f(r[k]);
  }
  if(t < e1){
    int idx = t + g;
    bool ok = idx < e1;
    int s = esrc[ok ? idx : e0];
    u16x8 r = *(const u16x8*)(xin + (size_t)s*64 + 8*sub);
    float w = ok ? 1.f : 0.f;
    #pragma unroll
    for(int k=0;k<8;k++) acc[k] += w*bf2f(r[k]);
  }
  #pragma unroll
  for(int off=32; off>=8; off>>=1)
    #pragma unroll
    for(int k=0;k<8;k++) acc[k] += __shfl_down(acc[k], off);
  if(lane < 8){
    u16x8 rs = *(const u16x8*)(xin + (size_t)wid*64 + 8*sub);
    u16x8 h, l;
    #pragma unroll
    for(int k=0;k<8;k++){
      float o = acc[k] + bf2f(rs[k]);
      if(BR) o = fmaxf(o + bias[8*sub + k], 0.f);
      unsigned short hb = f2bf(o);
      h[k] = hb; l[k] = f2bf(o - bf2f(hb));
    }
    int mc = wid >> 4;
    size_t base = ((size_t)(mc*2 + (sub>>2))*64 + (wid & 15) + (sub & 3)*16) * 8;
    *(u16x8*)(fhi + base) = h;
    *(u16x8*)(flo + base) = l;
  }
}

// ---------------- split-bf16 fragment prep (A from fp32, x only) ----------------
__global__ __launch_bounds__(256) void k_prepA(const float* __restrict__ A,
                                               unsigned short* __restrict__ hi,
                                               unsigned short* __restrict__ lo,
                                               int M, int K, int Mc, int Kc){
  int gid = blockIdx.x*256 + threadIdx.x;
  int lane = gid & 63;
  int fid  = gid >> 6;
  if(fid >= Mc*Kc) return;
  int mc = fid / Kc, kc = fid - mc*Kc;
  int row = mc*16 + (lane & 15);
  int k0  = kc*32 + (lane >> 4)*8;
  s16x8 h, l;
  if(row < M){
    const float* ap = A + (size_t)row*K + k0;
    #pragma unroll
    for(int j=0;j<8;j++){
      float v = (k0 + j < K) ? ap[j] : 0.f;
      unsigned short hb = f2bf(v);
      float r = v - bf2f(hb);
      h[j] = (short)hb; l[j] = (short)f2bf(r);
    }
  } else {
    #pragma unroll
    for(int j=0;j<8;j++){ h[j]=0; l[j]=0; }
  }
  size_t off = (size_t)fid*512 + (size_t)lane*8;
  *(s16x8*)(hi + off) = h;
  *(s16x8*)(lo + off) = l;
}

// ---------------- all 6 weight matrices -> one fragment arena ----------------
// frag layout: [fid][lane][8]; cum frag offsets: W0=0 W1=4 W2=12 W3=28 W4=60 W5=124, total 188
__global__ __launch_bounds__(256) void k_prepB_all(const float* __restrict__ B0,
                                                   const float* __restrict__ B1,
                                                   const float* __restrict__ B2,
                                                   const float* __restrict__ B3,
                                                   const float* __restrict__ B4,
                                                   const float* __restrict__ B5,
                                                   unsigned short* __restrict__ hi,
                                                   unsigned short* __restrict__ lo){
  int gid = blockIdx.x*256 + threadIdx.x;
  int lane = gid & 63;
  int fid  = gid >> 6;
  if(fid >= 188) return;
  const float* B; int K, Nd, Kc, fl;
  if(fid < 4)       { B=B0; K=10;  Nd=64;  Kc=1; fl=fid;     }
  else if(fid < 12) { B=B1; K=64;  Nd=64;  Kc=2; fl=fid-4;   }
  else if(fid < 28) { B=B2; K=64;  Nd=128; Kc=2; fl=fid-12;  }
  else if(fid < 60) { B=B3; K=128; Nd=128; Kc=4; fl=fid-28;  }
  else if(fid < 124){ B=B4; K=128; Nd=256; Kc=4; fl=fid-60;  }
  else              { B=B5; K=256; Nd=128; Kc=8; fl=fid-124; }
  int nc = fl / Kc, kc = fl - nc*Kc;
  int col = nc*16 + (lane & 15);
  int k0  = kc*32 + (lane >> 4)*8;
  s16x8 h, l;
  #pragma unroll
  for(int j=0;j<8;j++){
    int k = k0 + j;
    float v = (k < K) ? B[(size_t)k*Nd + col] : 0.f;
    unsigned short hb = f2bf(v);
    float r = v - bf2f(hb);
    h[j] = (short)hb; l[j] = (short)f2bf(r);
  }
  size_t off = (size_t)fid*512 + (size_t)lane*8;
  *(s16x8*)(hi + off) = h;
  *(s16x8*)(lo + off) = l;
}

// ---------------- split-bf16 MFMA GEMM ----------------
// OMODE: 0 fp32 C | 1 bf16 row-major | 2 A-frag out | 3 A-frag out + atomic dots
//        4 bf16 row-major (via LDS transpose) + atomic dots
template<int ACT, bool HASBIAS, int OMODE>
__global__ __launch_bounds__(256) void k_mgemm(const unsigned short* __restrict__ Ahi,
                                               const unsigned short* __restrict__ Alo,
                                               const unsigned short* __restrict__ Bhi,
                                               const unsigned short* __restrict__ Blo,
                                               const float* __restrict__ bias,
                                               float* __restrict__ C,
                                               unsigned short* __restrict__ Cbf,
                                               unsigned short* __restrict__ foh,
                                               unsigned short* __restrict__ fol,
                                               const float* __restrict__ dwS,
                                               const float* __restrict__ dwD,
                                               float* __restrict__ dotS,
                                               float* __restrict__ dotD,
                                               int M, int Nd, int Kc, int Mc){
  int tid = threadIdx.x;
  int wid = tid >> 6, lane = tid & 63;
  int wm = wid >> 1, wn = wid & 1;
  int mcb = blockIdx.x*8 + wm*4;
  int ncb = blockIdx.y*4 + wn*2;

  f32x4 acc[4][2];
  #pragma unroll
  for(int f=0;f<4;f++)
    #pragma unroll
    for(int g=0;g<2;g++) acc[f][g] = (f32x4){0.f,0.f,0.f,0.f};

  for(int kc=0; kc<Kc; kc++){
    s16x8 ah[4], al[4], bh[2], bl[2];
    #pragma unroll
    for(int f=0;f<4;f++){
      int mcf = mcb + f; if(mcf > Mc-1) mcf = Mc-1;
      size_t off = ((size_t)mcf*Kc + kc)*512 + (size_t)lane*8;
      ah[f] = *(const s16x8*)(Ahi + off);
      al[f] = *(const s16x8*)(Alo + off);
    }
    #pragma unroll
    for(int g=0;g<2;g++){
      size_t off = ((size_t)(ncb+g)*Kc + kc)*512 + (size_t)lane*8;
      bh[g] = *(const s16x8*)(Bhi + off);
      bl[g] = *(const s16x8*)(Blo + off);
    }
    #pragma unroll
    for(int f=0;f<4;f++)
      #pragma unroll
      for(int g=0;g<2;g++){
        acc[f][g] = bmma(ah[f], bh[g], acc[f][g]);
        acc[f][g] = bmma(ah[f], bl[g], acc[f][g]);
        acc[f][g] = bmma(al[f], bh[g], acc[f][g]);
      }
  }

  if constexpr(OMODE <= 1){
    #pragma unroll
    for(int g=0;g<2;g++){
      int col = (ncb+g)*16 + (lane & 15);
      float bv = HASBIAS ? bias[col] : 0.f;
      #pragma unroll
      for(int f=0;f<4;f++){
        int row0 = (mcb+f)*16 + (lane>>4)*4;
        #pragma unroll
        for(int r=0;r<4;r++){
          int row = row0 + r;
          if(row < M){
            float v = acc[f][g][r] + bv;
            if(ACT) v = fmaxf(v, 0.f);
            if(OMODE==1) Cbf[(size_t)row*Nd + col] = f2bf(v);
            else         C  [(size_t)row*Nd + col] = v;
          }
        }
      }
    }
  } else {
    // transpose 64x32 wave tile via LDS -> row-contiguous o[8] per lane
    __shared__ float tile[4][64][33];
    #pragma unroll
    for(int g=0;g<2;g++){
      float bv = HASBIAS ? bias[(ncb+g)*16 + (lane&15)] : 0.f;
      int ck = g*16 + (lane & 15);
      #pragma unroll
      for(int f=0;f<4;f++){
        int rb = f*16 + (lane>>4)*4;
        #pragma unroll
        for(int r=0;r<4;r++){
          float v = acc[f][g][r] + bv;
          if(ACT) v = fmaxf(v, 0.f);
          tile[wid][rb + r][ck] = v;
        }
      }
    }
    asm volatile("" ::: "memory");
    int Kcn = Nd >> 5;
    int kcn = ncb >> 1;
    int rr = lane & 15, cb = lane >> 4;
    #pragma unroll
    for(int f=0;f<4;f++){
      int mcf = mcb + f;
      if(mcf >= Mc) continue;
      float o[8];
      #pragma unroll
      for(int j=0;j<8;j++) o[j] = tile[wid][f*16 + rr][cb*8 + j];
      if constexpr(OMODE == 4){
        u16x8 hb;
        #pragma unroll
        for(int j=0;j<8;j++) hb[j] = f2bf(o[j]);
        int row = mcf*16 + rr;
        *(u16x8*)(Cbf + (size_t)row*Nd + kcn*32 + cb*8) = hb;
      } else {
        u16x8 h, l;
        #pragma unroll
        for(int j=0;j<8;j++){
          unsigned short hb = f2bf(o[j]);
          h[j] = hb; l[j] = f2bf(o[j] - bf2f(hb));
        }
        size_t base = ((size_t)mcf*Kcn + kcn)*512 + (size_t)lane*8;
        *(u16x8*)(foh + base) = h;
        *(u16x8*)(fol + base) = l;
      }
      if constexpr(OMODE == 3 || OMODE == 4){
        float sv = 0.f, dv = 0.f;
        #pragma unroll
        for(int j=0;j<8;j++){
          int col = kcn*32 + cb*8 + j;
          sv += o[j]*dwS[col]; dv += o[j]*dwD[col];
        }
        sv += __shfl_xor(sv, 16); sv += __shfl_xor(sv, 32);
        dv += __shfl_xor(dv, 16); dv += __shfl_xor(dv, 32);
        if(cb == 0){
          int row = mcf*16 + rr;
          atomicAdd(dotS + row, sv);
          atomicAdd(dotD + row, dv);
        }
      }
    }
  }
}

// ---------------- both folded attention vectors in one kernel ----------------
// waves 0..127:  W1[128x256] rows; waves 128..383: W2[256x128] rows
__global__ __launch_bounds__(256) void k_wa2(const float* __restrict__ W1,
                                             const float* __restrict__ a1s, const float* __restrict__ a1d,
                                             const float* __restrict__ W2,
                                             const float* __restrict__ a2s, const float* __restrict__ a2d,
                                             float* __restrict__ o1s, float* __restrict__ o1d,
                                             float* __restrict__ o2s, float* __restrict__ o2d){
  int wid  = (int)((blockIdx.x*256u + threadIdx.x) >> 6);
  int lane = threadIdx.x & 63;
  float s = 0.f, d = 0.f;
  if(wid < 128){
    #pragma unroll
    for(int j=0;j<4;j++){
      int c = lane + j*64;
      float v = W1[(size_t)wid*256 + c];
      s += v * a1s[c]; d += v * a1d[c];
    }
  } else if(wid < 384){
    int r = wid - 128;
    #pragma unroll
    for(int j=0;j<2;j++){
      int c = lane + j*64;
      float v = W2[(size_t)r*128 + c];
      s += v * a2s[c]; d += v * a2d[c];
    }
  } else return;
  #pragma unroll
  for(int off=32; off; off>>=1){ s += __shfl_down(s, off); d += __shfl_down(d, off); }
  if(lane==0){
    if(wid < 128){ o1s[wid] = s; o1d[wid] = d; }
    else         { o2s[wid-128] = s; o2d[wid-128] = d; }
  }
}

// ---------------- GAT1 pre-projection agg: D=128 bf16, quarter-wave, online softmax, frag out ----------------
__global__ __launch_bounds__(256) void k_gat1_aggpre(const unsigned short* __restrict__ hB,
                                                     const float* __restrict__ as_, const float* __restrict__ ad_,
                                                     const int* __restrict__ offs, const int* __restrict__ esrc,
                                                     unsigned short* __restrict__ fhi, unsigned short* __restrict__ flo,
                                                     int n){
  int wid  = (int)((blockIdx.x*256u + threadIdx.x) >> 6);
  int lane = threadIdx.x & 63;
  if(wid >= n) return;
  int q = lane >> 4, sub = lane & 15;
  float adi = ad_[wid];
  u16x8 rs = *(const u16x8*)(hB + (size_t)wid*128 + 8*sub);
  float m, S, acc[8];
  if(q == 0){
    m = lrelu(as_[wid] + adi); S = 1.f;
    #pragma unroll
    for(int k=0;k<8;k++) acc[k] = bf2f(rs[k]);
  } else {
    m = -3e38f; S = 0.f;
    #pragma unroll
    for(int k=0;k<8;k++) acc[k] = 0.f;
  }
  int e0 = offs[wid], e1 = offs[wid+1];
  int t = e0;
  for(; t+15 < e1; t += 16){
    int s0 = esrc[t + q], s1 = esrc[t + 4 + q], s2 = esrc[t + 8 + q], s3 = esrc[t + 12 + q];
    u16x8 r0 = *(const u16x8*)(hB + (size_t)s0*128 + 8*sub);
    u16x8 r1 = *(const u16x8*)(hB + (size_t)s1*128 + 8*sub);
    u16x8 r2 = *(const u16x8*)(hB + (size_t)s2*128 + 8*sub);
    u16x8 r3 = *(const u16x8*)(hB + (size_t)s3*128 + 8*sub);
    float l0 = lrelu(as_[s0] + adi), l1 = lrelu(as_[s1] + adi);
    float l2 = lrelu(as_[s2] + adi), l3 = lrelu(as_[s3] + adi);
    float lm = fmaxf(fmaxf(l0, l1), fmaxf(l2, l3));
    if(lm > m + 8.f){
      float sc = __expf(m - lm); S *= sc;
      #pragma unroll
      for(int k=0;k<8;k++) acc[k] *= sc;
      m = lm;
    }
    float w0 = __expf(l0 - m), w1 = __expf(l1 - m), w2 = __expf(l2 - m), w3 = __expf(l3 - m);
    S += w0 + w1 + w2 + w3;
    #pragma unroll
    for(int k=0;k<8;k++)
      acc[k] += w0*bf2f(r0[k]) + w1*bf2f(r1[k]) + w2*bf2f(r2[k]) + w3*bf2f(r3[k]);
  }
  for(; t+7 < e1; t += 8){
    int s0 = esrc[t + q], s1 = esrc[t + 4 + q];
    u16x8 r0 = *(const u16x8*)(hB + (size_t)s0*128 + 8*sub);
    u16x8 r1 = *(const u16x8*)(hB + (size_t)s1*128 + 8*sub);
    float l0 = lrelu(as_[s0] + adi), l1 = lrelu(as_[s1] + adi);
    float lm = fmaxf(l0, l1);
    if(lm > m + 8.f){
      float sc = __expf(m - lm); S *= sc;
      #pragma unroll
      for(int k=0;k<8;k++) acc[k] *= sc;
      m = lm;
    }
    float w0 = __expf(l0 - m), w1 = __expf(l1 - m);
    S += w0 + w1;
    #pragma unroll
    for(int k=0;k<8;k++) acc[k] += w0*bf2f(r0[k]) + w1*bf2f(r1[k]);
  }
  while(t < e1){
    int idx = t + q;
    bool ok = idx < e1;
    int s = esrc[ok ? idx : e0];
    u16x8 r = *(const u16x8*)(hB + (size_t)s*128 + 8*sub);
    float l = ok ? lrelu(as_[s] + adi) : -3e38f;
    if(l > m + 8.f){
      float sc = __expf(m - l); S *= sc;
      #pragma unroll
      for(int k=0;k<8;k++) acc[k] *= sc;
      m = l;
    }
    float w = __expf(l - m);
    S += w;
    #pragma unroll
    for(int k=0;k<8;k++) acc[k] += w*bf2f(r[k]);
    t += 4;
  }
  #pragma unroll
  for(int off=32; off>=16; off>>=1){
    float mo = __shfl_down(m, off), So = __shfl_down(S, off);
    float ao[8];
    #pragma unroll
    for(int k=0;k<8;k++) ao[k] = __shfl_down(acc[k], off);
    float M = fmaxf(m, mo);
    float sc0 = __expf(m - M), sc1 = __expf(mo - M);
    S = S*sc0 + So*sc1;
    #pragma unroll
    for(int k=0;k<8;k++) acc[k] = acc[k]*sc0 + ao[k]*sc1;
    m = M;
  }
  if(lane < 16){
    float inv = 1.f/(S + 1e-16f);
    u16x8 h, l;
    #pragma unroll
    for(int k=0;k<8;k++){
      float v = acc[k]*inv;
      unsigned short hb = f2bf(v);
      h[k] = hb; l[k] = f2bf(v - bf2f(hb));
    }
    int mc = wid >> 4;
    size_t base = ((size_t)(mc*4 + (sub>>2))*64 + (wid & 15) + (sub & 3)*16) * 8;
    *(u16x8*)(fhi + base) = h;
    *(u16x8*)(flo + base) = l;
  }
}

// ---------------- GAT2 agg: D=128, quarter-wave, online softmax, fp32 out ----------------
__global__ __launch_bounds__(256) void k_gat2_agg(const unsigned short* __restrict__ hP,
                                                  const float* __restrict__ as_, const float* __restrict__ ad_,
                                                  const int* __restrict__ offs, const int* __restrict__ esrc,
                                                  const float* __restrict__ bias, float* __restrict__ out, int n){
  int wid  = (int)((blockIdx.x*256u + threadIdx.x) >> 6);
  int lane = threadIdx.x & 63;
  if(wid >= n) return;
  int q = lane >> 4, sub = lane & 15;
  float adi = ad_[wid];
  u16x8 rs = *(const u16x8*)(hP + (size_t)wid*128 + 8*sub);
  float m, S, acc[8];
  if(q == 0){
    m = lrelu(as_[wid] + adi); S = 1.f;
    #pragma unroll
    for(int k=0;k<8;k++) acc[k] = bf2f(rs[k]);
  } else {
    m = -3e38f; S = 0.f;
    #pragma unroll
    for(int k=0;k<8;k++) acc[k] = 0.f;
  }
  int e0 = offs[wid], e1 = offs[wid+1];
  int t = e0;
  for(; t+15 < e1; t += 16){
    int s0 = esrc[t + q], s1 = esrc[t + 4 + q], s2 = esrc[t + 8 + q], s3 = esrc[t + 12 + q];
    u16x8 r0 = *(const u16x8*)(hP + (size_t)s0*128 + 8*sub);
    u16x8 r1 = *(const u16x8*)(hP + (size_t)s1*128 + 8*sub);
    u16x8 r2 = *(const u16x8*)(hP + (size_t)s2*128 + 8*sub);
    u16x8 r3 = *(const u16x8*)(hP + (size_t)s3*128 + 8*sub);
    float l0 = lrelu(as_[s0] + adi), l1 = lrelu(as_[s1] + adi);
    float l2 = lrelu(as_[s2] + adi), l3 = lrelu(as_[s3] + adi);
    float lm = fmaxf(fmaxf(l0, l1), fmaxf(l2, l3));
    if(lm > m + 8.f){
      float sc = __expf(m - lm); S *= sc;
      #pragma unroll
      for(int k=0;k<8;k++) acc[k] *= sc;
      m = lm;
    }
    float w0 = __expf(l0 - m), w1 = __expf(l1 - m), w2 = __expf(l2 - m), w3 = __expf(l3 - m);
    S += w0 + w1 + w2 + w3;
    #pragma unroll
    for(int k=0;k<8;k++)
      acc[k] += w0*bf2f(r0[k]) + w1*bf2f(r1[k]) + w2*bf2f(r2[k]) + w3*bf2f(r3[k]);
  }
  for(; t+7 < e1; t += 8){
    int s0 = esrc[t + q], s1 = esrc[t + 4 + q];
    u16x8 r0 = *(const u16x8*)(hP + (size_t)s0*128 + 8*sub);
    u16x8 r1 = *(const u16x8*)(hP + (size_t)s1*128 + 8*sub);
    float l0 = lrelu(as_[s0] + adi), l1 = lrelu(as_[s1] + adi);
    float lm = fmaxf(l0, l1);
    if(lm > m + 8.f){
      float sc = __expf(m - lm); S *= sc;
      #pragma unroll
      for(int k=0;k<8;k++) acc[k] *= sc;
      m = lm;
    }
    float w0 = __expf(l0 - m), w1 = __expf(l1 - m);
    S += w0 + w1;
    #pragma unroll
    for(int k=0;k<8;k++) acc[k] += w0*bf2f(r0[k]) + w1*bf2f(r1[k]);
  }
  while(t < e1){
    int idx = t + q;
    bool ok = idx < e1;
    int s = esrc[ok ? idx : e0];
    u16x8 r = *(const u16x8*)(hP + (size_t)s*128 + 8*sub);
    float l = ok ? lrelu(as_[s] + adi) : -3e38f;
    if(l > m + 8.f){
      float sc = __expf(m - l); S *= sc;
      #pragma unroll
      for(int k=0;k<8;k++) acc[k] *= sc;
      m = l;
    }
    float w = __expf(l - m);
    S += w;
    #pragma unroll
    for(int k=0;k<8;k++) acc[k] += w*bf2f(r[k]);
    t += 4;
  }
  #pragma unroll
  for(int off=32; off>=16; off>>=1){
    float mo = __shfl_down(m, off), So = __shfl_down(S, off);
    float ao[8];
    #pragma unroll
    for(int k=0;k<8;k++) ao[k] = __shfl_down(acc[k], off);
    float M = fmaxf(m, mo);
    float sc0 = __expf(m - M), sc1 = __expf(mo - M);
    S = S*sc0 + So*sc1;
    #pragma unroll
    for(int k=0;k<8;k++) acc[k] = acc[k]*sc0 + ao[k]*sc1;
    m = M;
  }
  if(lane < 16){
    float inv = 1.f/(S + 1e-16f);
    float4 o0, o1;
    o0.x = acc[0]*inv + bias[8*sub  ]; o0.y = acc[1]*inv + bias[8*sub+1];
    o0.z = acc[2]*inv + bias[8*sub+2]; o0.w = acc[3]*inv + bias[8*sub+3];
    o1.x = acc[4]*inv + bias[8*sub+4]; o1.y = acc[5]*inv + bias[8*sub+5];
    o1.z = acc[6]*inv + bias[8*sub+6]; o1.w = acc[7]*inv + bias[8*sub+7];
    *(float4*)(out + (size_t)wid*128 + 8*sub)     = o0;
    *(float4*)(out + (size_t)wid*128 + 8*sub + 4) = o1;
  }
}

extern "C" void kernel_launch(void* const* d_in, const int* in_sizes, int n_in,
                              void* d_out, int out_size, void* d_ws, size_t ws_size,
                              hipStream_t stream){
  const float* x        = (const float*)d_in[0];
  const int*   ei       = (const int*)  d_in[1];
  const float* gin1_w1  = (const float*)d_in[3];
  const float* gin1_b1  = (const float*)d_in[4];
  const float* gin1_w2  = (const float*)d_in[5];
  const float* gin1_b2  = (const float*)d_in[6];
  const float* gin2_w1  = (const float*)d_in[7];
  const float* gin2_b1  = (const float*)d_in[8];
  const float* gin2_w2  = (const float*)d_in[9];
  const float* gin2_b2  = (const float*)d_in[10];
  const float* gat1_w   = (const float*)d_in[11];
  const float* gat1_as  = (const float*)d_in[12];
  const float* gat1_ad  = (const float*)d_in[13];
  const float* gat1_b   = (const float*)d_in[14];
  const float* gat2_w   = (const float*)d_in[15];
  const float* gat2_as  = (const float*)d_in[16];
  const float* gat2_ad  = (const float*)d_in[17];
  const float* gat2_b   = (const float*)d_in[18];

  const int n = in_sizes[0] / 10;
  const int E = in_sizes[1] / 2;
  const int* src = ei;
  const int* dst = ei + E;
  const int Mc = (n + 15) / 16;
  const int nb = (n + 1023) / 1024;
  const size_t npad = ((size_t)n*4 + 255) & ~(size_t)255;

  char* w = (char*)d_ws;
  auto carve = [&](size_t bytes)->char*{ char* p = w; w += (bytes + 255) & ~(size_t)255; return p; };
  int*   esrc = (int*)  carve((size_t)E*4);
  int*   offs = (int*)  carve((size_t)(n+1)*4);
  int*   deg  = (int*)  carve(npad);          // deg & cur contiguous -> one memset
  int*   cur  = (int*)  carve(npad);
  int*   part = (int*)  carve((size_t)n*4);
  int*   bsum = (int*)  carve((size_t)1024*4);
  unsigned short* Ybf   = (unsigned short*)carve((size_t)n*64*2);
  unsigned short* Hbf   = (unsigned short*)carve((size_t)n*64*2);
  unsigned short* hB2bf = (unsigned short*)carve((size_t)n*128*2);
  unsigned short* Pbf2  = (unsigned short*)carve((size_t)n*128*2);
  float* as_  = (float*)carve((size_t)n*4);
  float* ad_  = (float*)carve((size_t)n*4);
  float* as2_ = (float*)carve((size_t)n*4);
  float* ad2_ = (float*)carve((size_t)n*4);
  float* waS  = (float*)carve(256*4);
  float* waD  = (float*)carve(256*4);
  float* waS2 = (float*)carve(256*4);
  float* waD2 = (float*)carve(256*4);
  unsigned short* FAh = (unsigned short*)carve((size_t)Mc*8*512*2);
  unsigned short* FAl = (unsigned short*)carve((size_t)Mc*8*512*2);
  unsigned short* FBh = (unsigned short*)carve((size_t)Mc*8*512*2);
  unsigned short* FBl = (unsigned short*)carve((size_t)Mc*8*512*2);
  unsigned short* WfH = (unsigned short*)carve((size_t)188*512*2);
  unsigned short* WfL = (unsigned short*)carve((size_t)188*512*2);

  const int TPB = 256;
  int ebk = (E + TPB - 1) / TPB;
  int wbk = (n + 3) / 4;
  int gx  = (Mc + 7) / 8;
  // weight arena frag offsets
  const size_t W0 = 0, W1o = 4*512, W2o = 12*512, W3o = 28*512, W4o = 60*512, W5o = 124*512;

  // weight preps (independent of graph build)
  k_prepB_all<<<(188*64 + 255)/256, TPB, 0, stream>>>(gin1_w1, gin1_w2, gin2_w1, gin2_w2,
                                                      gat1_w, gat2_w, WfH, WfL);
  k_wa2<<<96, TPB, 0, stream>>>(gat1_w, gat1_as, gat1_ad, gat2_w, gat2_as, gat2_ad,
                                waS, waD, waS2, waD2);
  k_prepA<<<(Mc*1*64 + 255)/256, 256, 0, stream>>>(x, FAh, FAl, n, 10, Mc, 1);

  // CSR build (+ zero logit accumulators in scan3); 2-pass fill for L2-resident scatter
  hipMemsetAsync(deg, 0, npad*2, stream);
  k_deg<<<ebk, TPB, 0, stream>>>(dst, deg, E);
  k_scan1<<<nb, 1024, 0, stream>>>(deg, part, bsum, n);
  k_scan2<<<1, 1024, 0, stream>>>(bsum, nb);
  k_scan3<<<(n + 1023)/1024, 1024, 0, stream>>>(part, bsum, offs, as_, ad_, as2_, ad2_, n, E);
  int half = (n + 1) / 2;
  k_fill<<<ebk, TPB, 0, stream>>>(src, dst, offs, cur, esrc, E, 0, half);
  k_fill<<<ebk, TPB, 0, stream>>>(src, dst, offs, cur, esrc, E, half, n);

  // GIN1 (projection-first): y = x@W1 -> Ybf; agg(Ybf)+b1+relu -> FB frags; 64->64 +b2+relu -> Hbf
  k_mgemm<0,false,1><<<dim3(gx,1), TPB, 0, stream>>>(FAh, FAl, WfH+W0, WfL+W0, nullptr,
      nullptr, Ybf, nullptr, nullptr, nullptr, nullptr, nullptr, nullptr, n, 64, 1, Mc);
  k_gin_agg<true><<<wbk, TPB, 0, stream>>>(Ybf, offs, esrc, gin1_b1, FBh, FBl, n);
  k_mgemm<1,true,1><<<dim3(gx,1), TPB, 0, stream>>>(FBh, FBl, WfH+W1o, WfL+W1o, gin1_b2,
      nullptr, Hbf, nullptr, nullptr, nullptr, nullptr, nullptr, nullptr, n, 64, 2, Mc);

  // GIN2: agg(Hbf) -> FA frags; 64->128 relu -> FB frags; 128->128 +bias -> hB2bf + GAT1 logits
  k_gin_agg<false><<<wbk, TPB, 0, stream>>>(Hbf, offs, esrc, nullptr, FAh, FAl, n);
  k_mgemm<1,true,2><<<dim3(gx,2), TPB, 0, stream>>>(FAh, FAl, WfH+W2o, WfL+W2o, gin2_b1,
      nullptr, nullptr, FBh, FBl, nullptr, nullptr, nullptr, nullptr, n, 128, 2, Mc);
  k_mgemm<0,true,4><<<dim3(gx,2), TPB, 0, stream>>>(FBh, FBl, WfH+W3o, WfL+W3o, gin2_b2,
      nullptr, hB2bf, nullptr, nullptr, waS, waD, as_, ad_, n, 128, 4, Mc);

  // GAT1: pre-projection fused agg+softmax -> FA frags; proj 128->256 +bias+relu -> FB frags + GAT2 logits
  k_gat1_aggpre<<<wbk, TPB, 0, stream>>>(hB2bf, as_, ad_, offs, esrc, FAh, FAl, n);
  k_mgemm<1,true,3><<<dim3(gx,4), TPB, 0, stream>>>(FAh, FAl, WfH+W4o, WfL+W4o, gat1_b,
      nullptr, nullptr, FBh, FBl, waS2, waD2, as2_, ad2_, n, 256, 4, Mc);

  // GAT2: proj 256->128 -> Pbf2; fused agg+softmax -> d_out
  k_mgemm<0,false,1><<<dim3(gx,2), TPB, 0, stream>>>(FBh, FBl, WfH+W5o, WfL+W5o, nullptr,
      nullptr, Pbf2, nullptr, nullptr, nullptr, nullptr, nullptr, nullptr, n, 128, 8, Mc);
  k_gat2_agg<<<wbk, TPB, 0, stream>>>(Pbf2, as2_, ad2_, offs, esrc, gat2_b, (float*)d_out, n);
}

// Round 12
// 326.237 us; speedup vs baseline: 3.0731x; 1.0240x over previous
//
#include <hip/hip_runtime.h>
#include <math.h>

__device__ __forceinline__ float lrelu(float x){ return x > 0.f ? x : 0.2f*x; }

typedef short s16x8 __attribute__((ext_vector_type(8)));
typedef float f32x4 __attribute__((ext_vector_type(4)));
typedef unsigned short u16x8 __attribute__((ext_vector_type(8)));

__device__ __forceinline__ f32x4 bmma(s16x8 a, s16x8 b, f32x4 c){
  return __builtin_amdgcn_mfma_f32_16x16x32_bf16(a, b, c, 0, 0, 0);
}

__device__ __forceinline__ unsigned short f2bf(float f){
  unsigned u = __float_as_uint(f);
  unsigned r = (u + 0x7fffu + ((u >> 16) & 1u)) >> 16;
  return (unsigned short)r;
}
__device__ __forceinline__ float bf2f(unsigned short h){
  return __uint_as_float(((unsigned)h) << 16);
}

// ---------------- fused setup: weight frags + folded attn vecs + x frags + degree count ----
// block ranges: [0,PB) prepB_all | [PB,PB+WA) wa2 | [.., +PA) prepA(x) | rest: deg atomics
__global__ __launch_bounds__(256) void k_setup(const float* __restrict__ B0,
                                               const float* __restrict__ B1,
                                               const float* __restrict__ B2,
                                               const float* __restrict__ B3,
                                               const float* __restrict__ B4,
                                               const float* __restrict__ B5,
                                               unsigned short* __restrict__ WfH,
                                               unsigned short* __restrict__ WfL,
                                               const float* __restrict__ a1s, const float* __restrict__ a1d,
                                               const float* __restrict__ a2s, const float* __restrict__ a2d,
                                               float* __restrict__ o1s, float* __restrict__ o1d,
                                               float* __restrict__ o2s, float* __restrict__ o2d,
                                               const float* __restrict__ x,
                                               unsigned short* __restrict__ XH,
                                               unsigned short* __restrict__ XL,
                                               int Mc, int n,
                                               const int* __restrict__ dst, int* __restrict__ deg, int E,
                                               int PB, int WA, int PA){
  int b = blockIdx.x;
  int tid = threadIdx.x;
  int lane = tid & 63;
  if(b < PB){
    // weight fragment arena: 188 frags, 4 per block
    int fid = b*4 + (tid >> 6);
    if(fid >= 188) return;
    const float* B; int K, Nd, Kc, fl;
    if(fid < 4)       { B=B0; K=10;  Nd=64;  Kc=1; fl=fid;     }
    else if(fid < 12) { B=B1; K=64;  Nd=64;  Kc=2; fl=fid-4;   }
    else if(fid < 28) { B=B2; K=64;  Nd=128; Kc=2; fl=fid-12;  }
    else if(fid < 60) { B=B3; K=128; Nd=128; Kc=4; fl=fid-28;  }
    else if(fid < 124){ B=B4; K=128; Nd=256; Kc=4; fl=fid-60;  }
    else              { B=B5; K=256; Nd=128; Kc=8; fl=fid-124; }
    int nc = fl / Kc, kc = fl - nc*Kc;
    int col = nc*16 + (lane & 15);
    int k0  = kc*32 + (lane >> 4)*8;
    s16x8 h, l;
    #pragma unroll
    for(int j=0;j<8;j++){
      int k = k0 + j;
      float v = (k < K) ? B[(size_t)k*Nd + col] : 0.f;
      unsigned short hb = f2bf(v);
      h[j] = (short)hb; l[j] = (short)f2bf(v - bf2f(hb));
    }
    size_t off = (size_t)fid*512 + (size_t)lane*8;
    *(s16x8*)(WfH + off) = h;
    *(s16x8*)(WfL + off) = l;
  } else if(b < PB + WA){
    // folded attention vectors: waves 0..127 -> W1 rows, 128..383 -> W2 rows
    int wid = (b - PB)*4 + (tid >> 6);
    float s = 0.f, d = 0.f;
    if(wid < 128){
      #pragma unroll
      for(int j=0;j<4;j++){
        int c = lane + j*64;
        float v = B4[(size_t)wid*256 + c];
        s += v * a1s[c]; d += v * a1d[c];
      }
    } else {
      int r = wid - 128;
      #pragma unroll
      for(int j=0;j<2;j++){
        int c = lane + j*64;
        float v = B5[(size_t)r*128 + c];
        s += v * a2s[c]; d += v * a2d[c];
      }
    }
    #pragma unroll
    for(int off=32; off; off>>=1){ s += __shfl_down(s, off); d += __shfl_down(d, off); }
    if(lane==0){
      if(wid < 128){ o1s[wid] = s; o1d[wid] = d; }
      else         { o2s[wid-128] = s; o2d[wid-128] = d; }
    }
  } else if(b < PB + WA + PA){
    // prepA for x [n x 10], Kc=1
    int fid = (b - PB - WA)*4 + (tid >> 6);
    if(fid >= Mc) return;
    int row = fid*16 + (lane & 15);
    int k0  = (lane >> 4)*8;
    s16x8 h, l;
    if(row < n){
      const float* ap = x + (size_t)row*10;
      #pragma unroll
      for(int j=0;j<8;j++){
        float v = (k0 + j < 10) ? ap[k0 + j] : 0.f;
        unsigned short hb = f2bf(v);
        h[j] = (short)hb; l[j] = (short)f2bf(v - bf2f(hb));
      }
    } else {
      #pragma unroll
      for(int j=0;j<8;j++){ h[j]=0; l[j]=0; }
    }
    size_t off = (size_t)fid*512 + (size_t)lane*8;
    *(s16x8*)(XH + off) = h;
    *(s16x8*)(XL + off) = l;
  } else {
    int e = (b - PB - WA - PA)*256 + tid;
    if(e < E) atomicAdd(&deg[dst[e]], 1);
  }
}

// ---------------- scan ----------------
__global__ __launch_bounds__(1024) void k_scan1(const int* __restrict__ deg,
                                                int* __restrict__ part,
                                                int* __restrict__ bsum, int n){
  int i = blockIdx.x*1024 + threadIdx.x;
  int lane = threadIdx.x & 63, wv = threadIdx.x >> 6;
  int v = (i < n) ? deg[i] : 0;
  int s = v;
  #pragma unroll
  for(int off=1; off<64; off<<=1){
    int t = __shfl_up(s, off);
    if(lane >= off) s += t;
  }
  __shared__ int wsum[16];
  if(lane==63) wsum[wv] = s;
  __syncthreads();
  if(wv==0 && lane<16){
    int t = wsum[lane], ss = t;
    #pragma unroll
    for(int off=1; off<16; off<<=1){
      int u = __shfl_up(ss, off);
      if(lane >= off) ss += u;
    }
    wsum[lane] = ss - t;
    if(lane==15) bsum[blockIdx.x] = ss;
  }
  __syncthreads();
  if(i < n) part[i] = s - v + wsum[wv];
}

// per-block base = sum(bsum[0..b)) computed locally (nb is small); also zeroes logit bufs
__global__ __launch_bounds__(1024) void k_scan3(const int* __restrict__ part,
                                                const int* __restrict__ bsum,
                                                int* __restrict__ offs,
                                                float* __restrict__ z0, float* __restrict__ z1,
                                                float* __restrict__ z2, float* __restrict__ z3,
                                                int n, int E){
  __shared__ int base_sh;
  int b = blockIdx.x;
  if(threadIdx.x < 64){
    int acc = 0;
    for(int j = (int)threadIdx.x; j < b; j += 64) acc += bsum[j];
    #pragma unroll
    for(int off=32; off; off>>=1) acc += __shfl_down(acc, off);
    if(threadIdx.x==0) base_sh = acc;
  }
  __syncthreads();
  int base = base_sh;
  int i = b*1024 + (int)threadIdx.x;
  if(i < n){
    offs[i] = part[i] + base;
    z0[i] = 0.f; z1[i] = 0.f; z2[i] = 0.f; z3[i] = 0.f;
  }
  if(b==0 && threadIdx.x==0) offs[n] = E;
}

// range-restricted placement pass (keeps live scatter region L2-resident)
__global__ void k_fill(const int* __restrict__ src, const int* __restrict__ dst,
                       const int* __restrict__ offs, int* __restrict__ cur,
                       int* __restrict__ esrc, int E, int lo, int hi){
  int e = blockIdx.x*blockDim.x + threadIdx.x;
  if(e < E){
    int d = dst[e];
    if(d >= lo && d < hi){
      int pos = offs[d] + atomicAdd(&cur[d], 1);
      esrc[pos] = src[e];
    }
  }
}

// ---------------- GIN agg: bf16 rows D=64, eighth-wave split, frag-epilogue ----------------
template<bool BR>
__global__ __launch_bounds__(256) void k_gin_agg(const unsigned short* __restrict__ xin,
                                                 const int* __restrict__ offs,
                                                 const int* __restrict__ esrc,
                                                 const float* __restrict__ bias,
                                                 unsigned short* __restrict__ fhi,
                                                 unsigned short* __restrict__ flo, int n){
  int wid  = (int)((blockIdx.x*256u + threadIdx.x) >> 6);
  int lane = threadIdx.x & 63;
  if(wid >= n) return;
  int g = lane >> 3, sub = lane & 7;
  float acc[8];
  #pragma unroll
  for(int k=0;k<8;k++) acc[k] = 0.f;
  int e0 = offs[wid], e1 = offs[wid+1];
  int t = e0;
  for(; t+15 < e1; t += 16){
    int sA = esrc[t + g], sB = esrc[t + 8 + g];
    u16x8 rA = *(const u16x8*)(xin + (size_t)sA*64 + 8*sub);
    u16x8 rB = *(const u16x8*)(xin + (size_t)sB*64 + 8*sub);
    #pragma unroll
    for(int k=0;k<8;k++) acc[k] += bf2f(rA[k]) + bf2f(rB[k]);
  }
  for(; t+7 < e1; t += 8){
    int s = esrc[t + g];
    u16x8 r = *(const u16x8*)(xin + (size_t)s*64 + 8*sub);
    #pragma unroll
    for(int k=0;k<8;k++) acc[k] += bf2f(r[k]);
  }
  if(t < e1){
    int idx = t + g;
    bool ok = idx < e1;
    int s = esrc[ok ? idx : e0];
    u16x8 r = *(const u16x8*)(xin + (size_t)s*64 + 8*sub);
    float w = ok ? 1.f : 0.f;
    #pragma unroll
    for(int k=0;k<8;k++) acc[k] += w*bf2f(r[k]);
  }
  #pragma unroll
  for(int off=32; off>=8; off>>=1)
    #pragma unroll
    for(int k=0;k<8;k++) acc[k] += __shfl_down(acc[k], off);
  if(lane < 8){
    u16x8 rs = *(const u16x8*)(xin + (size_t)wid*64 + 8*sub);
    u16x8 h, l;
    #pragma unroll
    for(int k=0;k<8;k++){
      float o = acc[k] + bf2f(rs[k]);
      if(BR) o = fmaxf(o + bias[8*sub + k], 0.f);
      unsigned short hb = f2bf(o);
      h[k] = hb; l[k] = f2bf(o - bf2f(hb));
    }
    int mc = wid >> 4;
    size_t base = ((size_t)(mc*2 + (sub>>2))*64 + (wid & 15) + (sub & 3)*16) * 8;
    *(u16x8*)(fhi + base) = h;
    *(u16x8*)(flo + base) = l;
  }
}

// ---------------- split-bf16 MFMA GEMM ----------------
// OMODE: 0 fp32 C | 1 bf16 row-major | 2 A-frag out | 3 A-frag out + atomic dots
//        4 bf16 row-major (via LDS transpose) + atomic dots
template<int ACT, bool HASBIAS, int OMODE>
__global__ __launch_bounds__(256) void k_mgemm(const unsigned short* __restrict__ Ahi,
                                               const unsigned short* __restrict__ Alo,
                                               const unsigned short* __restrict__ Bhi,
                                               const unsigned short* __restrict__ Blo,
                                               const float* __restrict__ bias,
                                               float* __restrict__ C,
                                               unsigned short* __restrict__ Cbf,
                                               unsigned short* __restrict__ foh,
                                               unsigned short* __restrict__ fol,
                                               const float* __restrict__ dwS,
                                               const float* __restrict__ dwD,
                                               float* __restrict__ dotS,
                                               float* __restrict__ dotD,
                                               int M, int Nd, int Kc, int Mc){
  int tid = threadIdx.x;
  int wid = tid >> 6, lane = tid & 63;
  int wm = wid >> 1, wn = wid & 1;
  int mcb = blockIdx.x*8 + wm*4;
  int ncb = blockIdx.y*4 + wn*2;

  f32x4 acc[4][2];
  #pragma unroll
  for(int f=0;f<4;f++)
    #pragma unroll
    for(int g=0;g<2;g++) acc[f][g] = (f32x4){0.f,0.f,0.f,0.f};

  for(int kc=0; kc<Kc; kc++){
    s16x8 ah[4], al[4], bh[2], bl[2];
    #pragma unroll
    for(int f=0;f<4;f++){
      int mcf = mcb + f; if(mcf > Mc-1) mcf = Mc-1;
      size_t off = ((size_t)mcf*Kc + kc)*512 + (size_t)lane*8;
      ah[f] = *(const s16x8*)(Ahi + off);
      al[f] = *(const s16x8*)(Alo + off);
    }
    #pragma unroll
    for(int g=0;g<2;g++){
      size_t off = ((size_t)(ncb+g)*Kc + kc)*512 + (size_t)lane*8;
      bh[g] = *(const s16x8*)(Bhi + off);
      bl[g] = *(const s16x8*)(Blo + off);
    }
    #pragma unroll
    for(int f=0;f<4;f++)
      #pragma unroll
      for(int g=0;g<2;g++){
        acc[f][g] = bmma(ah[f], bh[g], acc[f][g]);
        acc[f][g] = bmma(ah[f], bl[g], acc[f][g]);
        acc[f][g] = bmma(al[f], bh[g], acc[f][g]);
      }
  }

  if constexpr(OMODE <= 1){
    #pragma unroll
    for(int g=0;g<2;g++){
      int col = (ncb+g)*16 + (lane & 15);
      float bv = HASBIAS ? bias[col] : 0.f;
      #pragma unroll
      for(int f=0;f<4;f++){
        int row0 = (mcb+f)*16 + (lane>>4)*4;
        #pragma unroll
        for(int r=0;r<4;r++){
          int row = row0 + r;
          if(row < M){
            float v = acc[f][g][r] + bv;
            if(ACT) v = fmaxf(v, 0.f);
            if(OMODE==1) Cbf[(size_t)row*Nd + col] = f2bf(v);
            else         C  [(size_t)row*Nd + col] = v;
          }
        }
      }
    }
  } else {
    // transpose 64x32 wave tile via LDS -> row-contiguous o[8] per lane
    __shared__ float tile[4][64][33];
    #pragma unroll
    for(int g=0;g<2;g++){
      float bv = HASBIAS ? bias[(ncb+g)*16 + (lane&15)] : 0.f;
      int ck = g*16 + (lane & 15);
      #pragma unroll
      for(int f=0;f<4;f++){
        int rb = f*16 + (lane>>4)*4;
        #pragma unroll
        for(int r=0;r<4;r++){
          float v = acc[f][g][r] + bv;
          if(ACT) v = fmaxf(v, 0.f);
          tile[wid][rb + r][ck] = v;
        }
      }
    }
    asm volatile("" ::: "memory");
    int Kcn = Nd >> 5;
    int kcn = ncb >> 1;
    int rr = lane & 15, cb = lane >> 4;
    #pragma unroll
    for(int f=0;f<4;f++){
      int mcf = mcb + f;
      if(mcf >= Mc) continue;
      float o[8];
      #pragma unroll
      for(int j=0;j<8;j++) o[j] = tile[wid][f*16 + rr][cb*8 + j];
      if constexpr(OMODE == 4){
        u16x8 hb;
        #pragma unroll
        for(int j=0;j<8;j++) hb[j] = f2bf(o[j]);
        int row = mcf*16 + rr;
        *(u16x8*)(Cbf + (size_t)row*Nd + kcn*32 + cb*8) = hb;
      } else {
        u16x8 h, l;
        #pragma unroll
        for(int j=0;j<8;j++){
          unsigned short hb = f2bf(o[j]);
          h[j] = hb; l[j] = f2bf(o[j] - bf2f(hb));
        }
        size_t base = ((size_t)mcf*Kcn + kcn)*512 + (size_t)lane*8;
        *(u16x8*)(foh + base) = h;
        *(u16x8*)(fol + base) = l;
      }
      if constexpr(OMODE == 3 || OMODE == 4){
        float sv = 0.f, dv = 0.f;
        #pragma unroll
        for(int j=0;j<8;j++){
          int col = kcn*32 + cb*8 + j;
          sv += o[j]*dwS[col]; dv += o[j]*dwD[col];
        }
        sv += __shfl_xor(sv, 16); sv += __shfl_xor(sv, 32);
        dv += __shfl_xor(dv, 16); dv += __shfl_xor(dv, 32);
        if(cb == 0){
          int row = mcf*16 + rr;
          atomicAdd(dotS + row, sv);
          atomicAdd(dotD + row, dv);
        }
      }
    }
  }
}

// ---------------- GAT1 pre-projection agg: D=128 bf16, quarter-wave, online softmax, frag out ----------------
__global__ __launch_bounds__(256) void k_gat1_aggpre(const unsigned short* __restrict__ hB,
                                                     const float* __restrict__ as_, const float* __restrict__ ad_,
                                                     const int* __restrict__ offs, const int* __restrict__ esrc,
                                                     unsigned short* __restrict__ fhi, unsigned short* __restrict__ flo,
                                                     int n){
  int wid  = (int)((blockIdx.x*256u + threadIdx.x) >> 6);
  int lane = threadIdx.x & 63;
  if(wid >= n) return;
  int q = lane >> 4, sub = lane & 15;
  float adi = ad_[wid];
  u16x8 rs = *(const u16x8*)(hB + (size_t)wid*128 + 8*sub);
  float m, S, acc[8];
  if(q == 0){
    m = lrelu(as_[wid] + adi); S = 1.f;
    #pragma unroll
    for(int k=0;k<8;k++) acc[k] = bf2f(rs[k]);
  } else {
    m = -3e38f; S = 0.f;
    #pragma unroll
    for(int k=0;k<8;k++) acc[k] = 0.f;
  }
  int e0 = offs[wid], e1 = offs[wid+1];
  int t = e0;
  for(; t+15 < e1; t += 16){
    int s0 = esrc[t + q], s1 = esrc[t + 4 + q], s2 = esrc[t + 8 + q], s3 = esrc[t + 12 + q];
    u16x8 r0 = *(const u16x8*)(hB + (size_t)s0*128 + 8*sub);
    u16x8 r1 = *(const u16x8*)(hB + (size_t)s1*128 + 8*sub);
    u16x8 r2 = *(const u16x8*)(hB + (size_t)s2*128 + 8*sub);
    u16x8 r3 = *(const u16x8*)(hB + (size_t)s3*128 + 8*sub);
    float l0 = lrelu(as_[s0] + adi), l1 = lrelu(as_[s1] + adi);
    float l2 = lrelu(as_[s2] + adi), l3 = lrelu(as_[s3] + adi);
    float lm = fmaxf(fmaxf(l0, l1), fmaxf(l2, l3));
    if(lm > m + 8.f){
      float sc = __expf(m - lm); S *= sc;
      #pragma unroll
      for(int k=0;k<8;k++) acc[k] *= sc;
      m = lm;
    }
    float w0 = __expf(l0 - m), w1 = __expf(l1 - m), w2 = __expf(l2 - m), w3 = __expf(l3 - m);
    S += w0 + w1 + w2 + w3;
    #pragma unroll
    for(int k=0;k<8;k++)
      acc[k] += w0*bf2f(r0[k]) + w1*bf2f(r1[k]) + w2*bf2f(r2[k]) + w3*bf2f(r3[k]);
  }
  for(; t+7 < e1; t += 8){
    int s0 = esrc[t + q], s1 = esrc[t + 4 + q];
    u16x8 r0 = *(const u16x8*)(hB + (size_t)s0*128 + 8*sub);
    u16x8 r1 = *(const u16x8*)(hB + (size_t)s1*128 + 8*sub);
    float l0 = lrelu(as_[s0] + adi), l1 = lrelu(as_[s1] + adi);
    float lm = fmaxf(l0, l1);
    if(lm > m + 8.f){
      float sc = __expf(m - lm); S *= sc;
      #pragma unroll
      for(int k=0;k<8;k++) acc[k] *= sc;
      m = lm;
    }
    float w0 = __expf(l0 - m), w1 = __expf(l1 - m);
    S += w0 + w1;
    #pragma unroll
    for(int k=0;k<8;k++) acc[k] += w0*bf2f(r0[k]) + w1*bf2f(r1[k]);
  }
  while(t < e1){
    int idx = t + q;
    bool ok = idx < e1;
    int s = esrc[ok ? idx : e0];
    u16x8 r = *(const u16x8*)(hB + (size_t)s*128 + 8*sub);
    float l = ok ? lrelu(as_[s] + adi) : -3e38f;
    if(l > m + 8.f){
      float sc = __expf(m - l); S *= sc;
      #pragma unroll
      for(int k=0;k<8;k++) acc[k] *= sc;
      m = l;
    }
    float w = __expf(l - m);
    S += w;
    #pragma unroll
    for(int k=0;k<8;k++) acc[k] += w*bf2f(r[k]);
    t += 4;
  }
  #pragma unroll
  for(int off=32; off>=16; off>>=1){
    float mo = __shfl_down(m, off), So = __shfl_down(S, off);
    float ao[8];
    #pragma unroll
    for(int k=0;k<8;k++) ao[k] = __shfl_down(acc[k], off);
    float M = fmaxf(m, mo);
    float sc0 = __expf(m - M), sc1 = __expf(mo - M);
    S = S*sc0 + So*sc1;
    #pragma unroll
    for(int k=0;k<8;k++) acc[k] = acc[k]*sc0 + ao[k]*sc1;
    m = M;
  }
  if(lane < 16){
    float inv = 1.f/(S + 1e-16f);
    u16x8 h, l;
    #pragma unroll
    for(int k=0;k<8;k++){
      float v = acc[k]*inv;
      unsigned short hb = f2bf(v);
      h[k] = hb; l[k] = f2bf(v - bf2f(hb));
    }
    int mc = wid >> 4;
    size_t base = ((size_t)(mc*4 + (sub>>2))*64 + (wid & 15) + (sub & 3)*16) * 8;
    *(u16x8*)(fhi + base) = h;
    *(u16x8*)(flo + base) = l;
  }
}

// ---------------- GAT2 agg: D=128, quarter-wave, online softmax, fp32 out ----------------
__global__ __launch_bounds__(256) void k_gat2_agg(const unsigned short* __restrict__ hP,
                                                  const float* __restrict__ as_, const float* __restrict__ ad_,
                                                  const int* __restrict__ offs, const int* __restrict__ esrc,
                                                  const float* __restrict__ bias, float* __restrict__ out, int n){
  int wid  = (int)((blockIdx.x*256u + threadIdx.x) >> 6);
  int lane = threadIdx.x & 63;
  if(wid >= n) return;
  int q = lane >> 4, sub = lane & 15;
  float adi = ad_[wid];
  u16x8 rs = *(const u16x8*)(hP + (size_t)wid*128 + 8*sub);
  float m, S, acc[8];
  if(q == 0){
    m = lrelu(as_[wid] + adi); S = 1.f;
    #pragma unroll
    for(int k=0;k<8;k++) acc[k] = bf2f(rs[k]);
  } else {
    m = -3e38f; S = 0.f;
    #pragma unroll
    for(int k=0;k<8;k++) acc[k] = 0.f;
  }
  int e0 = offs[wid], e1 = offs[wid+1];
  int t = e0;
  for(; t+15 < e1; t += 16){
    int s0 = esrc[t + q], s1 = esrc[t + 4 + q], s2 = esrc[t + 8 + q], s3 = esrc[t + 12 + q];
    u16x8 r0 = *(const u16x8*)(hP + (size_t)s0*128 + 8*sub);
    u16x8 r1 = *(const u16x8*)(hP + (size_t)s1*128 + 8*sub);
    u16x8 r2 = *(const u16x8*)(hP + (size_t)s2*128 + 8*sub);
    u16x8 r3 = *(const u16x8*)(hP + (size_t)s3*128 + 8*sub);
    float l0 = lrelu(as_[s0] + adi), l1 = lrelu(as_[s1] + adi);
    float l2 = lrelu(as_[s2] + adi), l3 = lrelu(as_[s3] + adi);
    float lm = fmaxf(fmaxf(l0, l1), fmaxf(l2, l3));
    if(lm > m + 8.f){
      float sc = __expf(m - lm); S *= sc;
      #pragma unroll
      for(int k=0;k<8;k++) acc[k] *= sc;
      m = lm;
    }
    float w0 = __expf(l0 - m), w1 = __expf(l1 - m), w2 = __expf(l2 - m), w3 = __expf(l3 - m);
    S += w0 + w1 + w2 + w3;
    #pragma unroll
    for(int k=0;k<8;k++)
      acc[k] += w0*bf2f(r0[k]) + w1*bf2f(r1[k]) + w2*bf2f(r2[k]) + w3*bf2f(r3[k]);
  }
  for(; t+7 < e1; t += 8){
    int s0 = esrc[t + q], s1 = esrc[t + 4 + q];
    u16x8 r0 = *(const u16x8*)(hP + (size_t)s0*128 + 8*sub);
    u16x8 r1 = *(const u16x8*)(hP + (size_t)s1*128 + 8*sub);
    float l0 = lrelu(as_[s0] + adi), l1 = lrelu(as_[s1] + adi);
    float lm = fmaxf(l0, l1);
    if(lm > m + 8.f){
      float sc = __expf(m - lm); S *= sc;
      #pragma unroll
      for(int k=0;k<8;k++) acc[k] *= sc;
      m = lm;
    }
    float w0 = __expf(l0 - m), w1 = __expf(l1 - m);
    S += w0 + w1;
    #pragma unroll
    for(int k=0;k<8;k++) acc[k] += w0*bf2f(r0[k]) + w1*bf2f(r1[k]);
  }
  while(t < e1){
    int idx = t + q;
    bool ok = idx < e1;
    int s = esrc[ok ? idx : e0];
    u16x8 r = *(const u16x8*)(hP + (size_t)s*128 + 8*sub);
    float l = ok ? lrelu(as_[s] + adi) : -3e38f;
    if(l > m + 8.f){
      float sc = __expf(m - l); S *= sc;
      #pragma unroll
      for(int k=0;k<8;k++) acc[k] *= sc;
      m = l;
    }
    float w = __expf(l - m);
    S += w;
    #pragma unroll
    for(int k=0;k<8;k++) acc[k] += w*bf2f(r[k]);
    t += 4;
  }
  #pragma unroll
  for(int off=32; off>=16; off>>=1){
    float mo = __shfl_down(m, off), So = __shfl_down(S, off);
    float ao[8];
    #pragma unroll
    for(int k=0;k<8;k++) ao[k] = __shfl_down(acc[k], off);
    float M = fmaxf(m, mo);
    float sc0 = __expf(m - M), sc1 = __expf(mo - M);
    S = S*sc0 + So*sc1;
    #pragma unroll
    for(int k=0;k<8;k++) acc[k] = acc[k]*sc0 + ao[k]*sc1;
    m = M;
  }
  if(lane < 16){
    float inv = 1.f/(S + 1e-16f);
    float4 o0, o1;
    o0.x = acc[0]*inv + bias[8*sub  ]; o0.y = acc[1]*inv + bias[8*sub+1];
    o0.z = acc[2]*inv + bias[8*sub+2]; o0.w = acc[3]*inv + bias[8*sub+3];
    o1.x = acc[4]*inv + bias[8*sub+4]; o1.y = acc[5]*inv + bias[8*sub+5];
    o1.z = acc[6]*inv + bias[8*sub+6]; o1.w = acc[7]*inv + bias[8*sub+7];
    *(float4*)(out + (size_t)wid*128 + 8*sub)     = o0;
    *(float4*)(out + (size_t)wid*128 + 8*sub + 4) = o1;
  }
}

extern "C" void kernel_launch(void* const* d_in, const int* in_sizes, int n_in,
                              void* d_out, int out_size, void* d_ws, size_t ws_size,
                              hipStream_t stream){
  const float* x        = (const float*)d_in[0];
  const int*   ei       = (const int*)  d_in[1];
  const float* gin1_w1  = (const float*)d_in[3];
  const float* gin1_b1  = (const float*)d_in[4];
  const float* gin1_w2  = (const float*)d_in[5];
  const float* gin1_b2  = (const float*)d_in[6];
  const float* gin2_w1  = (const float*)d_in[7];
  const float* gin2_b1  = (const float*)d_in[8];
  const float* gin2_w2  = (const float*)d_in[9];
  const float* gin2_b2  = (const float*)d_in[10];
  const float* gat1_w   = (const float*)d_in[11];
  const float* gat1_as  = (const float*)d_in[12];
  const float* gat1_ad  = (const float*)d_in[13];
  const float* gat1_b   = (const float*)d_in[14];
  const float* gat2_w   = (const float*)d_in[15];
  const float* gat2_as  = (const float*)d_in[16];
  const float* gat2_ad  = (const float*)d_in[17];
  const float* gat2_b   = (const float*)d_in[18];

  const int n = in_sizes[0] / 10;
  const int E = in_sizes[1] / 2;
  const int* src = ei;
  const int* dst = ei + E;
  const int Mc = (n + 15) / 16;
  const int nb = (n + 1023) / 1024;
  const size_t npad = ((size_t)n*4 + 255) & ~(size_t)255;

  char* w = (char*)d_ws;
  auto carve = [&](size_t bytes)->char*{ char* p = w; w += (bytes + 255) & ~(size_t)255; return p; };
  int*   esrc = (int*)  carve((size_t)E*4);
  int*   offs = (int*)  carve((size_t)(n+1)*4);
  int*   deg  = (int*)  carve(npad);          // deg & cur contiguous -> one memset
  int*   cur  = (int*)  carve(npad);
  int*   part = (int*)  carve((size_t)n*4);
  int*   bsum = (int*)  carve((size_t)1024*4);
  unsigned short* Ybf   = (unsigned short*)carve((size_t)n*64*2);
  unsigned short* Hbf   = (unsigned short*)carve((size_t)n*64*2);
  unsigned short* hB2bf = (unsigned short*)carve((size_t)n*128*2);
  unsigned short* Pbf2  = (unsigned short*)carve((size_t)n*128*2);
  float* as_  = (float*)carve((size_t)n*4);
  float* ad_  = (float*)carve((size_t)n*4);
  float* as2_ = (float*)carve((size_t)n*4);
  float* ad2_ = (float*)carve((size_t)n*4);
  float* waS  = (float*)carve(256*4);
  float* waD  = (float*)carve(256*4);
  float* waS2 = (float*)carve(256*4);
  float* waD2 = (float*)carve(256*4);
  unsigned short* FAh = (unsigned short*)carve((size_t)Mc*8*512*2);
  unsigned short* FAl = (unsigned short*)carve((size_t)Mc*8*512*2);
  unsigned short* FBh = (unsigned short*)carve((size_t)Mc*8*512*2);
  unsigned short* FBl = (unsigned short*)carve((size_t)Mc*8*512*2);
  unsigned short* WfH = (unsigned short*)carve((size_t)188*512*2);
  unsigned short* WfL = (unsigned short*)carve((size_t)188*512*2);

  const int TPB = 256;
  int ebk = (E + TPB - 1) / TPB;
  int wbk = (n + 3) / 4;
  int gx  = (Mc + 7) / 8;
  // weight arena frag offsets
  const size_t W0 = 0, W1o = 4*512, W2o = 12*512, W3o = 28*512, W4o = 60*512, W5o = 124*512;

  // fused setup: weight frags + folded attn vecs + x frags + degree histogram
  hipMemsetAsync(deg, 0, npad*2, stream);
  int PB = 47, WA = 96, PA = (Mc*64 + 255)/256;
  k_setup<<<PB + WA + PA + ebk, TPB, 0, stream>>>(
      gin1_w1, gin1_w2, gin2_w1, gin2_w2, gat1_w, gat2_w, WfH, WfL,
      gat1_as, gat1_ad, gat2_as, gat2_ad, waS, waD, waS2, waD2,
      x, FAh, FAl, Mc, n, dst, deg, E, PB, WA, PA);

  // scan + 2-pass fill (L2-resident scatter)
  k_scan1<<<nb, 1024, 0, stream>>>(deg, part, bsum, n);
  k_scan3<<<nb, 1024, 0, stream>>>(part, bsum, offs, as_, ad_, as2_, ad2_, n, E);
  int half = (n + 1) / 2;
  k_fill<<<ebk, TPB, 0, stream>>>(src, dst, offs, cur, esrc, E, 0, half);
  k_fill<<<ebk, TPB, 0, stream>>>(src, dst, offs, cur, esrc, E, half, n);

  // GIN1 (projection-first): y = x@W1 -> Ybf; agg(Ybf)+b1+relu -> FB frags; 64->64 +b2+relu -> Hbf
  k_mgemm<0,false,1><<<dim3(gx,1), TPB, 0, stream>>>(FAh, FAl, WfH+W0, WfL+W0, nullptr,
      nullptr, Ybf, nullptr, nullptr, nullptr, nullptr, nullptr, nullptr, n, 64, 1, Mc);
  k_gin_agg<true><<<wbk, TPB, 0, stream>>>(Ybf, offs, esrc, gin1_b1, FBh, FBl, n);
  k_mgemm<1,true,1><<<dim3(gx,1), TPB, 0, stream>>>(FBh, FBl, WfH+W1o, WfL+W1o, gin1_b2,
      nullptr, Hbf, nullptr, nullptr, nullptr, nullptr, nullptr, nullptr, n, 64, 2, Mc);

  // GIN2: agg(Hbf) -> FA frags; 64->128 relu -> FB frags; 128->128 +bias -> hB2bf + GAT1 logits
  k_gin_agg<false><<<wbk, TPB, 0, stream>>>(Hbf, offs, esrc, nullptr, FAh, FAl, n);
  k_mgemm<1,true,2><<<dim3(gx,2), TPB, 0, stream>>>(FAh, FAl, WfH+W2o, WfL+W2o, gin2_b1,
      nullptr, nullptr, FBh, FBl, nullptr, nullptr, nullptr, nullptr, n, 128, 2, Mc);
  k_mgemm<0,true,4><<<dim3(gx,2), TPB, 0, stream>>>(FBh, FBl, WfH+W3o, WfL+W3o, gin2_b2,
      nullptr, hB2bf, nullptr, nullptr, waS, waD, as_, ad_, n, 128, 4, Mc);

  // GAT1: pre-projection fused agg+softmax -> FA frags; proj 128->256 +bias+relu -> FB frags + GAT2 logits
  k_gat1_aggpre<<<wbk, TPB, 0, stream>>>(hB2bf, as_, ad_, offs, esrc, FAh, FAl, n);
  k_mgemm<1,true,3><<<dim3(gx,4), TPB, 0, stream>>>(FAh, FAl, WfH+W4o, WfL+W4o, gat1_b,
      nullptr, nullptr, FBh, FBl, waS2, waD2, as2_, ad2_, n, 256, 4, Mc);

  // GAT2: proj 256->128 -> Pbf2; fused agg+softmax -> d_out
  k_mgemm<0,false,1><<<dim3(gx,2), TPB, 0, stream>>>(FBh, FBl, WfH+W5o, WfL+W5o, nullptr,
      nullptr, Pbf2, nullptr, nullptr, nullptr, nullptr, nullptr, nullptr, n, 128, 8, Mc);
  k_gat2_agg<<<wbk, TPB, 0, stream>>>(Pbf2, as2_, ad2_, offs, esrc, gat2_b, (float*)d_out, n);
}

// Round 13
// 322.606 us; speedup vs baseline: 3.1077x; 1.0113x over previous
//
#include <hip/hip_runtime.h>
#include <math.h>

__device__ __forceinline__ float lrelu(float x){ return x > 0.f ? x : 0.2f*x; }

typedef short s16x8 __attribute__((ext_vector_type(8)));
typedef float f32x4 __attribute__((ext_vector_type(4)));
typedef unsigned short u16x8 __attribute__((ext_vector_type(8)));

__device__ __forceinline__ f32x4 bmma(s16x8 a, s16x8 b, f32x4 c){
  return __builtin_amdgcn_mfma_f32_16x16x32_bf16(a, b, c, 0, 0, 0);
}

__device__ __forceinline__ unsigned short f2bf(float f){
  unsigned u = __float_as_uint(f);
  unsigned r = (u + 0x7fffu + ((u >> 16) & 1u)) >> 16;
  return (unsigned short)r;
}
__device__ __forceinline__ float bf2f(unsigned short h){
  return __uint_as_float(((unsigned)h) << 16);
}

// ---------------- fused setup: weight frags + folded attn vecs + x frags + degree count ----
// block ranges: [0,PB) prepB_all | [PB,PB+WA) wa2 | [.., +PA) prepA(x) | rest: deg atomics (4 edges/thread)
__global__ __launch_bounds__(256) void k_setup(const float* __restrict__ B0,
                                               const float* __restrict__ B1,
                                               const float* __restrict__ B2,
                                               const float* __restrict__ B3,
                                               const float* __restrict__ B4,
                                               const float* __restrict__ B5,
                                               unsigned short* __restrict__ WfH,
                                               unsigned short* __restrict__ WfL,
                                               const float* __restrict__ a1s, const float* __restrict__ a1d,
                                               const float* __restrict__ a2s, const float* __restrict__ a2d,
                                               float* __restrict__ o1s, float* __restrict__ o1d,
                                               float* __restrict__ o2s, float* __restrict__ o2d,
                                               const float* __restrict__ x,
                                               unsigned short* __restrict__ XH,
                                               unsigned short* __restrict__ XL,
                                               int Mc, int n,
                                               const int* __restrict__ dst, int* __restrict__ deg, int E,
                                               int PB, int WA, int PA){
  int b = blockIdx.x;
  int tid = threadIdx.x;
  int lane = tid & 63;
  if(b < PB){
    int fid = b*4 + (tid >> 6);
    if(fid >= 188) return;
    const float* B; int K, Nd, Kc, fl;
    if(fid < 4)       { B=B0; K=10;  Nd=64;  Kc=1; fl=fid;     }
    else if(fid < 12) { B=B1; K=64;  Nd=64;  Kc=2; fl=fid-4;   }
    else if(fid < 28) { B=B2; K=64;  Nd=128; Kc=2; fl=fid-12;  }
    else if(fid < 60) { B=B3; K=128; Nd=128; Kc=4; fl=fid-28;  }
    else if(fid < 124){ B=B4; K=128; Nd=256; Kc=4; fl=fid-60;  }
    else              { B=B5; K=256; Nd=128; Kc=8; fl=fid-124; }
    int nc = fl / Kc, kc = fl - nc*Kc;
    int col = nc*16 + (lane & 15);
    int k0  = kc*32 + (lane >> 4)*8;
    s16x8 h, l;
    #pragma unroll
    for(int j=0;j<8;j++){
      int k = k0 + j;
      float v = (k < K) ? B[(size_t)k*Nd + col] : 0.f;
      unsigned short hb = f2bf(v);
      h[j] = (short)hb; l[j] = (short)f2bf(v - bf2f(hb));
    }
    size_t off = (size_t)fid*512 + (size_t)lane*8;
    *(s16x8*)(WfH + off) = h;
    *(s16x8*)(WfL + off) = l;
  } else if(b < PB + WA){
    int wid = (b - PB)*4 + (tid >> 6);
    float s = 0.f, d = 0.f;
    if(wid < 128){
      #pragma unroll
      for(int j=0;j<4;j++){
        int c = lane + j*64;
        float v = B4[(size_t)wid*256 + c];
        s += v * a1s[c]; d += v * a1d[c];
      }
    } else {
      int r = wid - 128;
      #pragma unroll
      for(int j=0;j<2;j++){
        int c = lane + j*64;
        float v = B5[(size_t)r*128 + c];
        s += v * a2s[c]; d += v * a2d[c];
      }
    }
    #pragma unroll
    for(int off=32; off; off>>=1){ s += __shfl_down(s, off); d += __shfl_down(d, off); }
    if(lane==0){
      if(wid < 128){ o1s[wid] = s; o1d[wid] = d; }
      else         { o2s[wid-128] = s; o2d[wid-128] = d; }
    }
  } else if(b < PB + WA + PA){
    int fid = (b - PB - WA)*4 + (tid >> 6);
    if(fid >= Mc) return;
    int row = fid*16 + (lane & 15);
    int k0  = (lane >> 4)*8;
    s16x8 h, l;
    if(row < n){
      const float* ap = x + (size_t)row*10;
      #pragma unroll
      for(int j=0;j<8;j++){
        float v = (k0 + j < 10) ? ap[k0 + j] : 0.f;
        unsigned short hb = f2bf(v);
        h[j] = (short)hb; l[j] = (short)f2bf(v - bf2f(hb));
      }
    } else {
      #pragma unroll
      for(int j=0;j<8;j++){ h[j]=0; l[j]=0; }
    }
    size_t off = (size_t)fid*512 + (size_t)lane*8;
    *(s16x8*)(XH + off) = h;
    *(s16x8*)(XL + off) = l;
  } else {
    int base = (b - PB - WA - PA)*1024 + tid;
    #pragma unroll
    for(int j=0;j<4;j++){
      int e = base + j*256;
      if(e < E) atomicAdd(&deg[dst[e]], 1);
    }
  }
}

// ---------------- scan ----------------
__global__ __launch_bounds__(1024) void k_scan1(const int* __restrict__ deg,
                                                int* __restrict__ part,
                                                int* __restrict__ bsum, int n){
  int i = blockIdx.x*1024 + threadIdx.x;
  int lane = threadIdx.x & 63, wv = threadIdx.x >> 6;
  int v = (i < n) ? deg[i] : 0;
  int s = v;
  #pragma unroll
  for(int off=1; off<64; off<<=1){
    int t = __shfl_up(s, off);
    if(lane >= off) s += t;
  }
  __shared__ int wsum[16];
  if(lane==63) wsum[wv] = s;
  __syncthreads();
  if(wv==0 && lane<16){
    int t = wsum[lane], ss = t;
    #pragma unroll
    for(int off=1; off<16; off<<=1){
      int u = __shfl_up(ss, off);
      if(lane >= off) ss += u;
    }
    wsum[lane] = ss - t;
    if(lane==15) bsum[blockIdx.x] = ss;
  }
  __syncthreads();
  if(i < n) part[i] = s - v + wsum[wv];
}

// per-block base = sum(bsum[0..b)) computed locally; also zeroes logit bufs
__global__ __launch_bounds__(1024) void k_scan3(const int* __restrict__ part,
                                                const int* __restrict__ bsum,
                                                int* __restrict__ offs,
                                                float* __restrict__ z0, float* __restrict__ z1,
                                                float* __restrict__ z2, float* __restrict__ z3,
                                                int n, int E){
  __shared__ int base_sh;
  int b = blockIdx.x;
  if(threadIdx.x < 64){
    int acc = 0;
    for(int j = (int)threadIdx.x; j < b; j += 64) acc += bsum[j];
    #pragma unroll
    for(int off=32; off; off>>=1) acc += __shfl_down(acc, off);
    if(threadIdx.x==0) base_sh = acc;
  }
  __syncthreads();
  int base = base_sh;
  int i = b*1024 + (int)threadIdx.x;
  if(i < n){
    offs[i] = part[i] + base;
    z0[i] = 0.f; z1[i] = 0.f; z2[i] = 0.f; z3[i] = 0.f;
  }
  if(b==0 && threadIdx.x==0) offs[n] = E;
}

// single-dispatch 2-phase placement: blocks [0,ebk) handle dst<half, [ebk,2ebk) the rest.
// HW dispatches blocks in order -> scatter window stays small/L2-resident per phase.
__global__ void k_fill2(const int* __restrict__ src, const int* __restrict__ dst,
                        const int* __restrict__ offs, int* __restrict__ cur,
                        int* __restrict__ esrc, int E, int half, int n, int ebk){
  int phase = (blockIdx.x >= (unsigned)ebk) ? 1 : 0;
  int b = blockIdx.x - phase*ebk;
  int e = b*256 + (int)threadIdx.x;
  int lo = phase ? half : 0;
  int hi = phase ? n : half;
  if(e < E){
    int d = dst[e];
    if(d >= lo && d < hi){
      int pos = offs[d] + atomicAdd(&cur[d], 1);
      esrc[pos] = src[e];
    }
  }
}

// ---------------- GIN agg: bf16 rows D=64, eighth-wave split, frag-epilogue ----------------
template<bool BR>
__global__ __launch_bounds__(256) void k_gin_agg(const unsigned short* __restrict__ xin,
                                                 const int* __restrict__ offs,
                                                 const int* __restrict__ esrc,
                                                 const float* __restrict__ bias,
                                                 unsigned short* __restrict__ fhi,
                                                 unsigned short* __restrict__ flo, int n){
  int wid  = (int)((blockIdx.x*256u + threadIdx.x) >> 6);
  int lane = threadIdx.x & 63;
  if(wid >= n) return;
  int g = lane >> 3, sub = lane & 7;
  float acc[8];
  #pragma unroll
  for(int k=0;k<8;k++) acc[k] = 0.f;
  int e0 = offs[wid], e1 = offs[wid+1];
  int t = e0;
  for(; t+15 < e1; t += 16){
    int sA = esrc[t + g], sB = esrc[t + 8 + g];
    u16x8 rA = *(const u16x8*)(xin + (size_t)sA*64 + 8*sub);
    u16x8 rB = *(const u16x8*)(xin + (size_t)sB*64 + 8*sub);
    #pragma unroll
    for(int k=0;k<8;k++) acc[k] += bf2f(rA[k]) + bf2f(rB[k]);
  }
  for(; t+7 < e1; t += 8){
    int s = esrc[t + g];
    u16x8 r = *(const u16x8*)(xin + (size_t)s*64 + 8*sub);
    #pragma unroll
    for(int k=0;k<8;k++) acc[k] += bf2f(r[k]);
  }
  if(t < e1){
    int idx = t + g;
    bool ok = idx < e1;
    int s = esrc[ok ? idx : e0];
    u16x8 r = *(const u16x8*)(xin + (size_t)s*64 + 8*sub);
    float w = ok ? 1.f : 0.f;
    #pragma unroll
    for(int k=0;k<8;k++) acc[k] += w*bf2f(r[k]);
  }
  #pragma unroll
  for(int off=32; off>=8; off>>=1)
    #pragma unroll
    for(int k=0;k<8;k++) acc[k] += __shfl_down(acc[k], off);
  if(lane < 8){
    u16x8 rs = *(const u16x8*)(xin + (size_t)wid*64 + 8*sub);
    u16x8 h, l;
    #pragma unroll
    for(int k=0;k<8;k++){
      float o = acc[k] + bf2f(rs[k]);
      if(BR) o = fmaxf(o + bias[8*sub + k], 0.f);
      unsigned short hb = f2bf(o);
      h[k] = hb; l[k] = f2bf(o - bf2f(hb));
    }
    int mc = wid >> 4;
    size_t base = ((size_t)(mc*2 + (sub>>2))*64 + (wid & 15) + (sub & 3)*16) * 8;
    *(u16x8*)(fhi + base) = h;
    *(u16x8*)(flo + base) = l;
  }
}

// ---------------- split-bf16 MFMA GEMM ----------------
// OMODE: 0 fp32 C | 1 bf16 row-major | 2 A-frag out | 3 A-frag out + atomic dots
//        4 bf16 row-major (via LDS transpose) + atomic dots
template<int ACT, bool HASBIAS, int OMODE>
__global__ __launch_bounds__(256) void k_mgemm(const unsigned short* __restrict__ Ahi,
                                               const unsigned short* __restrict__ Alo,
                                               const unsigned short* __restrict__ Bhi,
                                               const unsigned short* __restrict__ Blo,
                                               const float* __restrict__ bias,
                                               float* __restrict__ C,
                                               unsigned short* __restrict__ Cbf,
                                               unsigned short* __restrict__ foh,
                                               unsigned short* __restrict__ fol,
                                               const float* __restrict__ dwS,
                                               const float* __restrict__ dwD,
                                               float* __restrict__ dotS,
                                               float* __restrict__ dotD,
                                               int M, int Nd, int Kc, int Mc){
  int tid = threadIdx.x;
  int wid = tid >> 6, lane = tid & 63;
  int wm = wid >> 1, wn = wid & 1;
  int mcb = blockIdx.x*8 + wm*4;
  int ncb = blockIdx.y*4 + wn*2;

  f32x4 acc[4][2];
  #pragma unroll
  for(int f=0;f<4;f++)
    #pragma unroll
    for(int g=0;g<2;g++) acc[f][g] = (f32x4){0.f,0.f,0.f,0.f};

  for(int kc=0; kc<Kc; kc++){
    s16x8 ah[4], al[4], bh[2], bl[2];
    #pragma unroll
    for(int f=0;f<4;f++){
      int mcf = mcb + f; if(mcf > Mc-1) mcf = Mc-1;
      size_t off = ((size_t)mcf*Kc + kc)*512 + (size_t)lane*8;
      ah[f] = *(const s16x8*)(Ahi + off);
      al[f] = *(const s16x8*)(Alo + off);
    }
    #pragma unroll
    for(int g=0;g<2;g++){
      size_t off = ((size_t)(ncb+g)*Kc + kc)*512 + (size_t)lane*8;
      bh[g] = *(const s16x8*)(Bhi + off);
      bl[g] = *(const s16x8*)(Blo + off);
    }
    #pragma unroll
    for(int f=0;f<4;f++)
      #pragma unroll
      for(int g=0;g<2;g++){
        acc[f][g] = bmma(ah[f], bh[g], acc[f][g]);
        acc[f][g] = bmma(ah[f], bl[g], acc[f][g]);
        acc[f][g] = bmma(al[f], bh[g], acc[f][g]);
      }
  }

  if constexpr(OMODE <= 1){
    #pragma unroll
    for(int g=0;g<2;g++){
      int col = (ncb+g)*16 + (lane & 15);
      float bv = HASBIAS ? bias[col] : 0.f;
      #pragma unroll
      for(int f=0;f<4;f++){
        int row0 = (mcb+f)*16 + (lane>>4)*4;
        #pragma unroll
        for(int r=0;r<4;r++){
          int row = row0 + r;
          if(row < M){
            float v = acc[f][g][r] + bv;
            if(ACT) v = fmaxf(v, 0.f);
            if(OMODE==1) Cbf[(size_t)row*Nd + col] = f2bf(v);
            else         C  [(size_t)row*Nd + col] = v;
          }
        }
      }
    }
  } else {
    __shared__ float tile[4][64][33];
    #pragma unroll
    for(int g=0;g<2;g++){
      float bv = HASBIAS ? bias[(ncb+g)*16 + (lane&15)] : 0.f;
      int ck = g*16 + (lane & 15);
      #pragma unroll
      for(int f=0;f<4;f++){
        int rb = f*16 + (lane>>4)*4;
        #pragma unroll
        for(int r=0;r<4;r++){
          float v = acc[f][g][r] + bv;
          if(ACT) v = fmaxf(v, 0.f);
          tile[wid][rb + r][ck] = v;
        }
      }
    }
    asm volatile("" ::: "memory");
    int Kcn = Nd >> 5;
    int kcn = ncb >> 1;
    int rr = lane & 15, cb = lane >> 4;
    #pragma unroll
    for(int f=0;f<4;f++){
      int mcf = mcb + f;
      if(mcf >= Mc) continue;
      float o[8];
      #pragma unroll
      for(int j=0;j<8;j++) o[j] = tile[wid][f*16 + rr][cb*8 + j];
      if constexpr(OMODE == 4){
        u16x8 hb;
        #pragma unroll
        for(int j=0;j<8;j++) hb[j] = f2bf(o[j]);
        int row = mcf*16 + rr;
        *(u16x8*)(Cbf + (size_t)row*Nd + kcn*32 + cb*8) = hb;
      } else {
        u16x8 h, l;
        #pragma unroll
        for(int j=0;j<8;j++){
          unsigned short hb = f2bf(o[j]);
          h[j] = hb; l[j] = f2bf(o[j] - bf2f(hb));
        }
        size_t base = ((size_t)mcf*Kcn + kcn)*512 + (size_t)lane*8;
        *(u16x8*)(foh + base) = h;
        *(u16x8*)(fol + base) = l;
      }
      if constexpr(OMODE == 3 || OMODE == 4){
        float sv = 0.f, dv = 0.f;
        #pragma unroll
        for(int j=0;j<8;j++){
          int col = kcn*32 + cb*8 + j;
          sv += o[j]*dwS[col]; dv += o[j]*dwD[col];
        }
        sv += __shfl_xor(sv, 16); sv += __shfl_xor(sv, 32);
        dv += __shfl_xor(dv, 16); dv += __shfl_xor(dv, 32);
        if(cb == 0){
          int row = mcf*16 + rr;
          atomicAdd(dotS + row, sv);
          atomicAdd(dotD + row, dv);
        }
      }
    }
  }
}

// ---------------- GAT1 pre-projection agg: D=128 bf16, quarter-wave, online softmax, frag out ----------------
__global__ __launch_bounds__(256) void k_gat1_aggpre(const unsigned short* __restrict__ hB,
                                                     const float* __restrict__ as_, const float* __restrict__ ad_,
                                                     const int* __restrict__ offs, const int* __restrict__ esrc,
                                                     unsigned short* __restrict__ fhi, unsigned short* __restrict__ flo,
                                                     int n){
  int wid  = (int)((blockIdx.x*256u + threadIdx.x) >> 6);
  int lane = threadIdx.x & 63;
  if(wid >= n) return;
  int q = lane >> 4, sub = lane & 15;
  float adi = ad_[wid];
  u16x8 rs = *(const u16x8*)(hB + (size_t)wid*128 + 8*sub);
  float m, S, acc[8];
  if(q == 0){
    m = lrelu(as_[wid] + adi); S = 1.f;
    #pragma unroll
    for(int k=0;k<8;k++) acc[k] = bf2f(rs[k]);
  } else {
    m = -3e38f; S = 0.f;
    #pragma unroll
    for(int k=0;k<8;k++) acc[k] = 0.f;
  }
  int e0 = offs[wid], e1 = offs[wid+1];
  int t = e0;
  for(; t+15 < e1; t += 16){
    int s0 = esrc[t + q], s1 = esrc[t + 4 + q], s2 = esrc[t + 8 + q], s3 = esrc[t + 12 + q];
    u16x8 r0 = *(const u16x8*)(hB + (size_t)s0*128 + 8*sub);
    u16x8 r1 = *(const u16x8*)(hB + (size_t)s1*128 + 8*sub);
    u16x8 r2 = *(const u16x8*)(hB + (size_t)s2*128 + 8*sub);
    u16x8 r3 = *(const u16x8*)(hB + (size_t)s3*128 + 8*sub);
    float l0 = lrelu(as_[s0] + adi), l1 = lrelu(as_[s1] + adi);
    float l2 = lrelu(as_[s2] + adi), l3 = lrelu(as_[s3] + adi);
    float lm = fmaxf(fmaxf(l0, l1), fmaxf(l2, l3));
    if(lm > m + 8.f){
      float sc = __expf(m - lm); S *= sc;
      #pragma unroll
      for(int k=0;k<8;k++) acc[k] *= sc;
      m = lm;
    }
    float w0 = __expf(l0 - m), w1 = __expf(l1 - m), w2 = __expf(l2 - m), w3 = __expf(l3 - m);
    S += w0 + w1 + w2 + w3;
    #pragma unroll
    for(int k=0;k<8;k++)
      acc[k] += w0*bf2f(r0[k]) + w1*bf2f(r1[k]) + w2*bf2f(r2[k]) + w3*bf2f(r3[k]);
  }
  for(; t+7 < e1; t += 8){
    int s0 = esrc[t + q], s1 = esrc[t + 4 + q];
    u16x8 r0 = *(const u16x8*)(hB + (size_t)s0*128 + 8*sub);
    u16x8 r1 = *(const u16x8*)(hB + (size_t)s1*128 + 8*sub);
    float l0 = lrelu(as_[s0] + adi), l1 = lrelu(as_[s1] + adi);
    float lm = fmaxf(l0, l1);
    if(lm > m + 8.f){
      float sc = __expf(m - lm); S *= sc;
      #pragma unroll
      for(int k=0;k<8;k++) acc[k] *= sc;
      m = lm;
    }
    float w0 = __expf(l0 - m), w1 = __expf(l1 - m);
    S += w0 + w1;
    #pragma unroll
    for(int k=0;k<8;k++) acc[k] += w0*bf2f(r0[k]) + w1*bf2f(r1[k]);
  }
  while(t < e1){
    int idx = t + q;
    bool ok = idx < e1;
    int s = esrc[ok ? idx : e0];
    u16x8 r = *(const u16x8*)(hB + (size_t)s*128 + 8*sub);
    float l = ok ? lrelu(as_[s] + adi) : -3e38f;
    if(l > m + 8.f){
      float sc = __expf(m - l); S *= sc;
      #pragma unroll
      for(int k=0;k<8;k++) acc[k] *= sc;
      m = l;
    }
    float w = __expf(l - m);
    S += w;
    #pragma unroll
    for(int k=0;k<8;k++) acc[k] += w*bf2f(r[k]);
    t += 4;
  }
  #pragma unroll
  for(int off=32; off>=16; off>>=1){
    float mo = __shfl_down(m, off), So = __shfl_down(S, off);
    float ao[8];
    #pragma unroll
    for(int k=0;k<8;k++) ao[k] = __shfl_down(acc[k], off);
    float M = fmaxf(m, mo);
    float sc0 = __expf(m - M), sc1 = __expf(mo - M);
    S = S*sc0 + So*sc1;
    #pragma unroll
    for(int k=0;k<8;k++) acc[k] = acc[k]*sc0 + ao[k]*sc1;
    m = M;
  }
  if(lane < 16){
    float inv = 1.f/(S + 1e-16f);
    u16x8 h, l;
    #pragma unroll
    for(int k=0;k<8;k++){
      float v = acc[k]*inv;
      unsigned short hb = f2bf(v);
      h[k] = hb; l[k] = f2bf(v - bf2f(hb));
    }
    int mc = wid >> 4;
    size_t base = ((size_t)(mc*4 + (sub>>2))*64 + (wid & 15) + (sub & 3)*16) * 8;
    *(u16x8*)(fhi + base) = h;
    *(u16x8*)(flo + base) = l;
  }
}

// ---------------- GAT2 agg: D=128, quarter-wave, online softmax, fp32 out ----------------
__global__ __launch_bounds__(256) void k_gat2_agg(const unsigned short* __restrict__ hP,
                                                  const float* __restrict__ as_, const float* __restrict__ ad_,
                                                  const int* __restrict__ offs, const int* __restrict__ esrc,
                                                  const float* __restrict__ bias, float* __restrict__ out, int n){
  int wid  = (int)((blockIdx.x*256u + threadIdx.x) >> 6);
  int lane = threadIdx.x & 63;
  if(wid >= n) return;
  int q = lane >> 4, sub = lane & 15;
  float adi = ad_[wid];
  u16x8 rs = *(const u16x8*)(hP + (size_t)wid*128 + 8*sub);
  float m, S, acc[8];
  if(q == 0){
    m = lrelu(as_[wid] + adi); S = 1.f;
    #pragma unroll
    for(int k=0;k<8;k++) acc[k] = bf2f(rs[k]);
  } else {
    m = -3e38f; S = 0.f;
    #pragma unroll
    for(int k=0;k<8;k++) acc[k] = 0.f;
  }
  int e0 = offs[wid], e1 = offs[wid+1];
  int t = e0;
  for(; t+15 < e1; t += 16){
    int s0 = esrc[t + q], s1 = esrc[t + 4 + q], s2 = esrc[t + 8 + q], s3 = esrc[t + 12 + q];
    u16x8 r0 = *(const u16x8*)(hP + (size_t)s0*128 + 8*sub);
    u16x8 r1 = *(const u16x8*)(hP + (size_t)s1*128 + 8*sub);
    u16x8 r2 = *(const u16x8*)(hP + (size_t)s2*128 + 8*sub);
    u16x8 r3 = *(const u16x8*)(hP + (size_t)s3*128 + 8*sub);
    float l0 = lrelu(as_[s0] + adi), l1 = lrelu(as_[s1] + adi);
    float l2 = lrelu(as_[s2] + adi), l3 = lrelu(as_[s3] + adi);
    float lm = fmaxf(fmaxf(l0, l1), fmaxf(l2, l3));
    if(lm > m + 8.f){
      float sc = __expf(m - lm); S *= sc;
      #pragma unroll
      for(int k=0;k<8;k++) acc[k] *= sc;
      m = lm;
    }
    float w0 = __expf(l0 - m), w1 = __expf(l1 - m), w2 = __expf(l2 - m), w3 = __expf(l3 - m);
    S += w0 + w1 + w2 + w3;
    #pragma unroll
    for(int k=0;k<8;k++)
      acc[k] += w0*bf2f(r0[k]) + w1*bf2f(r1[k]) + w2*bf2f(r2[k]) + w3*bf2f(r3[k]);
  }
  for(; t+7 < e1; t += 8){
    int s0 = esrc[t + q], s1 = esrc[t + 4 + q];
    u16x8 r0 = *(const u16x8*)(hP + (size_t)s0*128 + 8*sub);
    u16x8 r1 = *(const u16x8*)(hP + (size_t)s1*128 + 8*sub);
    float l0 = lrelu(as_[s0] + adi), l1 = lrelu(as_[s1] + adi);
    float lm = fmaxf(l0, l1);
    if(lm > m + 8.f){
      float sc = __expf(m - lm); S *= sc;
      #pragma unroll
      for(int k=0;k<8;k++) acc[k] *= sc;
      m = lm;
    }
    float w0 = __expf(l0 - m), w1 = __expf(l1 - m);
    S += w0 + w1;
    #pragma unroll
    for(int k=0;k<8;k++) acc[k] += w0*bf2f(r0[k]) + w1*bf2f(r1[k]);
  }
  while(t < e1){
    int idx = t + q;
    bool ok = idx < e1;
    int s = esrc[ok ? idx : e0];
    u16x8 r = *(const u16x8*)(hP + (size_t)s*128 + 8*sub);
    float l = ok ? lrelu(as_[s] + adi) : -3e38f;
    if(l > m + 8.f){
      float sc = __expf(m - l); S *= sc;
      #pragma unroll
      for(int k=0;k<8;k++) acc[k] *= sc;
      m = l;
    }
    float w = __expf(l - m);
    S += w;
    #pragma unroll
    for(int k=0;k<8;k++) acc[k] += w*bf2f(r[k]);
    t += 4;
  }
  #pragma unroll
  for(int off=32; off>=16; off>>=1){
    float mo = __shfl_down(m, off), So = __shfl_down(S, off);
    float ao[8];
    #pragma unroll
    for(int k=0;k<8;k++) ao[k] = __shfl_down(acc[k], off);
    float M = fmaxf(m, mo);
    float sc0 = __expf(m - M), sc1 = __expf(mo - M);
    S = S*sc0 + So*sc1;
    #pragma unroll
    for(int k=0;k<8;k++) acc[k] = acc[k]*sc0 + ao[k]*sc1;
    m = M;
  }
  if(lane < 16){
    float inv = 1.f/(S + 1e-16f);
    float4 o0, o1;
    o0.x = acc[0]*inv + bias[8*sub  ]; o0.y = acc[1]*inv + bias[8*sub+1];
    o0.z = acc[2]*inv + bias[8*sub+2]; o0.w = acc[3]*inv + bias[8*sub+3];
    o1.x = acc[4]*inv + bias[8*sub+4]; o1.y = acc[5]*inv + bias[8*sub+5];
    o1.z = acc[6]*inv + bias[8*sub+6]; o1.w = acc[7]*inv + bias[8*sub+7];
    *(float4*)(out + (size_t)wid*128 + 8*sub)     = o0;
    *(float4*)(out + (size_t)wid*128 + 8*sub + 4) = o1;
  }
}

extern "C" void kernel_launch(void* const* d_in, const int* in_sizes, int n_in,
                              void* d_out, int out_size, void* d_ws, size_t ws_size,
                              hipStream_t stream){
  const float* x        = (const float*)d_in[0];
  const int*   ei       = (const int*)  d_in[1];
  const float* gin1_w1  = (const float*)d_in[3];
  const float* gin1_b1  = (const float*)d_in[4];
  const float* gin1_w2  = (const float*)d_in[5];
  const float* gin1_b2  = (const float*)d_in[6];
  const float* gin2_w1  = (const float*)d_in[7];
  const float* gin2_b1  = (const float*)d_in[8];
  const float* gin2_w2  = (const float*)d_in[9];
  const float* gin2_b2  = (const float*)d_in[10];
  const float* gat1_w   = (const float*)d_in[11];
  const float* gat1_as  = (const float*)d_in[12];
  const float* gat1_ad  = (const float*)d_in[13];
  const float* gat1_b   = (const float*)d_in[14];
  const float* gat2_w   = (const float*)d_in[15];
  const float* gat2_as  = (const float*)d_in[16];
  const float* gat2_ad  = (const float*)d_in[17];
  const float* gat2_b   = (const float*)d_in[18];

  const int n = in_sizes[0] / 10;
  const int E = in_sizes[1] / 2;
  const int* src = ei;
  const int* dst = ei + E;
  const int Mc = (n + 15) / 16;
  const int nb = (n + 1023) / 1024;
  const size_t npad = ((size_t)n*4 + 255) & ~(size_t)255;

  char* w = (char*)d_ws;
  auto carve = [&](size_t bytes)->char*{ char* p = w; w += (bytes + 255) & ~(size_t)255; return p; };
  int*   esrc = (int*)  carve((size_t)E*4);
  int*   offs = (int*)  carve((size_t)(n+1)*4);
  int*   deg  = (int*)  carve(npad);          // deg & cur contiguous -> one memset
  int*   cur  = (int*)  carve(npad);
  int*   part = (int*)  carve((size_t)n*4);
  int*   bsum = (int*)  carve((size_t)1024*4);
  unsigned short* Ybf   = (unsigned short*)carve((size_t)n*64*2);
  unsigned short* Hbf   = (unsigned short*)carve((size_t)n*64*2);
  unsigned short* hB2bf = (unsigned short*)carve((size_t)n*128*2);
  unsigned short* Pbf2  = (unsigned short*)carve((size_t)n*128*2);
  float* as_  = (float*)carve((size_t)n*4);
  float* ad_  = (float*)carve((size_t)n*4);
  float* as2_ = (float*)carve((size_t)n*4);
  float* ad2_ = (float*)carve((size_t)n*4);
  float* waS  = (float*)carve(256*4);
  float* waD  = (float*)carve(256*4);
  float* waS2 = (float*)carve(256*4);
  float* waD2 = (float*)carve(256*4);
  unsigned short* FAh = (unsigned short*)carve((size_t)Mc*8*512*2);
  unsigned short* FAl = (unsigned short*)carve((size_t)Mc*8*512*2);
  unsigned short* FBh = (unsigned short*)carve((size_t)Mc*8*512*2);
  unsigned short* FBl = (unsigned short*)carve((size_t)Mc*8*512*2);
  unsigned short* WfH = (unsigned short*)carve((size_t)188*512*2);
  unsigned short* WfL = (unsigned short*)carve((size_t)188*512*2);

  const int TPB = 256;
  int ebk = (E + TPB - 1) / TPB;
  int wbk = (n + 3) / 4;
  int gx  = (Mc + 7) / 8;
  const size_t W0 = 0, W1o = 4*512, W2o = 12*512, W3o = 28*512, W4o = 60*512, W5o = 124*512;

  // fused setup: weight frags + folded attn vecs + x frags + degree histogram (4 edges/thread)
  hipMemsetAsync(deg, 0, npad*2, stream);
  int PB = 47, WA = 96, PA = (Mc*64 + 255)/256;
  int DG = (E + 1023) / 1024;
  k_setup<<<PB + WA + PA + DG, TPB, 0, stream>>>(
      gin1_w1, gin1_w2, gin2_w1, gin2_w2, gat1_w, gat2_w, WfH, WfL,
      gat1_as, gat1_ad, gat2_as, gat2_ad, waS, waD, waS2, waD2,
      x, FAh, FAl, Mc, n, dst, deg, E, PB, WA, PA);

  // scan + single-dispatch 2-phase fill
  k_scan1<<<nb, 1024, 0, stream>>>(deg, part, bsum, n);
  k_scan3<<<nb, 1024, 0, stream>>>(part, bsum, offs, as_, ad_, as2_, ad2_, n, E);
  int half = (n + 1) / 2;
  k_fill2<<<2*ebk, TPB, 0, stream>>>(src, dst, offs, cur, esrc, E, half, n, ebk);

  // GIN1 (projection-first): y = x@W1 -> Ybf; agg(Ybf)+b1+relu -> FB frags; 64->64 +b2+relu -> Hbf
  k_mgemm<0,false,1><<<dim3(gx,1), TPB, 0, stream>>>(FAh, FAl, WfH+W0, WfL+W0, nullptr,
      nullptr, Ybf, nullptr, nullptr, nullptr, nullptr, nullptr, nullptr, n, 64, 1, Mc);
  k_gin_agg<true><<<wbk, TPB, 0, stream>>>(Ybf, offs, esrc, gin1_b1, FBh, FBl, n);
  k_mgemm<1,true,1><<<dim3(gx,1), TPB, 0, stream>>>(FBh, FBl, WfH+W1o, WfL+W1o, gin1_b2,
      nullptr, Hbf, nullptr, nullptr, nullptr, nullptr, nullptr, nullptr, n, 64, 2, Mc);

  // GIN2: agg(Hbf) -> FA frags; 64->128 relu -> FB frags; 128->128 +bias -> hB2bf + GAT1 logits
  k_gin_agg<false><<<wbk, TPB, 0, stream>>>(Hbf, offs, esrc, nullptr, FAh, FAl, n);
  k_mgemm<1,true,2><<<dim3(gx,2), TPB, 0, stream>>>(FAh, FAl, WfH+W2o, WfL+W2o, gin2_b1,
      nullptr, nullptr, FBh, FBl, nullptr, nullptr, nullptr, nullptr, n, 128, 2, Mc);
  k_mgemm<0,true,4><<<dim3(gx,2), TPB, 0, stream>>>(FBh, FBl, WfH+W3o, WfL+W3o, gin2_b2,
      nullptr, hB2bf, nullptr, nullptr, waS, waD, as_, ad_, n, 128, 4, Mc);

  // GAT1: pre-projection fused agg+softmax -> FA frags; proj 128->256 +bias+relu -> FB frags + GAT2 logits
  k_gat1_aggpre<<<wbk, TPB, 0, stream>>>(hB2bf, as_, ad_, offs, esrc, FAh, FAl, n);
  k_mgemm<1,true,3><<<dim3(gx,4), TPB, 0, stream>>>(FAh, FAl, WfH+W4o, WfL+W4o, gat1_b,
      nullptr, nullptr, FBh, FBl, waS2, waD2, as2_, ad2_, n, 256, 4, Mc);

  // GAT2: proj 256->128 -> Pbf2; fused agg+softmax -> d_out
  k_mgemm<0,false,1><<<dim3(gx,2), TPB, 0, stream>>>(FBh, FBl, WfH+W5o, WfL+W5o, nullptr,
      nullptr, Pbf2, nullptr, nullptr, nullptr, nullptr, nullptr, nullptr, n, 128, 8, Mc);
  k_gat2_agg<<<wbk, TPB, 0, stream>>>(Pbf2, as2_, ad2_, offs, esrc, gat2_b, (float*)d_out, n);
}

// Round 14
// 317.826 us; speedup vs baseline: 3.1544x; 1.0150x over previous
//
#include <hip/hip_runtime.h>
#include <math.h>

__device__ __forceinline__ float lrelu(float x){ return x > 0.f ? x : 0.2f*x; }

typedef short s16x8 __attribute__((ext_vector_type(8)));
typedef float f32x4 __attribute__((ext_vector_type(4)));
typedef unsigned short u16x8 __attribute__((ext_vector_type(8)));

__device__ __forceinline__ f32x4 bmma(s16x8 a, s16x8 b, f32x4 c){
  return __builtin_amdgcn_mfma_f32_16x16x32_bf16(a, b, c, 0, 0, 0);
}

__device__ __forceinline__ unsigned short f2bf(float f){
  unsigned u = __float_as_uint(f);
  unsigned r = (u + 0x7fffu + ((u >> 16) & 1u)) >> 16;
  return (unsigned short)r;
}
__device__ __forceinline__ float bf2f(unsigned short h){
  return __uint_as_float(((unsigned)h) << 16);
}

// ---------------- fused setup: weight frags + folded attn vecs + x frags + degree count ----
__global__ __launch_bounds__(256) void k_setup(const float* __restrict__ B0,
                                               const float* __restrict__ B1,
                                               const float* __restrict__ B2,
                                               const float* __restrict__ B3,
                                               const float* __restrict__ B4,
                                               const float* __restrict__ B5,
                                               unsigned short* __restrict__ WfH,
                                               unsigned short* __restrict__ WfL,
                                               const float* __restrict__ a1s, const float* __restrict__ a1d,
                                               const float* __restrict__ a2s, const float* __restrict__ a2d,
                                               float* __restrict__ o1s, float* __restrict__ o1d,
                                               float* __restrict__ o2s, float* __restrict__ o2d,
                                               const float* __restrict__ x,
                                               unsigned short* __restrict__ XH,
                                               unsigned short* __restrict__ XL,
                                               int Mc, int n,
                                               const int* __restrict__ dst, int* __restrict__ deg, int E,
                                               int PB, int WA, int PA){
  int b = blockIdx.x;
  int tid = threadIdx.x;
  int lane = tid & 63;
  if(b < PB){
    int fid = b*4 + (tid >> 6);
    if(fid >= 188) return;
    const float* B; int K, Nd, Kc, fl;
    if(fid < 4)       { B=B0; K=10;  Nd=64;  Kc=1; fl=fid;     }
    else if(fid < 12) { B=B1; K=64;  Nd=64;  Kc=2; fl=fid-4;   }
    else if(fid < 28) { B=B2; K=64;  Nd=128; Kc=2; fl=fid-12;  }
    else if(fid < 60) { B=B3; K=128; Nd=128; Kc=4; fl=fid-28;  }
    else if(fid < 124){ B=B4; K=128; Nd=256; Kc=4; fl=fid-60;  }
    else              { B=B5; K=256; Nd=128; Kc=8; fl=fid-124; }
    int nc = fl / Kc, kc = fl - nc*Kc;
    int col = nc*16 + (lane & 15);
    int k0  = kc*32 + (lane >> 4)*8;
    s16x8 h, l;
    #pragma unroll
    for(int j=0;j<8;j++){
      int k = k0 + j;
      float v = (k < K) ? B[(size_t)k*Nd + col] : 0.f;
      unsigned short hb = f2bf(v);
      h[j] = (short)hb; l[j] = (short)f2bf(v - bf2f(hb));
    }
    size_t off = (size_t)fid*512 + (size_t)lane*8;
    *(s16x8*)(WfH + off) = h;
    *(s16x8*)(WfL + off) = l;
  } else if(b < PB + WA){
    int wid = (b - PB)*4 + (tid >> 6);
    float s = 0.f, d = 0.f;
    if(wid < 128){
      #pragma unroll
      for(int j=0;j<4;j++){
        int c = lane + j*64;
        float v = B4[(size_t)wid*256 + c];
        s += v * a1s[c]; d += v * a1d[c];
      }
    } else {
      int r = wid - 128;
      #pragma unroll
      for(int j=0;j<2;j++){
        int c = lane + j*64;
        float v = B5[(size_t)r*128 + c];
        s += v * a2s[c]; d += v * a2d[c];
      }
    }
    #pragma unroll
    for(int off=32; off; off>>=1){ s += __shfl_down(s, off); d += __shfl_down(d, off); }
    if(lane==0){
      if(wid < 128){ o1s[wid] = s; o1d[wid] = d; }
      else         { o2s[wid-128] = s; o2d[wid-128] = d; }
    }
  } else if(b < PB + WA + PA){
    int fid = (b - PB - WA)*4 + (tid >> 6);
    if(fid >= Mc) return;
    int row = fid*16 + (lane & 15);
    int k0  = (lane >> 4)*8;
    s16x8 h, l;
    if(row < n){
      const float* ap = x + (size_t)row*10;
      #pragma unroll
      for(int j=0;j<8;j++){
        float v = (k0 + j < 10) ? ap[k0 + j] : 0.f;
        unsigned short hb = f2bf(v);
        h[j] = (short)hb; l[j] = (short)f2bf(v - bf2f(hb));
      }
    } else {
      #pragma unroll
      for(int j=0;j<8;j++){ h[j]=0; l[j]=0; }
    }
    size_t off = (size_t)fid*512 + (size_t)lane*8;
    *(s16x8*)(XH + off) = h;
    *(s16x8*)(XL + off) = l;
  } else {
    int base = (b - PB - WA - PA)*1024 + tid;
    #pragma unroll
    for(int j=0;j<4;j++){
      int e = base + j*256;
      if(e < E) atomicAdd(&deg[dst[e]], 1);
    }
  }
}

// ---------------- scan ----------------
__global__ __launch_bounds__(1024) void k_scan1(const int* __restrict__ deg,
                                                int* __restrict__ part,
                                                int* __restrict__ bsum, int n){
  int i = blockIdx.x*1024 + threadIdx.x;
  int lane = threadIdx.x & 63, wv = threadIdx.x >> 6;
  int v = (i < n) ? deg[i] : 0;
  int s = v;
  #pragma unroll
  for(int off=1; off<64; off<<=1){
    int t = __shfl_up(s, off);
    if(lane >= off) s += t;
  }
  __shared__ int wsum[16];
  if(lane==63) wsum[wv] = s;
  __syncthreads();
  if(wv==0 && lane<16){
    int t = wsum[lane], ss = t;
    #pragma unroll
    for(int off=1; off<16; off<<=1){
      int u = __shfl_up(ss, off);
      if(lane >= off) ss += u;
    }
    wsum[lane] = ss - t;
    if(lane==15) bsum[blockIdx.x] = ss;
  }
  __syncthreads();
  if(i < n) part[i] = s - v + wsum[wv];
}

// per-block base = sum(bsum[0..b)) computed locally; also zeroes logit bufs
__global__ __launch_bounds__(1024) void k_scan3(const int* __restrict__ part,
                                                const int* __restrict__ bsum,
                                                int* __restrict__ offs,
                                                float* __restrict__ z0, float* __restrict__ z1,
                                                float* __restrict__ z2, float* __restrict__ z3,
                                                int n, int E){
  __shared__ int base_sh;
  int b = blockIdx.x;
  if(threadIdx.x < 64){
    int acc = 0;
    for(int j = (int)threadIdx.x; j < b; j += 64) acc += bsum[j];
    #pragma unroll
    for(int off=32; off; off>>=1) acc += __shfl_down(acc, off);
    if(threadIdx.x==0) base_sh = acc;
  }
  __syncthreads();
  int base = base_sh;
  int i = b*1024 + (int)threadIdx.x;
  if(i < n){
    offs[i] = part[i] + base;
    z0[i] = 0.f; z1[i] = 0.f; z2[i] = 0.f; z3[i] = 0.f;
  }
  if(b==0 && threadIdx.x==0) offs[n] = E;
}

// XCD-partitioned placement: group g = blockIdx&7 (round-robins to XCD g) owns dst range g.
// Each esrc/cur line is then written by only one XCD -> partial lines merge in its L2.
__global__ void k_fill8(const int* __restrict__ src, const int* __restrict__ dst,
                        const int* __restrict__ offs, int* __restrict__ cur,
                        int* __restrict__ esrc, int E, int n){
  int grp = blockIdx.x & 7;
  int b   = blockIdx.x >> 3;
  int e = b*256 + (int)threadIdx.x;
  int per = (n + 7) >> 3;
  int lo = grp*per;
  int hi = lo + per; if(hi > n) hi = n;
  if(e < E){
    int d = dst[e];
    if(d >= lo && d < hi){
      int pos = offs[d] + atomicAdd(&cur[d], 1);
      esrc[pos] = src[e];
    }
  }
}

// ---------------- GIN agg: bf16 rows D=64, eighth-wave split, frag-epilogue ----------------
template<bool BR>
__global__ __launch_bounds__(256) void k_gin_agg(const unsigned short* __restrict__ xin,
                                                 const int* __restrict__ offs,
                                                 const int* __restrict__ esrc,
                                                 const float* __restrict__ bias,
                                                 unsigned short* __restrict__ fhi,
                                                 unsigned short* __restrict__ flo, int n){
  int wid  = (int)((blockIdx.x*256u + threadIdx.x) >> 6);
  int lane = threadIdx.x & 63;
  if(wid >= n) return;
  int g = lane >> 3, sub = lane & 7;
  float acc[8];
  #pragma unroll
  for(int k=0;k<8;k++) acc[k] = 0.f;
  int e0 = offs[wid], e1 = offs[wid+1];
  int t = e0;
  for(; t+15 < e1; t += 16){
    int sA = esrc[t + g], sB = esrc[t + 8 + g];
    u16x8 rA = *(const u16x8*)(xin + (size_t)sA*64 + 8*sub);
    u16x8 rB = *(const u16x8*)(xin + (size_t)sB*64 + 8*sub);
    #pragma unroll
    for(int k=0;k<8;k++) acc[k] += bf2f(rA[k]) + bf2f(rB[k]);
  }
  for(; t+7 < e1; t += 8){
    int s = esrc[t + g];
    u16x8 r = *(const u16x8*)(xin + (size_t)s*64 + 8*sub);
    #pragma unroll
    for(int k=0;k<8;k++) acc[k] += bf2f(r[k]);
  }
  if(t < e1){
    int idx = t + g;
    bool ok = idx < e1;
    int s = esrc[ok ? idx : e0];
    u16x8 r = *(const u16x8*)(xin + (size_t)s*64 + 8*sub);
    float w = ok ? 1.f : 0.f;
    #pragma unroll
    for(int k=0;k<8;k++) acc[k] += w*bf2f(r[k]);
  }
  #pragma unroll
  for(int off=32; off>=8; off>>=1)
    #pragma unroll
    for(int k=0;k<8;k++) acc[k] += __shfl_down(acc[k], off);
  if(lane < 8){
    u16x8 rs = *(const u16x8*)(xin + (size_t)wid*64 + 8*sub);
    u16x8 h, l;
    #pragma unroll
    for(int k=0;k<8;k++){
      float o = acc[k] + bf2f(rs[k]);
      if(BR) o = fmaxf(o + bias[8*sub + k], 0.f);
      unsigned short hb = f2bf(o);
      h[k] = hb; l[k] = f2bf(o - bf2f(hb));
    }
    int mc = wid >> 4;
    size_t base = ((size_t)(mc*2 + (sub>>2))*64 + (wid & 15) + (sub & 3)*16) * 8;
    *(u16x8*)(fhi + base) = h;
    *(u16x8*)(flo + base) = l;
  }
}

// ---------------- split-bf16 MFMA GEMM ----------------
// OMODE: 0 fp32 C | 1 bf16 row-major | 2 A-frag out | 3 A-frag out + atomic dots
//        4 bf16 row-major (via LDS transpose) + atomic dots
template<int ACT, bool HASBIAS, int OMODE>
__global__ __launch_bounds__(256) void k_mgemm(const unsigned short* __restrict__ Ahi,
                                               const unsigned short* __restrict__ Alo,
                                               const unsigned short* __restrict__ Bhi,
                                               const unsigned short* __restrict__ Blo,
                                               const float* __restrict__ bias,
                                               float* __restrict__ C,
                                               unsigned short* __restrict__ Cbf,
                                               unsigned short* __restrict__ foh,
                                               unsigned short* __restrict__ fol,
                                               const float* __restrict__ dwS,
                                               const float* __restrict__ dwD,
                                               float* __restrict__ dotS,
                                               float* __restrict__ dotD,
                                               int M, int Nd, int Kc, int Mc){
  int tid = threadIdx.x;
  int wid = tid >> 6, lane = tid & 63;
  int wm = wid >> 1, wn = wid & 1;
  int mcb = blockIdx.x*8 + wm*4;
  int ncb = blockIdx.y*4 + wn*2;

  f32x4 acc[4][2];
  #pragma unroll
  for(int f=0;f<4;f++)
    #pragma unroll
    for(int g=0;g<2;g++) acc[f][g] = (f32x4){0.f,0.f,0.f,0.f};

  for(int kc=0; kc<Kc; kc++){
    s16x8 ah[4], al[4], bh[2], bl[2];
    #pragma unroll
    for(int f=0;f<4;f++){
      int mcf = mcb + f; if(mcf > Mc-1) mcf = Mc-1;
      size_t off = ((size_t)mcf*Kc + kc)*512 + (size_t)lane*8;
      ah[f] = *(const s16x8*)(Ahi + off);
      al[f] = *(const s16x8*)(Alo + off);
    }
    #pragma unroll
    for(int g=0;g<2;g++){
      size_t off = ((size_t)(ncb+g)*Kc + kc)*512 + (size_t)lane*8;
      bh[g] = *(const s16x8*)(Bhi + off);
      bl[g] = *(const s16x8*)(Blo + off);
    }
    #pragma unroll
    for(int f=0;f<4;f++)
      #pragma unroll
      for(int g=0;g<2;g++){
        acc[f][g] = bmma(ah[f], bh[g], acc[f][g]);
        acc[f][g] = bmma(ah[f], bl[g], acc[f][g]);
        acc[f][g] = bmma(al[f], bh[g], acc[f][g]);
      }
  }

  if constexpr(OMODE <= 1){
    #pragma unroll
    for(int g=0;g<2;g++){
      int col = (ncb+g)*16 + (lane & 15);
      float bv = HASBIAS ? bias[col] : 0.f;
      #pragma unroll
      for(int f=0;f<4;f++){
        int row0 = (mcb+f)*16 + (lane>>4)*4;
        #pragma unroll
        for(int r=0;r<4;r++){
          int row = row0 + r;
          if(row < M){
            float v = acc[f][g][r] + bv;
            if(ACT) v = fmaxf(v, 0.f);
            if(OMODE==1) Cbf[(size_t)row*Nd + col] = f2bf(v);
            else         C  [(size_t)row*Nd + col] = v;
          }
        }
      }
    }
  } else {
    __shared__ float tile[4][64][33];
    #pragma unroll
    for(int g=0;g<2;g++){
      float bv = HASBIAS ? bias[(ncb+g)*16 + (lane&15)] : 0.f;
      int ck = g*16 + (lane & 15);
      #pragma unroll
      for(int f=0;f<4;f++){
        int rb = f*16 + (lane>>4)*4;
        #pragma unroll
        for(int r=0;r<4;r++){
          float v = acc[f][g][r] + bv;
          if(ACT) v = fmaxf(v, 0.f);
          tile[wid][rb + r][ck] = v;
        }
      }
    }
    asm volatile("" ::: "memory");
    int Kcn = Nd >> 5;
    int kcn = ncb >> 1;
    int rr = lane & 15, cb = lane >> 4;
    #pragma unroll
    for(int f=0;f<4;f++){
      int mcf = mcb + f;
      if(mcf >= Mc) continue;
      float o[8];
      #pragma unroll
      for(int j=0;j<8;j++) o[j] = tile[wid][f*16 + rr][cb*8 + j];
      if constexpr(OMODE == 4){
        u16x8 hb;
        #pragma unroll
        for(int j=0;j<8;j++) hb[j] = f2bf(o[j]);
        int row = mcf*16 + rr;
        *(u16x8*)(Cbf + (size_t)row*Nd + kcn*32 + cb*8) = hb;
      } else {
        u16x8 h, l;
        #pragma unroll
        for(int j=0;j<8;j++){
          unsigned short hb = f2bf(o[j]);
          h[j] = hb; l[j] = f2bf(o[j] - bf2f(hb));
        }
        size_t base = ((size_t)mcf*Kcn + kcn)*512 + (size_t)lane*8;
        *(u16x8*)(foh + base) = h;
        *(u16x8*)(fol + base) = l;
      }
      if constexpr(OMODE == 3 || OMODE == 4){
        float sv = 0.f, dv = 0.f;
        #pragma unroll
        for(int j=0;j<8;j++){
          int col = kcn*32 + cb*8 + j;
          sv += o[j]*dwS[col]; dv += o[j]*dwD[col];
        }
        sv += __shfl_xor(sv, 16); sv += __shfl_xor(sv, 32);
        dv += __shfl_xor(dv, 16); dv += __shfl_xor(dv, 32);
        if(cb == 0){
          int row = mcf*16 + rr;
          atomicAdd(dotS + row, sv);
          atomicAdd(dotD + row, dv);
        }
      }
    }
  }
}

// ---------------- GAT1 pre-projection agg: D=128 bf16, quarter-wave, online softmax, frag out ----------------
__global__ __launch_bounds__(256) void k_gat1_aggpre(const unsigned short* __restrict__ hB,
                                                     const float* __restrict__ as_, const float* __restrict__ ad_,
                                                     const int* __restrict__ offs, const int* __restrict__ esrc,
                                                     unsigned short* __restrict__ fhi, unsigned short* __restrict__ flo,
                                                     int n){
  int wid  = (int)((blockIdx.x*256u + threadIdx.x) >> 6);
  int lane = threadIdx.x & 63;
  if(wid >= n) return;
  int q = lane >> 4, sub = lane & 15;
  float adi = ad_[wid];
  u16x8 rs = *(const u16x8*)(hB + (size_t)wid*128 + 8*sub);
  float m, S, acc[8];
  if(q == 0){
    m = lrelu(as_[wid] + adi); S = 1.f;
    #pragma unroll
    for(int k=0;k<8;k++) acc[k] = bf2f(rs[k]);
  } else {
    m = -3e38f; S = 0.f;
    #pragma unroll
    for(int k=0;k<8;k++) acc[k] = 0.f;
  }
  int e0 = offs[wid], e1 = offs[wid+1];
  int t = e0;
  for(; t+15 < e1; t += 16){
    int s0 = esrc[t + q], s1 = esrc[t + 4 + q], s2 = esrc[t + 8 + q], s3 = esrc[t + 12 + q];
    u16x8 r0 = *(const u16x8*)(hB + (size_t)s0*128 + 8*sub);
    u16x8 r1 = *(const u16x8*)(hB + (size_t)s1*128 + 8*sub);
    u16x8 r2 = *(const u16x8*)(hB + (size_t)s2*128 + 8*sub);
    u16x8 r3 = *(const u16x8*)(hB + (size_t)s3*128 + 8*sub);
    float l0 = lrelu(as_[s0] + adi), l1 = lrelu(as_[s1] + adi);
    float l2 = lrelu(as_[s2] + adi), l3 = lrelu(as_[s3] + adi);
    float lm = fmaxf(fmaxf(l0, l1), fmaxf(l2, l3));
    if(lm > m + 8.f){
      float sc = __expf(m - lm); S *= sc;
      #pragma unroll
      for(int k=0;k<8;k++) acc[k] *= sc;
      m = lm;
    }
    float w0 = __expf(l0 - m), w1 = __expf(l1 - m), w2 = __expf(l2 - m), w3 = __expf(l3 - m);
    S += w0 + w1 + w2 + w3;
    #pragma unroll
    for(int k=0;k<8;k++)
      acc[k] += w0*bf2f(r0[k]) + w1*bf2f(r1[k]) + w2*bf2f(r2[k]) + w3*bf2f(r3[k]);
  }
  for(; t+7 < e1; t += 8){
    int s0 = esrc[t + q], s1 = esrc[t + 4 + q];
    u16x8 r0 = *(const u16x8*)(hB + (size_t)s0*128 + 8*sub);
    u16x8 r1 = *(const u16x8*)(hB + (size_t)s1*128 + 8*sub);
    float l0 = lrelu(as_[s0] + adi), l1 = lrelu(as_[s1] + adi);
    float lm = fmaxf(l0, l1);
    if(lm > m + 8.f){
      float sc = __expf(m - lm); S *= sc;
      #pragma unroll
      for(int k=0;k<8;k++) acc[k] *= sc;
      m = lm;
    }
    float w0 = __expf(l0 - m), w1 = __expf(l1 - m);
    S += w0 + w1;
    #pragma unroll
    for(int k=0;k<8;k++) acc[k] += w0*bf2f(r0[k]) + w1*bf2f(r1[k]);
  }
  while(t < e1){
    int idx = t + q;
    bool ok = idx < e1;
    int s = esrc[ok ? idx : e0];
    u16x8 r = *(const u16x8*)(hB + (size_t)s*128 + 8*sub);
    float l = ok ? lrelu(as_[s] + adi) : -3e38f;
    if(l > m + 8.f){
      float sc = __expf(m - l); S *= sc;
      #pragma unroll
      for(int k=0;k<8;k++) acc[k] *= sc;
      m = l;
    }
    float w = __expf(l - m);
    S += w;
    #pragma unroll
    for(int k=0;k<8;k++) acc[k] += w*bf2f(r[k]);
    t += 4;
  }
  #pragma unroll
  for(int off=32; off>=16; off>>=1){
    float mo = __shfl_down(m, off), So = __shfl_down(S, off);
    float ao[8];
    #pragma unroll
    for(int k=0;k<8;k++) ao[k] = __shfl_down(acc[k], off);
    float M = fmaxf(m, mo);
    float sc0 = __expf(m - M), sc1 = __expf(mo - M);
    S = S*sc0 + So*sc1;
    #pragma unroll
    for(int k=0;k<8;k++) acc[k] = acc[k]*sc0 + ao[k]*sc1;
    m = M;
  }
  if(lane < 16){
    float inv = 1.f/(S + 1e-16f);
    u16x8 h, l;
    #pragma unroll
    for(int k=0;k<8;k++){
      float v = acc[k]*inv;
      unsigned short hb = f2bf(v);
      h[k] = hb; l[k] = f2bf(v - bf2f(hb));
    }
    int mc = wid >> 4;
    size_t base = ((size_t)(mc*4 + (sub>>2))*64 + (wid & 15) + (sub & 3)*16) * 8;
    *(u16x8*)(fhi + base) = h;
    *(u16x8*)(flo + base) = l;
  }
}

// ---------------- GAT2 agg: D=128, quarter-wave, online softmax, fp32 out ----------------
__global__ __launch_bounds__(256) void k_gat2_agg(const unsigned short* __restrict__ hP,
                                                  const float* __restrict__ as_, const float* __restrict__ ad_,
                                                  const int* __restrict__ offs, const int* __restrict__ esrc,
                                                  const float* __restrict__ bias, float* __restrict__ out, int n){
  int wid  = (int)((blockIdx.x*256u + threadIdx.x) >> 6);
  int lane = threadIdx.x & 63;
  if(wid >= n) return;
  int q = lane >> 4, sub = lane & 15;
  float adi = ad_[wid];
  u16x8 rs = *(const u16x8*)(hP + (size_t)wid*128 + 8*sub);
  float m, S, acc[8];
  if(q == 0){
    m = lrelu(as_[wid] + adi); S = 1.f;
    #pragma unroll
    for(int k=0;k<8;k++) acc[k] = bf2f(rs[k]);
  } else {
    m = -3e38f; S = 0.f;
    #pragma unroll
    for(int k=0;k<8;k++) acc[k] = 0.f;
  }
  int e0 = offs[wid], e1 = offs[wid+1];
  int t = e0;
  for(; t+15 < e1; t += 16){
    int s0 = esrc[t + q], s1 = esrc[t + 4 + q], s2 = esrc[t + 8 + q], s3 = esrc[t + 12 + q];
    u16x8 r0 = *(const u16x8*)(hP + (size_t)s0*128 + 8*sub);
    u16x8 r1 = *(const u16x8*)(hP + (size_t)s1*128 + 8*sub);
    u16x8 r2 = *(const u16x8*)(hP + (size_t)s2*128 + 8*sub);
    u16x8 r3 = *(const u16x8*)(hP + (size_t)s3*128 + 8*sub);
    float l0 = lrelu(as_[s0] + adi), l1 = lrelu(as_[s1] + adi);
    float l2 = lrelu(as_[s2] + adi), l3 = lrelu(as_[s3] + adi);
    float lm = fmaxf(fmaxf(l0, l1), fmaxf(l2, l3));
    if(lm > m + 8.f){
      float sc = __expf(m - lm); S *= sc;
      #pragma unroll
      for(int k=0;k<8;k++) acc[k] *= sc;
      m = lm;
    }
    float w0 = __expf(l0 - m), w1 = __expf(l1 - m), w2 = __expf(l2 - m), w3 = __expf(l3 - m);
    S += w0 + w1 + w2 + w3;
    #pragma unroll
    for(int k=0;k<8;k++)
      acc[k] += w0*bf2f(r0[k]) + w1*bf2f(r1[k]) + w2*bf2f(r2[k]) + w3*bf2f(r3[k]);
  }
  for(; t+7 < e1; t += 8){
    int s0 = esrc[t + q], s1 = esrc[t + 4 + q];
    u16x8 r0 = *(const u16x8*)(hP + (size_t)s0*128 + 8*sub);
    u16x8 r1 = *(const u16x8*)(hP + (size_t)s1*128 + 8*sub);
    float l0 = lrelu(as_[s0] + adi), l1 = lrelu(as_[s1] + adi);
    float lm = fmaxf(l0, l1);
    if(lm > m + 8.f){
      float sc = __expf(m - lm); S *= sc;
      #pragma unroll
      for(int k=0;k<8;k++) acc[k] *= sc;
      m = lm;
    }
    float w0 = __expf(l0 - m), w1 = __expf(l1 - m);
    S += w0 + w1;
    #pragma unroll
    for(int k=0;k<8;k++) acc[k] += w0*bf2f(r0[k]) + w1*bf2f(r1[k]);
  }
  while(t < e1){
    int idx = t + q;
    bool ok = idx < e1;
    int s = esrc[ok ? idx : e0];
    u16x8 r = *(const u16x8*)(hP + (size_t)s*128 + 8*sub);
    float l = ok ? lrelu(as_[s] + adi) : -3e38f;
    if(l > m + 8.f){
      float sc = __expf(m - l); S *= sc;
      #pragma unroll
      for(int k=0;k<8;k++) acc[k] *= sc;
      m = l;
    }
    float w = __expf(l - m);
    S += w;
    #pragma unroll
    for(int k=0;k<8;k++) acc[k] += w*bf2f(r[k]);
    t += 4;
  }
  #pragma unroll
  for(int off=32; off>=16; off>>=1){
    float mo = __shfl_down(m, off), So = __shfl_down(S, off);
    float ao[8];
    #pragma unroll
    for(int k=0;k<8;k++) ao[k] = __shfl_down(acc[k], off);
    float M = fmaxf(m, mo);
    float sc0 = __expf(m - M), sc1 = __expf(mo - M);
    S = S*sc0 + So*sc1;
    #pragma unroll
    for(int k=0;k<8;k++) acc[k] = acc[k]*sc0 + ao[k]*sc1;
    m = M;
  }
  if(lane < 16){
    float inv = 1.f/(S + 1e-16f);
    float4 o0, o1;
    o0.x = acc[0]*inv + bias[8*sub  ]; o0.y = acc[1]*inv + bias[8*sub+1];
    o0.z = acc[2]*inv + bias[8*sub+2]; o0.w = acc[3]*inv + bias[8*sub+3];
    o1.x = acc[4]*inv + bias[8*sub+4]; o1.y = acc[5]*inv + bias[8*sub+5];
    o1.z = acc[6]*inv + bias[8*sub+6]; o1.w = acc[7]*inv + bias[8*sub+7];
    *(float4*)(out + (size_t)wid*128 + 8*sub)     = o0;
    *(float4*)(out + (size_t)wid*128 + 8*sub + 4) = o1;
  }
}

extern "C" void kernel_launch(void* const* d_in, const int* in_sizes, int n_in,
                              void* d_out, int out_size, void* d_ws, size_t ws_size,
                              hipStream_t stream){
  const float* x        = (const float*)d_in[0];
  const int*   ei       = (const int*)  d_in[1];
  const float* gin1_w1  = (const float*)d_in[3];
  const float* gin1_b1  = (const float*)d_in[4];
  const float* gin1_w2  = (const float*)d_in[5];
  const float* gin1_b2  = (const float*)d_in[6];
  const float* gin2_w1  = (const float*)d_in[7];
  const float* gin2_b1  = (const float*)d_in[8];
  const float* gin2_w2  = (const float*)d_in[9];
  const float* gin2_b2  = (const float*)d_in[10];
  const float* gat1_w   = (const float*)d_in[11];
  const float* gat1_as  = (const float*)d_in[12];
  const float* gat1_ad  = (const float*)d_in[13];
  const float* gat1_b   = (const float*)d_in[14];
  const float* gat2_w   = (const float*)d_in[15];
  const float* gat2_as  = (const float*)d_in[16];
  const float* gat2_ad  = (const float*)d_in[17];
  const float* gat2_b   = (const float*)d_in[18];

  const int n = in_sizes[0] / 10;
  const int E = in_sizes[1] / 2;
  const int* src = ei;
  const int* dst = ei + E;
  const int Mc = (n + 15) / 16;
  const int nb = (n + 1023) / 1024;
  const size_t npad = ((size_t)n*4 + 255) & ~(size_t)255;

  char* w = (char*)d_ws;
  auto carve = [&](size_t bytes)->char*{ char* p = w; w += (bytes + 255) & ~(size_t)255; return p; };
  int*   esrc = (int*)  carve((size_t)E*4);
  int*   offs = (int*)  carve((size_t)(n+1)*4);
  int*   deg  = (int*)  carve(npad);          // deg & cur contiguous -> one memset
  int*   cur  = (int*)  carve(npad);
  int*   part = (int*)  carve((size_t)n*4);
  int*   bsum = (int*)  carve((size_t)1024*4);
  unsigned short* Ybf   = (unsigned short*)carve((size_t)n*64*2);
  unsigned short* Hbf   = (unsigned short*)carve((size_t)n*64*2);
  unsigned short* hB2bf = (unsigned short*)carve((size_t)n*128*2);
  unsigned short* Pbf2  = (unsigned short*)carve((size_t)n*128*2);
  float* as_  = (float*)carve((size_t)n*4);
  float* ad_  = (float*)carve((size_t)n*4);
  float* as2_ = (float*)carve((size_t)n*4);
  float* ad2_ = (float*)carve((size_t)n*4);
  float* waS  = (float*)carve(256*4);
  float* waD  = (float*)carve(256*4);
  float* waS2 = (float*)carve(256*4);
  float* waD2 = (float*)carve(256*4);
  unsigned short* FAh = (unsigned short*)carve((size_t)Mc*8*512*2);
  unsigned short* FAl = (unsigned short*)carve((size_t)Mc*8*512*2);
  unsigned short* FBh = (unsigned short*)carve((size_t)Mc*8*512*2);
  unsigned short* FBl = (unsigned short*)carve((size_t)Mc*8*512*2);
  unsigned short* WfH = (unsigned short*)carve((size_t)188*512*2);
  unsigned short* WfL = (unsigned short*)carve((size_t)188*512*2);

  const int TPB = 256;
  int ebk = (E + TPB - 1) / TPB;
  int wbk = (n + 3) / 4;
  int gx  = (Mc + 7) / 8;
  const size_t W0 = 0, W1o = 4*512, W2o = 12*512, W3o = 28*512, W4o = 60*512, W5o = 124*512;

  // fused setup: weight frags + folded attn vecs + x frags + degree histogram (4 edges/thread)
  hipMemsetAsync(deg, 0, npad*2, stream);
  int PB = 47, WA = 96, PA = (Mc*64 + 255)/256;
  int DG = (E + 1023) / 1024;
  k_setup<<<PB + WA + PA + DG, TPB, 0, stream>>>(
      gin1_w1, gin1_w2, gin2_w1, gin2_w2, gat1_w, gat2_w, WfH, WfL,
      gat1_as, gat1_ad, gat2_as, gat2_ad, waS, waD, waS2, waD2,
      x, FAh, FAl, Mc, n, dst, deg, E, PB, WA, PA);

  // scan + XCD-partitioned fill
  k_scan1<<<nb, 1024, 0, stream>>>(deg, part, bsum, n);
  k_scan3<<<nb, 1024, 0, stream>>>(part, bsum, offs, as_, ad_, as2_, ad2_, n, E);
  k_fill8<<<8*ebk, TPB, 0, stream>>>(src, dst, offs, cur, esrc, E, n);

  // GIN1 (projection-first): y = x@W1 -> Ybf; agg(Ybf)+b1+relu -> FB frags; 64->64 +b2+relu -> Hbf
  k_mgemm<0,false,1><<<dim3(gx,1), TPB, 0, stream>>>(FAh, FAl, WfH+W0, WfL+W0, nullptr,
      nullptr, Ybf, nullptr, nullptr, nullptr, nullptr, nullptr, nullptr, n, 64, 1, Mc);
  k_gin_agg<true><<<wbk, TPB, 0, stream>>>(Ybf, offs, esrc, gin1_b1, FBh, FBl, n);
  k_mgemm<1,true,1><<<dim3(gx,1), TPB, 0, stream>>>(FBh, FBl, WfH+W1o, WfL+W1o, gin1_b2,
      nullptr, Hbf, nullptr, nullptr, nullptr, nullptr, nullptr, nullptr, n, 64, 2, Mc);

  // GIN2: agg(Hbf) -> FA frags; 64->128 relu -> FB frags; 128->128 +bias -> hB2bf + GAT1 logits
  k_gin_agg<false><<<wbk, TPB, 0, stream>>>(Hbf, offs, esrc, nullptr, FAh, FAl, n);
  k_mgemm<1,true,2><<<dim3(gx,2), TPB, 0, stream>>>(FAh, FAl, WfH+W2o, WfL+W2o, gin2_b1,
      nullptr, nullptr, FBh, FBl, nullptr, nullptr, nullptr, nullptr, n, 128, 2, Mc);
  k_mgemm<0,true,4><<<dim3(gx,2), TPB, 0, stream>>>(FBh, FBl, WfH+W3o, WfL+W3o, gin2_b2,
      nullptr, hB2bf, nullptr, nullptr, waS, waD, as_, ad_, n, 128, 4, Mc);

  // GAT1: pre-projection fused agg+softmax -> FA frags; proj 128->256 +bias+relu -> FB frags + GAT2 logits
  k_gat1_aggpre<<<wbk, TPB, 0, stream>>>(hB2bf, as_, ad_, offs, esrc, FAh, FAl, n);
  k_mgemm<1,true,3><<<dim3(gx,4), TPB, 0, stream>>>(FAh, FAl, WfH+W4o, WfL+W4o, gat1_b,
      nullptr, nullptr, FBh, FBl, waS2, waD2, as2_, ad2_, n, 256, 4, Mc);

  // GAT2: proj 256->128 -> Pbf2; fused agg+softmax -> d_out
  k_mgemm<0,false,1><<<dim3(gx,2), TPB, 0, stream>>>(FBh, FBl, WfH+W5o, WfL+W5o, nullptr,
      nullptr, Pbf2, nullptr, nullptr, nullptr, nullptr, nullptr, nullptr, n, 128, 8, Mc);
  k_gat2_agg<<<wbk, TPB, 0, stream>>>(Pbf2, as2_, ad2_, offs, esrc, gat2_b, (float*)d_out, n);
}